// Round 4
// baseline (788.515 us; speedup 1.0000x reference)
//
#include <hip/hip_runtime.h>

#define Nn 100000
#define Ee 1600000
#define FIN 128
#define HID 128
#define CLS 64

// ---------------- CSR build ----------------

__global__ void k_count(const int* __restrict__ dst, int* __restrict__ deg) {
    int e = blockIdx.x * blockDim.x + threadIdx.x;
    if (e < Ee) {
        int d = dst[e];
        if ((unsigned)d < Nn) atomicAdd(&deg[d], 1);
    }
}

// single-block exclusive scan of deg[N] -> rowptr[N+1]
__global__ void k_scan(const int* __restrict__ deg, int* __restrict__ rowptr) {
    __shared__ int sums[1024];
    const int t = threadIdx.x;
    const int chunk = (Nn + 1023) / 1024;   // 98
    const int start = t * chunk;
    const int end = min(start + chunk, Nn);
    int s = 0;
    for (int i = start; i < end; ++i) s += deg[i];
    sums[t] = s;
    __syncthreads();
    for (int off = 1; off < 1024; off <<= 1) {
        int v = (t >= off) ? sums[t - off] : 0;
        __syncthreads();
        sums[t] += v;
        __syncthreads();
    }
    int prefix = sums[t] - s;   // exclusive prefix for this thread's chunk
    for (int i = start; i < end; ++i) { rowptr[i] = prefix; prefix += deg[i]; }
    if (t == 1023) rowptr[Nn] = sums[1023];
}

__global__ void k_fill(const int* __restrict__ src, const int* __restrict__ dst,
                       const int* __restrict__ rowptr, int* __restrict__ cnt,
                       int* __restrict__ csr) {
    int e = blockIdx.x * blockDim.x + threadIdx.x;
    if (e < Ee) {
        int d = dst[e];
        if ((unsigned)d < Nn) {
            int pos = rowptr[d] + atomicAdd(&cnt[d], 1);
            csr[pos] = src[e];
        }
    }
}

// ---------------- scatter-mean aggregation (one wave per node) ----------------

__global__ __launch_bounds__(256) void k_agg(const float* __restrict__ feat,
                                             const int* __restrict__ rowptr,
                                             const int* __restrict__ csr,
                                             float* __restrict__ out) {
    int wid = (blockIdx.x * blockDim.x + threadIdx.x) >> 6;  // node id
    int lane = threadIdx.x & 63;
    if (wid >= Nn) return;
    int s0 = rowptr[wid], s1 = rowptr[wid + 1];
    float ax = 0.f, ay = 0.f;
    for (int e = s0; e < s1; ++e) {
        int s = csr[e];
        const float2 v = *reinterpret_cast<const float2*>(feat + (size_t)s * FIN + lane * 2);
        ax += v.x; ay += v.y;
    }
    float invd = (s1 > s0) ? 1.0f / (float)(s1 - s0) : 0.0f;
    float2 o; o.x = ax * invd; o.y = ay * invd;
    *reinterpret_cast<float2*>(out + (size_t)wid * FIN + lane * 2) = o;
}

// ---------------- fp32 tiled GEMMs ----------------

__device__ __forceinline__ float f4get(const float4 v, int i) {
    return (i == 0) ? v.x : (i == 1) ? v.y : (i == 2) ? v.z : v.w;
}

// out[N,128] = relu(A0@W0 + A1@W1 + bias); A* are [N,128], W* are [128,128]
__global__ __launch_bounds__(256) void k_gemm1(const float* __restrict__ A0,
                                               const float* __restrict__ A1,
                                               const float* __restrict__ W0,
                                               const float* __restrict__ W1,
                                               const float* __restrict__ bias,
                                               float* __restrict__ out) {
    __shared__ float sA[32][32];
    __shared__ float sW[32][128];
    const int tid = threadIdx.x;
    const int tx = tid & 31;        // col group: cols tx*4 .. tx*4+3
    const int ty = tid >> 5;        // rows ty, ty+8, ty+16, ty+24
    const int row0 = blockIdx.x * 32;   // N = 32*3125 exactly
    float4 acc[4];
    #pragma unroll
    for (int r = 0; r < 4; ++r) acc[r] = make_float4(0.f, 0.f, 0.f, 0.f);

    for (int pair = 0; pair < 2; ++pair) {
        const float* __restrict__ A = pair ? A1 : A0;
        const float* __restrict__ W = pair ? W1 : W0;
        for (int kc = 0; kc < 128; kc += 32) {
            {   // A tile: 32 rows x 32 k
                int r = tid >> 3, k4 = (tid & 7) << 2;
                *reinterpret_cast<float4*>(&sA[r][k4]) =
                    *reinterpret_cast<const float4*>(A + (size_t)(row0 + r) * 128 + kc + k4);
            }
            #pragma unroll
            for (int i = 0; i < 4; ++i) {   // W tile: 32 k x 128 cols
                int t4 = tid + i * 256;
                int k = t4 >> 5, c = (t4 & 31) << 2;
                *reinterpret_cast<float4*>(&sW[k][c]) =
                    *reinterpret_cast<const float4*>(W + (size_t)(kc + k) * 128 + c);
            }
            __syncthreads();
            #pragma unroll
            for (int k = 0; k < 32; k += 4) {
                float4 a[4];
                #pragma unroll
                for (int r = 0; r < 4; ++r)
                    a[r] = *reinterpret_cast<const float4*>(&sA[ty + r * 8][k]);
                #pragma unroll
                for (int kk = 0; kk < 4; ++kk) {
                    float4 w = *reinterpret_cast<const float4*>(&sW[k + kk][tx << 2]);
                    #pragma unroll
                    for (int r = 0; r < 4; ++r) {
                        float av = f4get(a[r], kk);
                        acc[r].x = fmaf(av, w.x, acc[r].x);
                        acc[r].y = fmaf(av, w.y, acc[r].y);
                        acc[r].z = fmaf(av, w.z, acc[r].z);
                        acc[r].w = fmaf(av, w.w, acc[r].w);
                    }
                }
            }
            __syncthreads();
        }
    }
    float4 bv = *reinterpret_cast<const float4*>(bias + (tx << 2));
    #pragma unroll
    for (int r = 0; r < 4; ++r) {
        float4 o;
        o.x = fmaxf(acc[r].x + bv.x, 0.f);
        o.y = fmaxf(acc[r].y + bv.y, 0.f);
        o.z = fmaxf(acc[r].z + bv.z, 0.f);
        o.w = fmaxf(acc[r].w + bv.w, 0.f);
        *reinterpret_cast<float4*>(out + (size_t)(row0 + ty + r * 8) * 128 + (tx << 2)) = o;
    }
}

// out[N,64] = A0@W0 + A1@W1 + bias; A* are [N,128], W* are [128,64]
__global__ __launch_bounds__(256) void k_gemm2(const float* __restrict__ A0,
                                               const float* __restrict__ A1,
                                               const float* __restrict__ W0,
                                               const float* __restrict__ W1,
                                               const float* __restrict__ bias,
                                               float* __restrict__ out) {
    __shared__ float sA[32][32];
    __shared__ float sW[32][64];
    const int tid = threadIdx.x;
    const int tx = tid & 15;        // cols tx*4 .. tx*4+3
    const int ty = tid >> 4;        // rows ty, ty+16
    const int row0 = blockIdx.x * 32;
    float4 acc[2];
    acc[0] = make_float4(0.f, 0.f, 0.f, 0.f);
    acc[1] = make_float4(0.f, 0.f, 0.f, 0.f);

    for (int pair = 0; pair < 2; ++pair) {
        const float* __restrict__ A = pair ? A1 : A0;
        const float* __restrict__ W = pair ? W1 : W0;
        for (int kc = 0; kc < 128; kc += 32) {
            {   // A tile: 32 x 32
                int r = tid >> 3, k4 = (tid & 7) << 2;
                *reinterpret_cast<float4*>(&sA[r][k4]) =
                    *reinterpret_cast<const float4*>(A + (size_t)(row0 + r) * 128 + kc + k4);
            }
            #pragma unroll
            for (int i = 0; i < 2; ++i) {   // W tile: 32 k x 64 cols
                int t4 = tid + i * 256;     // 0..511
                int k = t4 >> 4, c = (t4 & 15) << 2;
                *reinterpret_cast<float4*>(&sW[k][c]) =
                    *reinterpret_cast<const float4*>(W + (size_t)(kc + k) * 64 + c);
            }
            __syncthreads();
            #pragma unroll
            for (int k = 0; k < 32; k += 4) {
                float4 a[2];
                a[0] = *reinterpret_cast<const float4*>(&sA[ty][k]);
                a[1] = *reinterpret_cast<const float4*>(&sA[ty + 16][k]);
                #pragma unroll
                for (int kk = 0; kk < 4; ++kk) {
                    float4 w = *reinterpret_cast<const float4*>(&sW[k + kk][tx << 2]);
                    #pragma unroll
                    for (int r = 0; r < 2; ++r) {
                        float av = f4get(a[r], kk);
                        acc[r].x = fmaf(av, w.x, acc[r].x);
                        acc[r].y = fmaf(av, w.y, acc[r].y);
                        acc[r].z = fmaf(av, w.z, acc[r].z);
                        acc[r].w = fmaf(av, w.w, acc[r].w);
                    }
                }
            }
            __syncthreads();
        }
    }
    float4 bv = *reinterpret_cast<const float4*>(bias + (tx << 2));
    #pragma unroll
    for (int r = 0; r < 2; ++r) {
        float4 o;
        o.x = acc[r].x + bv.x;
        o.y = acc[r].y + bv.y;
        o.z = acc[r].z + bv.z;
        o.w = acc[r].w + bv.w;
        *reinterpret_cast<float4*>(out + (size_t)(row0 + ty + r * 16) * 64 + (tx << 2)) = o;
    }
}

// ---------------- in-place log_softmax over 64 classes (one wave per row) ----------------

__global__ __launch_bounds__(256) void k_logsm(float* __restrict__ out) {
    int wid = (blockIdx.x * blockDim.x + threadIdx.x) >> 6;
    int lane = threadIdx.x & 63;
    if (wid >= Nn) return;
    float v = out[(size_t)wid * 64 + lane];
    float m = v;
    #pragma unroll
    for (int off = 32; off; off >>= 1) m = fmaxf(m, __shfl_xor(m, off));
    float ex = __expf(v - m);
    float s = ex;
    #pragma unroll
    for (int off = 32; off; off >>= 1) s += __shfl_xor(s, off);
    out[(size_t)wid * 64 + lane] = v - m - __logf(s);
}

// ---------------- launch ----------------

extern "C" void kernel_launch(void* const* d_in, const int* in_sizes, int n_in,
                              void* d_out, int out_size, void* d_ws, size_t ws_size,
                              hipStream_t stream) {
    const float* x   = (const float*)d_in[0];
    const int*   ei  = (const int*)d_in[1];     // [2, E] int32
    const float* W1l = (const float*)d_in[2];
    const float* W1r = (const float*)d_in[3];
    const float* b1  = (const float*)d_in[4];
    const float* W2l = (const float*)d_in[5];
    const float* W2r = (const float*)d_in[6];
    const float* b2  = (const float*)d_in[7];
    float* out = (float*)d_out;

    char* ws = (char*)d_ws;
    int*   deg    = (int*)(ws + 0);          // N ints
    int*   cnt    = (int*)(ws + 400384);     // N ints
    int*   rowptr = (int*)(ws + 800768);     // N+1 ints
    int*   csr    = (int*)(ws + 1201152);    // E ints
    float* agg    = (float*)(ws + 7601152);  // N*128 f32
    float* h      = (float*)(ws + 58801152); // N*128 f32

    const int* src = ei;
    const int* dst = ei + Ee;

    // zero deg + cnt (one range covers both)
    hipMemsetAsync(deg, 0, 800768, stream);

    k_count<<<(Ee + 255) / 256, 256, 0, stream>>>(dst, deg);
    k_scan<<<1, 1024, 0, stream>>>(deg, rowptr);
    k_fill<<<(Ee + 255) / 256, 256, 0, stream>>>(src, dst, rowptr, cnt, csr);

    // layer 1
    k_agg<<<(Nn + 3) / 4, 256, 0, stream>>>(x, rowptr, csr, agg);
    k_gemm1<<<Nn / 32, 256, 0, stream>>>(agg, x, W1l, W1r, b1, h);

    // layer 2
    k_agg<<<(Nn + 3) / 4, 256, 0, stream>>>(h, rowptr, csr, agg);
    k_gemm2<<<Nn / 32, 256, 0, stream>>>(agg, h, W2l, W2r, b2, out);

    k_logsm<<<(Nn + 3) / 4, 256, 0, stream>>>(out);
}

// Round 8
// 766.370 us; speedup vs baseline: 1.0289x; 1.0289x over previous
//
#include <hip/hip_runtime.h>

#define Nn 100000
#define Ee 1600000
#define FIN 128
#define HID 128
#define CLS 64

typedef unsigned short ushort_t;
typedef unsigned int uint_t;

__device__ __forceinline__ ushort_t f2bf(float f) {   // RNE fp32->bf16
    uint_t u = __float_as_uint(f);
    return (ushort_t)((u + 0x7fffu + ((u >> 16) & 1u)) >> 16);
}
__device__ __forceinline__ float bflo(uint_t u) { return __uint_as_float(u << 16); }
__device__ __forceinline__ float bfhi(uint_t u) { return __uint_as_float(u & 0xffff0000u); }

// ---------------- CSR build ----------------

__global__ void k_count(const int* __restrict__ dst, int* __restrict__ deg) {
    int e = blockIdx.x * blockDim.x + threadIdx.x;
    if (e < Ee) {
        int d = dst[e];
        if ((unsigned)d < Nn) atomicAdd(&deg[d], 1);
    }
}

__global__ void k_scan(const int* __restrict__ deg, int* __restrict__ rowptr) {
    __shared__ int sums[1024];
    const int t = threadIdx.x;
    const int chunk = (Nn + 1023) / 1024;
    const int start = t * chunk;
    const int end = min(start + chunk, Nn);
    int s = 0;
    for (int i = start; i < end; ++i) s += deg[i];
    sums[t] = s;
    __syncthreads();
    for (int off = 1; off < 1024; off <<= 1) {
        int v = (t >= off) ? sums[t - off] : 0;
        __syncthreads();
        sums[t] += v;
        __syncthreads();
    }
    int prefix = sums[t] - s;
    for (int i = start; i < end; ++i) { rowptr[i] = prefix; prefix += deg[i]; }
    if (t == 1023) rowptr[Nn] = sums[1023];
}

__global__ void k_fill(const int* __restrict__ src, const int* __restrict__ dst,
                       const int* __restrict__ rowptr, int* __restrict__ cnt,
                       int* __restrict__ csr) {
    int e = blockIdx.x * blockDim.x + threadIdx.x;
    if (e < Ee) {
        int d = dst[e];
        if ((unsigned)d < Nn) {
            int pos = rowptr[d] + atomicAdd(&cnt[d], 1);
            csr[pos] = src[e];
        }
    }
}

// ---------------- fp32 -> bf16 table conversion ----------------

__global__ __launch_bounds__(256) void k_cvt(const float* __restrict__ in,
                                             ushort_t* __restrict__ outb, int n4) {
    int i = blockIdx.x * blockDim.x + threadIdx.x;
    if (i < n4) {
        float4 v = reinterpret_cast<const float4*>(in)[i];
        ushort4 o;
        o.x = f2bf(v.x); o.y = f2bf(v.y); o.z = f2bf(v.z); o.w = f2bf(v.w);
        reinterpret_cast<ushort4*>(outb)[i] = o;
    }
}

// ---------------- aggregation: bf16 gather, fp32 accumulate ----------------

// 128-wide table (layer 1): lane covers 2 elems
__global__ __launch_bounds__(256) void k_agg1(const ushort_t* __restrict__ xb,
                                              const int* __restrict__ rowptr,
                                              const int* __restrict__ csr,
                                              float* __restrict__ out) {
    int wid = (blockIdx.x * blockDim.x + threadIdx.x) >> 6;
    int lane = threadIdx.x & 63;
    if (wid >= Nn) return;
    int s0 = rowptr[wid], s1 = rowptr[wid + 1];
    float ax = 0.f, ay = 0.f;
    for (int e = s0; e < s1; ++e) {
        int s = csr[e];
        uint_t u = *reinterpret_cast<const uint_t*>(xb + (size_t)s * 128 + lane * 2);
        ax += bflo(u); ay += bfhi(u);
    }
    float invd = (s1 > s0) ? 1.0f / (float)(s1 - s0) : 0.0f;
    float2 o; o.x = ax * invd; o.y = ay * invd;
    *reinterpret_cast<float2*>(out + (size_t)wid * 128 + lane * 2) = o;
}

// 64-wide table (layer 2): lane covers 1 elem
__global__ __launch_bounds__(256) void k_agg2(const ushort_t* __restrict__ tb,
                                              const int* __restrict__ rowptr,
                                              const int* __restrict__ csr,
                                              float* __restrict__ out) {
    int wid = (blockIdx.x * blockDim.x + threadIdx.x) >> 6;
    int lane = threadIdx.x & 63;
    if (wid >= Nn) return;
    int s0 = rowptr[wid], s1 = rowptr[wid + 1];
    float a = 0.f;
    for (int e = s0; e < s1; ++e) {
        int s = csr[e];
        a += __uint_as_float(((uint_t)tb[(size_t)s * 64 + lane]) << 16);
    }
    float invd = (s1 > s0) ? 1.0f / (float)(s1 - s0) : 0.0f;
    out[(size_t)wid * 64 + lane] = a * invd;
}

// ---------------- GEMMs ----------------

__device__ __forceinline__ float f4get(const float4 v, int i) {
    return (i == 0) ? v.x : (i == 1) ? v.y : (i == 2) ? v.z : v.w;
}

// hb[N,128](bf16) = relu(A0@W0 + A1@W1 + bias); A0,A1 fp32 [N,128]; W [128,128]
__global__ __launch_bounds__(256) void k_gemm1(const float* __restrict__ A0,
                                               const float* __restrict__ A1,
                                               const float* __restrict__ W0,
                                               const float* __restrict__ W1,
                                               const float* __restrict__ bias,
                                               ushort_t* __restrict__ hb) {
    __shared__ float sA[32][32];
    __shared__ float sW[32][128];
    const int tid = threadIdx.x;
    const int tx = tid & 31;
    const int ty = tid >> 5;
    const int row0 = blockIdx.x * 32;
    float4 acc[4];
    #pragma unroll
    for (int r = 0; r < 4; ++r) acc[r] = make_float4(0.f, 0.f, 0.f, 0.f);

    for (int pair = 0; pair < 2; ++pair) {
        const float* __restrict__ A = pair ? A1 : A0;
        const float* __restrict__ W = pair ? W1 : W0;
        for (int kc = 0; kc < 128; kc += 32) {
            {
                int r = tid >> 3, k4 = (tid & 7) << 2;
                *reinterpret_cast<float4*>(&sA[r][k4]) =
                    *reinterpret_cast<const float4*>(A + (size_t)(row0 + r) * 128 + kc + k4);
            }
            #pragma unroll
            for (int i = 0; i < 4; ++i) {
                int t4 = tid + i * 256;
                int k = t4 >> 5, c = (t4 & 31) << 2;
                *reinterpret_cast<float4*>(&sW[k][c]) =
                    *reinterpret_cast<const float4*>(W + (size_t)(kc + k) * 128 + c);
            }
            __syncthreads();
            #pragma unroll
            for (int k = 0; k < 32; k += 4) {
                float4 a[4];
                #pragma unroll
                for (int r = 0; r < 4; ++r)
                    a[r] = *reinterpret_cast<const float4*>(&sA[ty + r * 8][k]);
                #pragma unroll
                for (int kk = 0; kk < 4; ++kk) {
                    float4 w = *reinterpret_cast<const float4*>(&sW[k + kk][tx << 2]);
                    #pragma unroll
                    for (int r = 0; r < 4; ++r) {
                        float av = f4get(a[r], kk);
                        acc[r].x = fmaf(av, w.x, acc[r].x);
                        acc[r].y = fmaf(av, w.y, acc[r].y);
                        acc[r].z = fmaf(av, w.z, acc[r].z);
                        acc[r].w = fmaf(av, w.w, acc[r].w);
                    }
                }
            }
            __syncthreads();
        }
    }
    float4 bv = *reinterpret_cast<const float4*>(bias + (tx << 2));
    #pragma unroll
    for (int r = 0; r < 4; ++r) {
        ushort4 o;
        o.x = f2bf(fmaxf(acc[r].x + bv.x, 0.f));
        o.y = f2bf(fmaxf(acc[r].y + bv.y, 0.f));
        o.z = f2bf(fmaxf(acc[r].z + bv.z, 0.f));
        o.w = f2bf(fmaxf(acc[r].w + bv.w, 0.f));
        *reinterpret_cast<ushort4*>(hb + (size_t)(row0 + ty + r * 8) * 128 + (tx << 2)) = o;
    }
}

// tb[N,64](bf16) = A(bf16 [N,128]) @ W(fp32 [128,64])   (lin_l projection, pre-aggregation)
__global__ __launch_bounds__(256) void k_gemm2a(const ushort_t* __restrict__ Ab,
                                                const float* __restrict__ W,
                                                ushort_t* __restrict__ tb) {
    __shared__ float sA[32][32];
    __shared__ float sW[32][64];
    const int tid = threadIdx.x;
    const int tx = tid & 15;
    const int ty = tid >> 4;
    const int row0 = blockIdx.x * 32;
    float4 acc[2];
    acc[0] = make_float4(0.f, 0.f, 0.f, 0.f);
    acc[1] = make_float4(0.f, 0.f, 0.f, 0.f);

    for (int kc = 0; kc < 128; kc += 32) {
        {
            int r = tid >> 3, k4 = (tid & 7) << 2;
            uint2 u = *reinterpret_cast<const uint2*>(Ab + (size_t)(row0 + r) * 128 + kc + k4);
            float4 af;
            af.x = bflo(u.x); af.y = bfhi(u.x); af.z = bflo(u.y); af.w = bfhi(u.y);
            *reinterpret_cast<float4*>(&sA[r][k4]) = af;
        }
        #pragma unroll
        for (int i = 0; i < 2; ++i) {
            int t4 = tid + i * 256;
            int k = t4 >> 4, c = (t4 & 15) << 2;
            *reinterpret_cast<float4*>(&sW[k][c]) =
                *reinterpret_cast<const float4*>(W + (size_t)(kc + k) * 64 + c);
        }
        __syncthreads();
        #pragma unroll
        for (int k = 0; k < 32; k += 4) {
            float4 a[2];
            a[0] = *reinterpret_cast<const float4*>(&sA[ty][k]);
            a[1] = *reinterpret_cast<const float4*>(&sA[ty + 16][k]);
            #pragma unroll
            for (int kk = 0; kk < 4; ++kk) {
                float4 w = *reinterpret_cast<const float4*>(&sW[k + kk][tx << 2]);
                #pragma unroll
                for (int r = 0; r < 2; ++r) {
                    float av = f4get(a[r], kk);
                    acc[r].x = fmaf(av, w.x, acc[r].x);
                    acc[r].y = fmaf(av, w.y, acc[r].y);
                    acc[r].z = fmaf(av, w.z, acc[r].z);
                    acc[r].w = fmaf(av, w.w, acc[r].w);
                }
            }
        }
        __syncthreads();
    }
    #pragma unroll
    for (int r = 0; r < 2; ++r) {
        ushort4 o;
        o.x = f2bf(acc[r].x); o.y = f2bf(acc[r].y);
        o.z = f2bf(acc[r].z); o.w = f2bf(acc[r].w);
        *reinterpret_cast<ushort4*>(tb + (size_t)(row0 + ty + r * 16) * 64 + (tx << 2)) = o;
    }
}

// out[N,64](fp32) = A(bf16 [N,128]) @ W(fp32 [128,64]) + agg2 + bias   (lin_r + aggregated lin_l)
__global__ __launch_bounds__(256) void k_gemm2b(const ushort_t* __restrict__ Ab,
                                                const float* __restrict__ W,
                                                const float* __restrict__ agg2,
                                                const float* __restrict__ bias,
                                                float* __restrict__ out) {
    __shared__ float sA[32][32];
    __shared__ float sW[32][64];
    const int tid = threadIdx.x;
    const int tx = tid & 15;
    const int ty = tid >> 4;
    const int row0 = blockIdx.x * 32;
    float4 acc[2];
    acc[0] = make_float4(0.f, 0.f, 0.f, 0.f);
    acc[1] = make_float4(0.f, 0.f, 0.f, 0.f);

    for (int kc = 0; kc < 128; kc += 32) {
        {
            int r = tid >> 3, k4 = (tid & 7) << 2;
            uint2 u = *reinterpret_cast<const uint2*>(Ab + (size_t)(row0 + r) * 128 + kc + k4);
            float4 af;
            af.x = bflo(u.x); af.y = bfhi(u.x); af.z = bflo(u.y); af.w = bfhi(u.y);
            *reinterpret_cast<float4*>(&sA[r][k4]) = af;
        }
        #pragma unroll
        for (int i = 0; i < 2; ++i) {
            int t4 = tid + i * 256;
            int k = t4 >> 4, c = (t4 & 15) << 2;
            *reinterpret_cast<float4*>(&sW[k][c]) =
                *reinterpret_cast<const float4*>(W + (size_t)(kc + k) * 64 + c);
        }
        __syncthreads();
        #pragma unroll
        for (int k = 0; k < 32; k += 4) {
            float4 a[2];
            a[0] = *reinterpret_cast<const float4*>(&sA[ty][k]);
            a[1] = *reinterpret_cast<const float4*>(&sA[ty + 16][k]);
            #pragma unroll
            for (int kk = 0; kk < 4; ++kk) {
                float4 w = *reinterpret_cast<const float4*>(&sW[k + kk][tx << 2]);
                #pragma unroll
                for (int r = 0; r < 2; ++r) {
                    float av = f4get(a[r], kk);
                    acc[r].x = fmaf(av, w.x, acc[r].x);
                    acc[r].y = fmaf(av, w.y, acc[r].y);
                    acc[r].z = fmaf(av, w.z, acc[r].z);
                    acc[r].w = fmaf(av, w.w, acc[r].w);
                }
            }
        }
        __syncthreads();
    }
    float4 bv = *reinterpret_cast<const float4*>(bias + (tx << 2));
    #pragma unroll
    for (int r = 0; r < 2; ++r) {
        float4 g = *reinterpret_cast<const float4*>(agg2 + (size_t)(row0 + ty + r * 16) * 64 + (tx << 2));
        float4 o;
        o.x = acc[r].x + g.x + bv.x;
        o.y = acc[r].y + g.y + bv.y;
        o.z = acc[r].z + g.z + bv.z;
        o.w = acc[r].w + g.w + bv.w;
        *reinterpret_cast<float4*>(out + (size_t)(row0 + ty + r * 16) * 64 + (tx << 2)) = o;
    }
}

// ---------------- in-place log_softmax over 64 classes ----------------

__global__ __launch_bounds__(256) void k_logsm(float* __restrict__ out) {
    int wid = (blockIdx.x * blockDim.x + threadIdx.x) >> 6;
    int lane = threadIdx.x & 63;
    if (wid >= Nn) return;
    float v = out[(size_t)wid * 64 + lane];
    float m = v;
    #pragma unroll
    for (int off = 32; off; off >>= 1) m = fmaxf(m, __shfl_xor(m, off));
    float ex = __expf(v - m);
    float s = ex;
    #pragma unroll
    for (int off = 32; off; off >>= 1) s += __shfl_xor(s, off);
    out[(size_t)wid * 64 + lane] = v - m - __logf(s);
}

// ---------------- launch ----------------

extern "C" void kernel_launch(void* const* d_in, const int* in_sizes, int n_in,
                              void* d_out, int out_size, void* d_ws, size_t ws_size,
                              hipStream_t stream) {
    const float* x   = (const float*)d_in[0];
    const int*   ei  = (const int*)d_in[1];
    const float* W1l = (const float*)d_in[2];
    const float* W1r = (const float*)d_in[3];
    const float* b1  = (const float*)d_in[4];
    const float* W2l = (const float*)d_in[5];
    const float* W2r = (const float*)d_in[6];
    const float* b2  = (const float*)d_in[7];
    float* out = (float*)d_out;

    char* ws = (char*)d_ws;
    int*      deg    = (int*)(ws + 0);            // N ints
    int*      cnt    = (int*)(ws + 400384);       // N ints
    int*      rowptr = (int*)(ws + 800768);       // N+1 ints
    int*      csr    = (int*)(ws + 1201152);      // E ints
    ushort_t* xb     = (ushort_t*)(ws + 7601152); // N*128 bf16 (layer-1 gather table)
    float*    agg    = (float*)(ws + 33201152);   // N*128 f32 (layer-1 agg)
    ushort_t* hb     = (ushort_t*)(ws + 84401152);// N*128 bf16 (hidden)
    // aliases (disjoint lifetimes):
    ushort_t* tb     = (ushort_t*)(ws + 7601152); // N*64 bf16 over dead xb
    float*    agg2   = (float*)(ws + 33201152);   // N*64 f32 over dead agg
    // high-water: 84401152 + 25600000 = 110001152 bytes

    const int* src = ei;
    const int* dst = ei + Ee;

    hipMemsetAsync(deg, 0, 800768, stream);   // deg + cnt

    k_count<<<(Ee + 255) / 256, 256, 0, stream>>>(dst, deg);
    k_scan<<<1, 1024, 0, stream>>>(deg, rowptr);
    k_fill<<<(Ee + 255) / 256, 256, 0, stream>>>(src, dst, rowptr, cnt, csr);

    // layer 1: xb = bf16(x); agg = mean-gather(xb); h = relu(agg@W1l + x@W1r + b1) -> bf16
    k_cvt<<<(Nn * FIN / 4 + 255) / 256, 256, 0, stream>>>(x, xb, Nn * FIN / 4);
    k_agg1<<<(Nn + 3) / 4, 256, 0, stream>>>(xb, rowptr, csr, agg);
    k_gemm1<<<Nn / 32, 256, 0, stream>>>(agg, x, W1l, W1r, b1, hb);

    // layer 2 (reassociated): tb = bf16(h@W2l); agg2 = mean-gather(tb); out = h@W2r + agg2 + b2
    k_gemm2a<<<Nn / 32, 256, 0, stream>>>(hb, W2l, tb);
    k_agg2<<<(Nn + 3) / 4, 256, 0, stream>>>(tb, rowptr, csr, agg2);
    k_gemm2b<<<Nn / 32, 256, 0, stream>>>(hb, W2r, agg2, b2, out);

    k_logsm<<<(Nn + 3) / 4, 256, 0, stream>>>(out);
}

// Round 9
// 614.132 us; speedup vs baseline: 1.2840x; 1.2479x over previous
//
#include <hip/hip_runtime.h>

#define Nn 100000
#define Ee 1600000
#define FIN 128
#define HID 128
#define CLS 64
#define SCAN_NB 25   // ceil(Nn / 4096)

typedef unsigned short ushort_t;
typedef unsigned int uint_t;

__device__ __forceinline__ ushort_t f2bf(float f) {   // RNE fp32->bf16
    uint_t u = __float_as_uint(f);
    return (ushort_t)((u + 0x7fffu + ((u >> 16) & 1u)) >> 16);
}
__device__ __forceinline__ float bflo(uint_t u) { return __uint_as_float(u << 16); }
__device__ __forceinline__ float bfhi(uint_t u) { return __uint_as_float(u & 0xffff0000u); }

// ---------------- CSR build ----------------

__global__ void k_count(const int* __restrict__ dst, int* __restrict__ deg) {
    int e = blockIdx.x * blockDim.x + threadIdx.x;
    if (e < Ee) {
        int d = dst[e];
        if ((unsigned)d < Nn) atomicAdd(&deg[d], 1);
    }
}

// pass 1: per-block (4096 elems) sums
__global__ __launch_bounds__(1024) void k_scan1(const int* __restrict__ deg,
                                                int* __restrict__ bsum) {
    __shared__ int red[16];
    int t = threadIdx.x, b = blockIdx.x;
    int i4 = b * 1024 + t;                  // int4 index; Nn/4 = 25000
    int s = 0;
    if (i4 < Nn / 4) {
        int4 v = reinterpret_cast<const int4*>(deg)[i4];
        s = v.x + v.y + v.z + v.w;
    }
    #pragma unroll
    for (int off = 32; off; off >>= 1) s += __shfl_down(s, off);
    if ((t & 63) == 0) red[t >> 6] = s;
    __syncthreads();
    if (t < 16) {
        int v = red[t];
        #pragma unroll
        for (int off = 8; off; off >>= 1) v += __shfl_down(v, off);
        if (t == 0) bsum[b] = v;
    }
}

// pass 2: exclusive scan of the 25 block sums (tiny, serial)
__global__ void k_scan2(int* __restrict__ bsum, int* __restrict__ rowptr) {
    if (threadIdx.x == 0) {
        int acc = 0;
        for (int b = 0; b < SCAN_NB; ++b) { int v = bsum[b]; bsum[b] = acc; acc += v; }
        rowptr[Nn] = acc;
    }
}

// pass 3: block-level exclusive scan + block offset -> rowptr[0..Nn)
__global__ __launch_bounds__(1024) void k_scan3(const int* __restrict__ deg,
                                                const int* __restrict__ bsum,
                                                int* __restrict__ rowptr) {
    __shared__ int sums[1024];
    int t = threadIdx.x, b = blockIdx.x;
    int i4 = b * 1024 + t;
    int4 v = make_int4(0, 0, 0, 0);
    if (i4 < Nn / 4) v = reinterpret_cast<const int4*>(deg)[i4];
    int s = v.x + v.y + v.z + v.w;
    sums[t] = s;
    __syncthreads();
    for (int off = 1; off < 1024; off <<= 1) {
        int vv = (t >= off) ? sums[t - off] : 0;
        __syncthreads();
        sums[t] += vv;
        __syncthreads();
    }
    int excl = sums[t] - s + bsum[b];
    if (i4 < Nn / 4) {
        int4 o;
        o.x = excl;
        o.y = excl + v.x;
        o.z = excl + v.x + v.y;
        o.w = excl + v.x + v.y + v.z;
        reinterpret_cast<int4*>(rowptr)[i4] = o;
    }
}

__global__ void k_fill(const int* __restrict__ src, const int* __restrict__ dst,
                       const int* __restrict__ rowptr, int* __restrict__ cnt,
                       int* __restrict__ csr) {
    int e = blockIdx.x * blockDim.x + threadIdx.x;
    if (e < Ee) {
        int d = dst[e];
        if ((unsigned)d < Nn) {
            int pos = rowptr[d] + atomicAdd(&cnt[d], 1);
            csr[pos] = src[e];
        }
    }
}

// ---------------- fp32 -> bf16 table conversion ----------------

__global__ __launch_bounds__(256) void k_cvt(const float* __restrict__ in,
                                             ushort_t* __restrict__ outb, int n4) {
    int i = blockIdx.x * blockDim.x + threadIdx.x;
    if (i < n4) {
        float4 v = reinterpret_cast<const float4*>(in)[i];
        ushort4 o;
        o.x = f2bf(v.x); o.y = f2bf(v.y); o.z = f2bf(v.z); o.w = f2bf(v.w);
        reinterpret_cast<ushort4*>(outb)[i] = o;
    }
}

// ---------------- aggregation: bf16 gather, fp32 accumulate ----------------

// 128-wide table (layer 1): lane covers 2 elems
__global__ __launch_bounds__(256) void k_agg1(const ushort_t* __restrict__ xb,
                                              const int* __restrict__ rowptr,
                                              const int* __restrict__ csr,
                                              float* __restrict__ out) {
    int wid = (blockIdx.x * blockDim.x + threadIdx.x) >> 6;
    int lane = threadIdx.x & 63;
    if (wid >= Nn) return;
    int s0 = rowptr[wid], s1 = rowptr[wid + 1];
    float ax = 0.f, ay = 0.f;
    for (int e = s0; e < s1; ++e) {
        int s = csr[e];
        uint_t u = *reinterpret_cast<const uint_t*>(xb + (size_t)s * 128 + lane * 2);
        ax += bflo(u); ay += bfhi(u);
    }
    float invd = (s1 > s0) ? 1.0f / (float)(s1 - s0) : 0.0f;
    float2 o; o.x = ax * invd; o.y = ay * invd;
    *reinterpret_cast<float2*>(out + (size_t)wid * 128 + lane * 2) = o;
}

// 64-wide table (layer 2): lane covers 1 elem
__global__ __launch_bounds__(256) void k_agg2(const ushort_t* __restrict__ tb,
                                              const int* __restrict__ rowptr,
                                              const int* __restrict__ csr,
                                              float* __restrict__ out) {
    int wid = (blockIdx.x * blockDim.x + threadIdx.x) >> 6;
    int lane = threadIdx.x & 63;
    if (wid >= Nn) return;
    int s0 = rowptr[wid], s1 = rowptr[wid + 1];
    float a = 0.f;
    for (int e = s0; e < s1; ++e) {
        int s = csr[e];
        a += __uint_as_float(((uint_t)tb[(size_t)s * 64 + lane]) << 16);
    }
    float invd = (s1 > s0) ? 1.0f / (float)(s1 - s0) : 0.0f;
    out[(size_t)wid * 64 + lane] = a * invd;
}

// ---------------- GEMMs ----------------

__device__ __forceinline__ float f4get(const float4 v, int i) {
    return (i == 0) ? v.x : (i == 1) ? v.y : (i == 2) ? v.z : v.w;
}

// hb[N,128](bf16) = relu(A0@W0 + A1@W1 + bias); A0,A1 fp32 [N,128]; W [128,128]
__global__ __launch_bounds__(256) void k_gemm1(const float* __restrict__ A0,
                                               const float* __restrict__ A1,
                                               const float* __restrict__ W0,
                                               const float* __restrict__ W1,
                                               const float* __restrict__ bias,
                                               ushort_t* __restrict__ hb) {
    __shared__ float sA[32][32];
    __shared__ float sW[32][128];
    const int tid = threadIdx.x;
    const int tx = tid & 31;
    const int ty = tid >> 5;
    const int row0 = blockIdx.x * 32;
    float4 acc[4];
    #pragma unroll
    for (int r = 0; r < 4; ++r) acc[r] = make_float4(0.f, 0.f, 0.f, 0.f);

    for (int pair = 0; pair < 2; ++pair) {
        const float* __restrict__ A = pair ? A1 : A0;
        const float* __restrict__ W = pair ? W1 : W0;
        for (int kc = 0; kc < 128; kc += 32) {
            {
                int r = tid >> 3, k4 = (tid & 7) << 2;
                *reinterpret_cast<float4*>(&sA[r][k4]) =
                    *reinterpret_cast<const float4*>(A + (size_t)(row0 + r) * 128 + kc + k4);
            }
            #pragma unroll
            for (int i = 0; i < 4; ++i) {
                int t4 = tid + i * 256;
                int k = t4 >> 5, c = (t4 & 31) << 2;
                *reinterpret_cast<float4*>(&sW[k][c]) =
                    *reinterpret_cast<const float4*>(W + (size_t)(kc + k) * 128 + c);
            }
            __syncthreads();
            #pragma unroll
            for (int k = 0; k < 32; k += 4) {
                float4 a[4];
                #pragma unroll
                for (int r = 0; r < 4; ++r)
                    a[r] = *reinterpret_cast<const float4*>(&sA[ty + r * 8][k]);
                #pragma unroll
                for (int kk = 0; kk < 4; ++kk) {
                    float4 w = *reinterpret_cast<const float4*>(&sW[k + kk][tx << 2]);
                    #pragma unroll
                    for (int r = 0; r < 4; ++r) {
                        float av = f4get(a[r], kk);
                        acc[r].x = fmaf(av, w.x, acc[r].x);
                        acc[r].y = fmaf(av, w.y, acc[r].y);
                        acc[r].z = fmaf(av, w.z, acc[r].z);
                        acc[r].w = fmaf(av, w.w, acc[r].w);
                    }
                }
            }
            __syncthreads();
        }
    }
    float4 bv = *reinterpret_cast<const float4*>(bias + (tx << 2));
    #pragma unroll
    for (int r = 0; r < 4; ++r) {
        ushort4 o;
        o.x = f2bf(fmaxf(acc[r].x + bv.x, 0.f));
        o.y = f2bf(fmaxf(acc[r].y + bv.y, 0.f));
        o.z = f2bf(fmaxf(acc[r].z + bv.z, 0.f));
        o.w = f2bf(fmaxf(acc[r].w + bv.w, 0.f));
        *reinterpret_cast<ushort4*>(hb + (size_t)(row0 + ty + r * 8) * 128 + (tx << 2)) = o;
    }
}

// tb[N,64](bf16) = A(bf16 [N,128]) @ W(fp32 [128,64])   (lin_l projection, pre-aggregation)
__global__ __launch_bounds__(256) void k_gemm2a(const ushort_t* __restrict__ Ab,
                                                const float* __restrict__ W,
                                                ushort_t* __restrict__ tb) {
    __shared__ float sA[32][32];
    __shared__ float sW[32][64];
    const int tid = threadIdx.x;
    const int tx = tid & 15;
    const int ty = tid >> 4;
    const int row0 = blockIdx.x * 32;
    float4 acc[2];
    acc[0] = make_float4(0.f, 0.f, 0.f, 0.f);
    acc[1] = make_float4(0.f, 0.f, 0.f, 0.f);

    for (int kc = 0; kc < 128; kc += 32) {
        {
            int r = tid >> 3, k4 = (tid & 7) << 2;
            uint2 u = *reinterpret_cast<const uint2*>(Ab + (size_t)(row0 + r) * 128 + kc + k4);
            float4 af;
            af.x = bflo(u.x); af.y = bfhi(u.x); af.z = bflo(u.y); af.w = bfhi(u.y);
            *reinterpret_cast<float4*>(&sA[r][k4]) = af;
        }
        #pragma unroll
        for (int i = 0; i < 2; ++i) {
            int t4 = tid + i * 256;
            int k = t4 >> 4, c = (t4 & 15) << 2;
            *reinterpret_cast<float4*>(&sW[k][c]) =
                *reinterpret_cast<const float4*>(W + (size_t)(kc + k) * 64 + c);
        }
        __syncthreads();
        #pragma unroll
        for (int k = 0; k < 32; k += 4) {
            float4 a[2];
            a[0] = *reinterpret_cast<const float4*>(&sA[ty][k]);
            a[1] = *reinterpret_cast<const float4*>(&sA[ty + 16][k]);
            #pragma unroll
            for (int kk = 0; kk < 4; ++kk) {
                float4 w = *reinterpret_cast<const float4*>(&sW[k + kk][tx << 2]);
                #pragma unroll
                for (int r = 0; r < 2; ++r) {
                    float av = f4get(a[r], kk);
                    acc[r].x = fmaf(av, w.x, acc[r].x);
                    acc[r].y = fmaf(av, w.y, acc[r].y);
                    acc[r].z = fmaf(av, w.z, acc[r].z);
                    acc[r].w = fmaf(av, w.w, acc[r].w);
                }
            }
        }
        __syncthreads();
    }
    #pragma unroll
    for (int r = 0; r < 2; ++r) {
        ushort4 o;
        o.x = f2bf(acc[r].x); o.y = f2bf(acc[r].y);
        o.z = f2bf(acc[r].z); o.w = f2bf(acc[r].w);
        *reinterpret_cast<ushort4*>(tb + (size_t)(row0 + ty + r * 16) * 64 + (tx << 2)) = o;
    }
}

// out[N,64](fp32) = A(bf16 [N,128]) @ W(fp32 [128,64]) + agg2 + bias   (lin_r + aggregated lin_l)
__global__ __launch_bounds__(256) void k_gemm2b(const ushort_t* __restrict__ Ab,
                                                const float* __restrict__ W,
                                                const float* __restrict__ agg2,
                                                const float* __restrict__ bias,
                                                float* __restrict__ out) {
    __shared__ float sA[32][32];
    __shared__ float sW[32][64];
    const int tid = threadIdx.x;
    const int tx = tid & 15;
    const int ty = tid >> 4;
    const int row0 = blockIdx.x * 32;
    float4 acc[2];
    acc[0] = make_float4(0.f, 0.f, 0.f, 0.f);
    acc[1] = make_float4(0.f, 0.f, 0.f, 0.f);

    for (int kc = 0; kc < 128; kc += 32) {
        {
            int r = tid >> 3, k4 = (tid & 7) << 2;
            uint2 u = *reinterpret_cast<const uint2*>(Ab + (size_t)(row0 + r) * 128 + kc + k4);
            float4 af;
            af.x = bflo(u.x); af.y = bfhi(u.x); af.z = bflo(u.y); af.w = bfhi(u.y);
            *reinterpret_cast<float4*>(&sA[r][k4]) = af;
        }
        #pragma unroll
        for (int i = 0; i < 2; ++i) {
            int t4 = tid + i * 256;
            int k = t4 >> 4, c = (t4 & 15) << 2;
            *reinterpret_cast<float4*>(&sW[k][c]) =
                *reinterpret_cast<const float4*>(W + (size_t)(kc + k) * 64 + c);
        }
        __syncthreads();
        #pragma unroll
        for (int k = 0; k < 32; k += 4) {
            float4 a[2];
            a[0] = *reinterpret_cast<const float4*>(&sA[ty][k]);
            a[1] = *reinterpret_cast<const float4*>(&sA[ty + 16][k]);
            #pragma unroll
            for (int kk = 0; kk < 4; ++kk) {
                float4 w = *reinterpret_cast<const float4*>(&sW[k + kk][tx << 2]);
                #pragma unroll
                for (int r = 0; r < 2; ++r) {
                    float av = f4get(a[r], kk);
                    acc[r].x = fmaf(av, w.x, acc[r].x);
                    acc[r].y = fmaf(av, w.y, acc[r].y);
                    acc[r].z = fmaf(av, w.z, acc[r].z);
                    acc[r].w = fmaf(av, w.w, acc[r].w);
                }
            }
        }
        __syncthreads();
    }
    float4 bv = *reinterpret_cast<const float4*>(bias + (tx << 2));
    #pragma unroll
    for (int r = 0; r < 2; ++r) {
        float4 g = *reinterpret_cast<const float4*>(agg2 + (size_t)(row0 + ty + r * 16) * 64 + (tx << 2));
        float4 o;
        o.x = acc[r].x + g.x + bv.x;
        o.y = acc[r].y + g.y + bv.y;
        o.z = acc[r].z + g.z + bv.z;
        o.w = acc[r].w + g.w + bv.w;
        *reinterpret_cast<float4*>(out + (size_t)(row0 + ty + r * 16) * 64 + (tx << 2)) = o;
    }
}

// ---------------- in-place log_softmax over 64 classes ----------------

__global__ __launch_bounds__(256) void k_logsm(float* __restrict__ out) {
    int wid = (blockIdx.x * blockDim.x + threadIdx.x) >> 6;
    int lane = threadIdx.x & 63;
    if (wid >= Nn) return;
    float v = out[(size_t)wid * 64 + lane];
    float m = v;
    #pragma unroll
    for (int off = 32; off; off >>= 1) m = fmaxf(m, __shfl_xor(m, off));
    float ex = __expf(v - m);
    float s = ex;
    #pragma unroll
    for (int off = 32; off; off >>= 1) s += __shfl_xor(s, off);
    out[(size_t)wid * 64 + lane] = v - m - __logf(s);
}

// ---------------- launch ----------------

extern "C" void kernel_launch(void* const* d_in, const int* in_sizes, int n_in,
                              void* d_out, int out_size, void* d_ws, size_t ws_size,
                              hipStream_t stream) {
    const float* x   = (const float*)d_in[0];
    const int*   ei  = (const int*)d_in[1];
    const float* W1l = (const float*)d_in[2];
    const float* W1r = (const float*)d_in[3];
    const float* b1  = (const float*)d_in[4];
    const float* W2l = (const float*)d_in[5];
    const float* W2r = (const float*)d_in[6];
    const float* b2  = (const float*)d_in[7];
    float* out = (float*)d_out;

    char* ws = (char*)d_ws;
    int*      deg    = (int*)(ws + 0);            // N ints
    int*      cnt    = (int*)(ws + 400384);       // N ints
    int*      rowptr = (int*)(ws + 800768);       // N+1 ints (16B aligned)
    int*      bsum   = (int*)(ws + 1200896);      // SCAN_NB ints (in rowptr-csr gap)
    int*      csr    = (int*)(ws + 1201152);      // E ints
    ushort_t* xb     = (ushort_t*)(ws + 7601152); // N*128 bf16 (layer-1 gather table)
    float*    agg    = (float*)(ws + 33201152);   // N*128 f32 (layer-1 agg)
    ushort_t* hb     = (ushort_t*)(ws + 84401152);// N*128 bf16 (hidden)
    // aliases (disjoint lifetimes):
    ushort_t* tb     = (ushort_t*)(ws + 7601152); // N*64 bf16 over dead xb
    float*    agg2   = (float*)(ws + 33201152);   // N*64 f32 over dead agg
    // high-water: 84401152 + 25600000 = 110001152 bytes

    const int* src = ei;
    const int* dst = ei + Ee;

    hipMemsetAsync(deg, 0, 800768, stream);   // deg + cnt

    k_count<<<(Ee + 255) / 256, 256, 0, stream>>>(dst, deg);
    k_scan1<<<SCAN_NB, 1024, 0, stream>>>(deg, bsum);
    k_scan2<<<1, 64, 0, stream>>>(bsum, rowptr);
    k_scan3<<<SCAN_NB, 1024, 0, stream>>>(deg, bsum, rowptr);
    k_fill<<<(Ee + 255) / 256, 256, 0, stream>>>(src, dst, rowptr, cnt, csr);

    // layer 1: xb = bf16(x); agg = mean-gather(xb); h = relu(agg@W1l + x@W1r + b1) -> bf16
    k_cvt<<<(Nn * FIN / 4 + 255) / 256, 256, 0, stream>>>(x, xb, Nn * FIN / 4);
    k_agg1<<<(Nn + 3) / 4, 256, 0, stream>>>(xb, rowptr, csr, agg);
    k_gemm1<<<Nn / 32, 256, 0, stream>>>(agg, x, W1l, W1r, b1, hb);

    // layer 2 (reassociated): tb = bf16(h@W2l); agg2 = mean-gather(tb); out = h@W2r + agg2 + b2
    k_gemm2a<<<Nn / 32, 256, 0, stream>>>(hb, W2l, tb);
    k_agg2<<<(Nn + 3) / 4, 256, 0, stream>>>(tb, rowptr, csr, agg2);
    k_gemm2b<<<Nn / 32, 256, 0, stream>>>(hb, W2r, agg2, b2, out);

    k_logsm<<<(Nn + 3) / 4, 256, 0, stream>>>(out);
}

// Round 10
// 463.478 us; speedup vs baseline: 1.7013x; 1.3251x over previous
//
#include <hip/hip_runtime.h>

#define Nn 100000
#define Ee 1600000
#define FIN 128
#define HID 128
#define CLS 64
#define SCAN_NB 25   // ceil(Nn / 4096)

typedef unsigned short ushort_t;
typedef unsigned int uint_t;

__device__ __forceinline__ ushort_t f2bf(float f) {   // RNE fp32->bf16
    uint_t u = __float_as_uint(f);
    return (ushort_t)((u + 0x7fffu + ((u >> 16) & 1u)) >> 16);
}
__device__ __forceinline__ float bflo(uint_t u) { return __uint_as_float(u << 16); }
__device__ __forceinline__ float bfhi(uint_t u) { return __uint_as_float(u & 0xffff0000u); }

// ---------------- CSR build ----------------

__global__ void k_count(const int* __restrict__ dst, int* __restrict__ deg) {
    int e = blockIdx.x * blockDim.x + threadIdx.x;
    if (e < Ee) {
        int d = dst[e];
        if ((unsigned)d < Nn) atomicAdd(&deg[d], 1);
    }
}

// pass 1: per-block (4096 elems) sums
__global__ __launch_bounds__(1024) void k_scan1(const int* __restrict__ deg,
                                                int* __restrict__ bsum) {
    __shared__ int red[16];
    int t = threadIdx.x, b = blockIdx.x;
    int i4 = b * 1024 + t;                  // int4 index; Nn/4 = 25000
    int s = 0;
    if (i4 < Nn / 4) {
        int4 v = reinterpret_cast<const int4*>(deg)[i4];
        s = v.x + v.y + v.z + v.w;
    }
    #pragma unroll
    for (int off = 32; off; off >>= 1) s += __shfl_down(s, off);
    if ((t & 63) == 0) red[t >> 6] = s;
    __syncthreads();
    if (t < 16) {
        int v = red[t];
        #pragma unroll
        for (int off = 8; off; off >>= 1) v += __shfl_down(v, off);
        if (t == 0) bsum[b] = v;
    }
}

// pass 2: exclusive scan of the 25 block sums (tiny, serial)
__global__ void k_scan2(int* __restrict__ bsum, int* __restrict__ rowptr) {
    if (threadIdx.x == 0) {
        int acc = 0;
        for (int b = 0; b < SCAN_NB; ++b) { int v = bsum[b]; bsum[b] = acc; acc += v; }
        rowptr[Nn] = acc;
    }
}

// pass 3: block-level exclusive scan + block offset -> rowptr[0..Nn)
__global__ __launch_bounds__(1024) void k_scan3(const int* __restrict__ deg,
                                                const int* __restrict__ bsum,
                                                int* __restrict__ rowptr) {
    __shared__ int sums[1024];
    int t = threadIdx.x, b = blockIdx.x;
    int i4 = b * 1024 + t;
    int4 v = make_int4(0, 0, 0, 0);
    if (i4 < Nn / 4) v = reinterpret_cast<const int4*>(deg)[i4];
    int s = v.x + v.y + v.z + v.w;
    sums[t] = s;
    __syncthreads();
    for (int off = 1; off < 1024; off <<= 1) {
        int vv = (t >= off) ? sums[t - off] : 0;
        __syncthreads();
        sums[t] += vv;
        __syncthreads();
    }
    int excl = sums[t] - s + bsum[b];
    if (i4 < Nn / 4) {
        int4 o;
        o.x = excl;
        o.y = excl + v.x;
        o.z = excl + v.x + v.y;
        o.w = excl + v.x + v.y + v.z;
        reinterpret_cast<int4*>(rowptr)[i4] = o;
    }
}

__global__ void k_fill(const int* __restrict__ src, const int* __restrict__ dst,
                       const int* __restrict__ rowptr, int* __restrict__ cnt,
                       int* __restrict__ csr) {
    int e = blockIdx.x * blockDim.x + threadIdx.x;
    if (e < Ee) {
        int d = dst[e];
        if ((unsigned)d < Nn) {
            int pos = rowptr[d] + atomicAdd(&cnt[d], 1);
            csr[pos] = src[e];
        }
    }
}

// ---------------- fp32 -> bf16 table conversion ----------------

__global__ __launch_bounds__(256) void k_cvt(const float* __restrict__ in,
                                             ushort_t* __restrict__ outb, int n4) {
    int i = blockIdx.x * blockDim.x + threadIdx.x;
    if (i < n4) {
        float4 v = reinterpret_cast<const float4*>(in)[i];
        ushort4 o;
        o.x = f2bf(v.x); o.y = f2bf(v.y); o.z = f2bf(v.z); o.w = f2bf(v.w);
        reinterpret_cast<ushort4*>(outb)[i] = o;
    }
}

// ---------------- aggregation: bf16 gather, fp32 accumulate ----------------
// Edge loop unrolled x8 with index prefetch: all 8 row-gathers issued
// back-to-back (independent loads in flight) instead of one dependent
// chain per edge. Summation order identical to the serial loop.

// 128-wide table (layer 1): lane covers 2 elems
__global__ __launch_bounds__(256) void k_agg1(const ushort_t* __restrict__ xb,
                                              const int* __restrict__ rowptr,
                                              const int* __restrict__ csr,
                                              float* __restrict__ out) {
    int wid = (blockIdx.x * blockDim.x + threadIdx.x) >> 6;
    int lane = threadIdx.x & 63;
    if (wid >= Nn) return;
    int s0 = rowptr[wid], s1 = rowptr[wid + 1];
    float ax = 0.f, ay = 0.f;
    int e = s0;
    for (; e + 8 <= s1; e += 8) {
        int idx[8];
        #pragma unroll
        for (int j = 0; j < 8; ++j) idx[j] = csr[e + j];
        uint_t u[8];
        #pragma unroll
        for (int j = 0; j < 8; ++j)
            u[j] = *reinterpret_cast<const uint_t*>(xb + (size_t)idx[j] * 128 + lane * 2);
        #pragma unroll
        for (int j = 0; j < 8; ++j) { ax += bflo(u[j]); ay += bfhi(u[j]); }
    }
    for (; e < s1; ++e) {
        int s = csr[e];
        uint_t u = *reinterpret_cast<const uint_t*>(xb + (size_t)s * 128 + lane * 2);
        ax += bflo(u); ay += bfhi(u);
    }
    float invd = (s1 > s0) ? 1.0f / (float)(s1 - s0) : 0.0f;
    float2 o; o.x = ax * invd; o.y = ay * invd;
    *reinterpret_cast<float2*>(out + (size_t)wid * 128 + lane * 2) = o;
}

// 64-wide table (layer 2): lane covers 1 elem
__global__ __launch_bounds__(256) void k_agg2(const ushort_t* __restrict__ tb,
                                              const int* __restrict__ rowptr,
                                              const int* __restrict__ csr,
                                              float* __restrict__ out) {
    int wid = (blockIdx.x * blockDim.x + threadIdx.x) >> 6;
    int lane = threadIdx.x & 63;
    if (wid >= Nn) return;
    int s0 = rowptr[wid], s1 = rowptr[wid + 1];
    float a = 0.f;
    int e = s0;
    for (; e + 8 <= s1; e += 8) {
        int idx[8];
        #pragma unroll
        for (int j = 0; j < 8; ++j) idx[j] = csr[e + j];
        ushort_t u[8];
        #pragma unroll
        for (int j = 0; j < 8; ++j) u[j] = tb[(size_t)idx[j] * 64 + lane];
        #pragma unroll
        for (int j = 0; j < 8; ++j) a += __uint_as_float(((uint_t)u[j]) << 16);
    }
    for (; e < s1; ++e) {
        int s = csr[e];
        a += __uint_as_float(((uint_t)tb[(size_t)s * 64 + lane]) << 16);
    }
    float invd = (s1 > s0) ? 1.0f / (float)(s1 - s0) : 0.0f;
    out[(size_t)wid * 64 + lane] = a * invd;
}

// ---------------- GEMMs ----------------

__device__ __forceinline__ float f4get(const float4 v, int i) {
    return (i == 0) ? v.x : (i == 1) ? v.y : (i == 2) ? v.z : v.w;
}

// hb[N,128](bf16) = relu(A0@W0 + A1@W1 + bias); A0,A1 fp32 [N,128]; W [128,128]
__global__ __launch_bounds__(256) void k_gemm1(const float* __restrict__ A0,
                                               const float* __restrict__ A1,
                                               const float* __restrict__ W0,
                                               const float* __restrict__ W1,
                                               const float* __restrict__ bias,
                                               ushort_t* __restrict__ hb) {
    __shared__ float sA[32][32];
    __shared__ float sW[32][128];
    const int tid = threadIdx.x;
    const int tx = tid & 31;
    const int ty = tid >> 5;
    const int row0 = blockIdx.x * 32;
    float4 acc[4];
    #pragma unroll
    for (int r = 0; r < 4; ++r) acc[r] = make_float4(0.f, 0.f, 0.f, 0.f);

    for (int pair = 0; pair < 2; ++pair) {
        const float* __restrict__ A = pair ? A1 : A0;
        const float* __restrict__ W = pair ? W1 : W0;
        for (int kc = 0; kc < 128; kc += 32) {
            {
                int r = tid >> 3, k4 = (tid & 7) << 2;
                *reinterpret_cast<float4*>(&sA[r][k4]) =
                    *reinterpret_cast<const float4*>(A + (size_t)(row0 + r) * 128 + kc + k4);
            }
            #pragma unroll
            for (int i = 0; i < 4; ++i) {
                int t4 = tid + i * 256;
                int k = t4 >> 5, c = (t4 & 31) << 2;
                *reinterpret_cast<float4*>(&sW[k][c]) =
                    *reinterpret_cast<const float4*>(W + (size_t)(kc + k) * 128 + c);
            }
            __syncthreads();
            #pragma unroll
            for (int k = 0; k < 32; k += 4) {
                float4 a[4];
                #pragma unroll
                for (int r = 0; r < 4; ++r)
                    a[r] = *reinterpret_cast<const float4*>(&sA[ty + r * 8][k]);
                #pragma unroll
                for (int kk = 0; kk < 4; ++kk) {
                    float4 w = *reinterpret_cast<const float4*>(&sW[k + kk][tx << 2]);
                    #pragma unroll
                    for (int r = 0; r < 4; ++r) {
                        float av = f4get(a[r], kk);
                        acc[r].x = fmaf(av, w.x, acc[r].x);
                        acc[r].y = fmaf(av, w.y, acc[r].y);
                        acc[r].z = fmaf(av, w.z, acc[r].z);
                        acc[r].w = fmaf(av, w.w, acc[r].w);
                    }
                }
            }
            __syncthreads();
        }
    }
    float4 bv = *reinterpret_cast<const float4*>(bias + (tx << 2));
    #pragma unroll
    for (int r = 0; r < 4; ++r) {
        ushort4 o;
        o.x = f2bf(fmaxf(acc[r].x + bv.x, 0.f));
        o.y = f2bf(fmaxf(acc[r].y + bv.y, 0.f));
        o.z = f2bf(fmaxf(acc[r].z + bv.z, 0.f));
        o.w = f2bf(fmaxf(acc[r].w + bv.w, 0.f));
        *reinterpret_cast<ushort4*>(hb + (size_t)(row0 + ty + r * 8) * 128 + (tx << 2)) = o;
    }
}

// tb[N,64](bf16) = A(bf16 [N,128]) @ W(fp32 [128,64])   (lin_l projection, pre-aggregation)
__global__ __launch_bounds__(256) void k_gemm2a(const ushort_t* __restrict__ Ab,
                                                const float* __restrict__ W,
                                                ushort_t* __restrict__ tb) {
    __shared__ float sA[32][32];
    __shared__ float sW[32][64];
    const int tid = threadIdx.x;
    const int tx = tid & 15;
    const int ty = tid >> 4;
    const int row0 = blockIdx.x * 32;
    float4 acc[2];
    acc[0] = make_float4(0.f, 0.f, 0.f, 0.f);
    acc[1] = make_float4(0.f, 0.f, 0.f, 0.f);

    for (int kc = 0; kc < 128; kc += 32) {
        {
            int r = tid >> 3, k4 = (tid & 7) << 2;
            uint2 u = *reinterpret_cast<const uint2*>(Ab + (size_t)(row0 + r) * 128 + kc + k4);
            float4 af;
            af.x = bflo(u.x); af.y = bfhi(u.x); af.z = bflo(u.y); af.w = bfhi(u.y);
            *reinterpret_cast<float4*>(&sA[r][k4]) = af;
        }
        #pragma unroll
        for (int i = 0; i < 2; ++i) {
            int t4 = tid + i * 256;
            int k = t4 >> 4, c = (t4 & 15) << 2;
            *reinterpret_cast<float4*>(&sW[k][c]) =
                *reinterpret_cast<const float4*>(W + (size_t)(kc + k) * 64 + c);
        }
        __syncthreads();
        #pragma unroll
        for (int k = 0; k < 32; k += 4) {
            float4 a[2];
            a[0] = *reinterpret_cast<const float4*>(&sA[ty][k]);
            a[1] = *reinterpret_cast<const float4*>(&sA[ty + 16][k]);
            #pragma unroll
            for (int kk = 0; kk < 4; ++kk) {
                float4 w = *reinterpret_cast<const float4*>(&sW[k + kk][tx << 2]);
                #pragma unroll
                for (int r = 0; r < 2; ++r) {
                    float av = f4get(a[r], kk);
                    acc[r].x = fmaf(av, w.x, acc[r].x);
                    acc[r].y = fmaf(av, w.y, acc[r].y);
                    acc[r].z = fmaf(av, w.z, acc[r].z);
                    acc[r].w = fmaf(av, w.w, acc[r].w);
                }
            }
        }
        __syncthreads();
    }
    #pragma unroll
    for (int r = 0; r < 2; ++r) {
        ushort4 o;
        o.x = f2bf(acc[r].x); o.y = f2bf(acc[r].y);
        o.z = f2bf(acc[r].z); o.w = f2bf(acc[r].w);
        *reinterpret_cast<ushort4*>(tb + (size_t)(row0 + ty + r * 16) * 64 + (tx << 2)) = o;
    }
}

// out[N,64](fp32) = A(bf16 [N,128]) @ W(fp32 [128,64]) + agg2 + bias   (lin_r + aggregated lin_l)
__global__ __launch_bounds__(256) void k_gemm2b(const ushort_t* __restrict__ Ab,
                                                const float* __restrict__ W,
                                                const float* __restrict__ agg2,
                                                const float* __restrict__ bias,
                                                float* __restrict__ out) {
    __shared__ float sA[32][32];
    __shared__ float sW[32][64];
    const int tid = threadIdx.x;
    const int tx = tid & 15;
    const int ty = tid >> 4;
    const int row0 = blockIdx.x * 32;
    float4 acc[2];
    acc[0] = make_float4(0.f, 0.f, 0.f, 0.f);
    acc[1] = make_float4(0.f, 0.f, 0.f, 0.f);

    for (int kc = 0; kc < 128; kc += 32) {
        {
            int r = tid >> 3, k4 = (tid & 7) << 2;
            uint2 u = *reinterpret_cast<const uint2*>(Ab + (size_t)(row0 + r) * 128 + kc + k4);
            float4 af;
            af.x = bflo(u.x); af.y = bfhi(u.x); af.z = bflo(u.y); af.w = bfhi(u.y);
            *reinterpret_cast<float4*>(&sA[r][k4]) = af;
        }
        #pragma unroll
        for (int i = 0; i < 2; ++i) {
            int t4 = tid + i * 256;
            int k = t4 >> 4, c = (t4 & 15) << 2;
            *reinterpret_cast<float4*>(&sW[k][c]) =
                *reinterpret_cast<const float4*>(W + (size_t)(kc + k) * 64 + c);
        }
        __syncthreads();
        #pragma unroll
        for (int k = 0; k < 32; k += 4) {
            float4 a[2];
            a[0] = *reinterpret_cast<const float4*>(&sA[ty][k]);
            a[1] = *reinterpret_cast<const float4*>(&sA[ty + 16][k]);
            #pragma unroll
            for (int kk = 0; kk < 4; ++kk) {
                float4 w = *reinterpret_cast<const float4*>(&sW[k + kk][tx << 2]);
                #pragma unroll
                for (int r = 0; r < 2; ++r) {
                    float av = f4get(a[r], kk);
                    acc[r].x = fmaf(av, w.x, acc[r].x);
                    acc[r].y = fmaf(av, w.y, acc[r].y);
                    acc[r].z = fmaf(av, w.z, acc[r].z);
                    acc[r].w = fmaf(av, w.w, acc[r].w);
                }
            }
        }
        __syncthreads();
    }
    float4 bv = *reinterpret_cast<const float4*>(bias + (tx << 2));
    #pragma unroll
    for (int r = 0; r < 2; ++r) {
        float4 g = *reinterpret_cast<const float4*>(agg2 + (size_t)(row0 + ty + r * 16) * 64 + (tx << 2));
        float4 o;
        o.x = acc[r].x + g.x + bv.x;
        o.y = acc[r].y + g.y + bv.y;
        o.z = acc[r].z + g.z + bv.z;
        o.w = acc[r].w + g.w + bv.w;
        *reinterpret_cast<float4*>(out + (size_t)(row0 + ty + r * 16) * 64 + (tx << 2)) = o;
    }
}

// ---------------- in-place log_softmax over 64 classes ----------------

__global__ __launch_bounds__(256) void k_logsm(float* __restrict__ out) {
    int wid = (blockIdx.x * blockDim.x + threadIdx.x) >> 6;
    int lane = threadIdx.x & 63;
    if (wid >= Nn) return;
    float v = out[(size_t)wid * 64 + lane];
    float m = v;
    #pragma unroll
    for (int off = 32; off; off >>= 1) m = fmaxf(m, __shfl_xor(m, off));
    float ex = __expf(v - m);
    float s = ex;
    #pragma unroll
    for (int off = 32; off; off >>= 1) s += __shfl_xor(s, off);
    out[(size_t)wid * 64 + lane] = v - m - __logf(s);
}

// ---------------- launch ----------------

extern "C" void kernel_launch(void* const* d_in, const int* in_sizes, int n_in,
                              void* d_out, int out_size, void* d_ws, size_t ws_size,
                              hipStream_t stream) {
    const float* x   = (const float*)d_in[0];
    const int*   ei  = (const int*)d_in[1];
    const float* W1l = (const float*)d_in[2];
    const float* W1r = (const float*)d_in[3];
    const float* b1  = (const float*)d_in[4];
    const float* W2l = (const float*)d_in[5];
    const float* W2r = (const float*)d_in[6];
    const float* b2  = (const float*)d_in[7];
    float* out = (float*)d_out;

    char* ws = (char*)d_ws;
    int*      deg    = (int*)(ws + 0);            // N ints
    int*      cnt    = (int*)(ws + 400384);       // N ints
    int*      rowptr = (int*)(ws + 800768);       // N+1 ints (16B aligned)
    int*      bsum   = (int*)(ws + 1200896);      // SCAN_NB ints (in rowptr-csr gap)
    int*      csr    = (int*)(ws + 1201152);      // E ints
    ushort_t* xb     = (ushort_t*)(ws + 7601152); // N*128 bf16 (layer-1 gather table)
    float*    agg    = (float*)(ws + 33201152);   // N*128 f32 (layer-1 agg)
    ushort_t* hb     = (ushort_t*)(ws + 84401152);// N*128 bf16 (hidden)
    // aliases (disjoint lifetimes):
    ushort_t* tb     = (ushort_t*)(ws + 7601152); // N*64 bf16 over dead xb
    float*    agg2   = (float*)(ws + 33201152);   // N*64 f32 over dead agg
    // high-water: 84401152 + 25600000 = 110001152 bytes

    const int* src = ei;
    const int* dst = ei + Ee;

    hipMemsetAsync(deg, 0, 800768, stream);   // deg + cnt

    k_count<<<(Ee + 255) / 256, 256, 0, stream>>>(dst, deg);
    k_scan1<<<SCAN_NB, 1024, 0, stream>>>(deg, bsum);
    k_scan2<<<1, 64, 0, stream>>>(bsum, rowptr);
    k_scan3<<<SCAN_NB, 1024, 0, stream>>>(deg, bsum, rowptr);
    k_fill<<<(Ee + 255) / 256, 256, 0, stream>>>(src, dst, rowptr, cnt, csr);

    // layer 1: xb = bf16(x); agg = mean-gather(xb); h = relu(agg@W1l + x@W1r + b1) -> bf16
    k_cvt<<<(Nn * FIN / 4 + 255) / 256, 256, 0, stream>>>(x, xb, Nn * FIN / 4);
    k_agg1<<<(Nn + 3) / 4, 256, 0, stream>>>(xb, rowptr, csr, agg);
    k_gemm1<<<Nn / 32, 256, 0, stream>>>(agg, x, W1l, W1r, b1, hb);

    // layer 2 (reassociated): tb = bf16(h@W2l); agg2 = mean-gather(tb); out = h@W2r + agg2 + b2
    k_gemm2a<<<Nn / 32, 256, 0, stream>>>(hb, W2l, tb);
    k_agg2<<<(Nn + 3) / 4, 256, 0, stream>>>(tb, rowptr, csr, agg2);
    k_gemm2b<<<Nn / 32, 256, 0, stream>>>(hb, W2r, agg2, b2, out);

    k_logsm<<<(Nn + 3) / 4, 256, 0, stream>>>(out);
}

// Round 11
// 458.174 us; speedup vs baseline: 1.7210x; 1.0116x over previous
//
#include <hip/hip_runtime.h>

#define Nn 100000
#define Ee 1600000
#define FIN 128
#define HID 128
#define CLS 64
#define SCAN_NB 25   // ceil(Nn / 4096)

typedef unsigned short ushort_t;
typedef unsigned int uint_t;
typedef __attribute__((ext_vector_type(8))) short bf16x8;
typedef __attribute__((ext_vector_type(4))) float f32x4;

__device__ __forceinline__ ushort_t f2bf(float f) {   // RNE fp32->bf16
    uint_t u = __float_as_uint(f);
    return (ushort_t)((u + 0x7fffu + ((u >> 16) & 1u)) >> 16);
}
__device__ __forceinline__ float bflo(uint_t u) { return __uint_as_float(u << 16); }
__device__ __forceinline__ float bfhi(uint_t u) { return __uint_as_float(u & 0xffff0000u); }

// ---------------- CSR build ----------------

__global__ void k_count(const int* __restrict__ dst, int* __restrict__ deg) {
    int e = blockIdx.x * blockDim.x + threadIdx.x;
    if (e < Ee) {
        int d = dst[e];
        if ((unsigned)d < Nn) atomicAdd(&deg[d], 1);
    }
}

__global__ __launch_bounds__(1024) void k_scan1(const int* __restrict__ deg,
                                                int* __restrict__ bsum) {
    __shared__ int red[16];
    int t = threadIdx.x, b = blockIdx.x;
    int i4 = b * 1024 + t;
    int s = 0;
    if (i4 < Nn / 4) {
        int4 v = reinterpret_cast<const int4*>(deg)[i4];
        s = v.x + v.y + v.z + v.w;
    }
    #pragma unroll
    for (int off = 32; off; off >>= 1) s += __shfl_down(s, off);
    if ((t & 63) == 0) red[t >> 6] = s;
    __syncthreads();
    if (t < 16) {
        int v = red[t];
        #pragma unroll
        for (int off = 8; off; off >>= 1) v += __shfl_down(v, off);
        if (t == 0) bsum[b] = v;
    }
}

__global__ void k_scan2(int* __restrict__ bsum, int* __restrict__ rowptr) {
    if (threadIdx.x == 0) {
        int acc = 0;
        for (int b = 0; b < SCAN_NB; ++b) { int v = bsum[b]; bsum[b] = acc; acc += v; }
        rowptr[Nn] = acc;
    }
}

__global__ __launch_bounds__(1024) void k_scan3(const int* __restrict__ deg,
                                                const int* __restrict__ bsum,
                                                int* __restrict__ rowptr) {
    __shared__ int sums[1024];
    int t = threadIdx.x, b = blockIdx.x;
    int i4 = b * 1024 + t;
    int4 v = make_int4(0, 0, 0, 0);
    if (i4 < Nn / 4) v = reinterpret_cast<const int4*>(deg)[i4];
    int s = v.x + v.y + v.z + v.w;
    sums[t] = s;
    __syncthreads();
    for (int off = 1; off < 1024; off <<= 1) {
        int vv = (t >= off) ? sums[t - off] : 0;
        __syncthreads();
        sums[t] += vv;
        __syncthreads();
    }
    int excl = sums[t] - s + bsum[b];
    if (i4 < Nn / 4) {
        int4 o;
        o.x = excl;
        o.y = excl + v.x;
        o.z = excl + v.x + v.y;
        o.w = excl + v.x + v.y + v.z;
        reinterpret_cast<int4*>(rowptr)[i4] = o;
    }
}

__global__ void k_fill(const int* __restrict__ src, const int* __restrict__ dst,
                       const int* __restrict__ rowptr, int* __restrict__ cnt,
                       int* __restrict__ csr) {
    int e = blockIdx.x * blockDim.x + threadIdx.x;
    if (e < Ee) {
        int d = dst[e];
        if ((unsigned)d < Nn) {
            int pos = rowptr[d] + atomicAdd(&cnt[d], 1);
            csr[pos] = src[e];
        }
    }
}

// ---------------- conversions ----------------

__global__ __launch_bounds__(256) void k_cvt(const float* __restrict__ in,
                                             ushort_t* __restrict__ outb, int n4) {
    int i = blockIdx.x * blockDim.x + threadIdx.x;
    if (i < n4) {
        float4 v = reinterpret_cast<const float4*>(in)[i];
        ushort4 o;
        o.x = f2bf(v.x); o.y = f2bf(v.y); o.z = f2bf(v.z); o.w = f2bf(v.w);
        reinterpret_cast<ushort4*>(outb)[i] = o;
    }
}

// W [K=128][Ncols] f32 row-major -> Wt [Ncols][128] bf16 (col-major of W)
__global__ __launch_bounds__(256) void k_cvtw(const float* __restrict__ W,
                                              ushort_t* __restrict__ Wt, int Ncols) {
    int i = blockIdx.x * blockDim.x + threadIdx.x;
    if (i < 128 * Ncols) {
        int k = i / Ncols, n = i % Ncols;
        Wt[(size_t)n * 128 + k] = f2bf(W[i]);
    }
}

// ---------------- aggregation: bf16 gather, fp32 accumulate, x8 prefetch ----------------

// 128-wide table (layer 1): lane covers 2 elems; bf16 output
__global__ __launch_bounds__(256) void k_agg1(const ushort_t* __restrict__ xb,
                                              const int* __restrict__ rowptr,
                                              const int* __restrict__ csr,
                                              ushort_t* __restrict__ outb) {
    int wid = (blockIdx.x * blockDim.x + threadIdx.x) >> 6;
    int lane = threadIdx.x & 63;
    if (wid >= Nn) return;
    int s0 = rowptr[wid], s1 = rowptr[wid + 1];
    float ax = 0.f, ay = 0.f;
    int e = s0;
    for (; e + 8 <= s1; e += 8) {
        int idx[8];
        #pragma unroll
        for (int j = 0; j < 8; ++j) idx[j] = csr[e + j];
        uint_t u[8];
        #pragma unroll
        for (int j = 0; j < 8; ++j)
            u[j] = *reinterpret_cast<const uint_t*>(xb + (size_t)idx[j] * 128 + lane * 2);
        #pragma unroll
        for (int j = 0; j < 8; ++j) { ax += bflo(u[j]); ay += bfhi(u[j]); }
    }
    for (; e < s1; ++e) {
        int s = csr[e];
        uint_t u = *reinterpret_cast<const uint_t*>(xb + (size_t)s * 128 + lane * 2);
        ax += bflo(u); ay += bfhi(u);
    }
    float invd = (s1 > s0) ? 1.0f / (float)(s1 - s0) : 0.0f;
    uint_t o = (uint_t)f2bf(ax * invd) | ((uint_t)f2bf(ay * invd) << 16);
    *reinterpret_cast<uint_t*>(outb + (size_t)wid * 128 + lane * 2) = o;
}

// 64-wide table (layer 2): lane covers 1 elem; fp32 output
__global__ __launch_bounds__(256) void k_agg2(const ushort_t* __restrict__ tb,
                                              const int* __restrict__ rowptr,
                                              const int* __restrict__ csr,
                                              float* __restrict__ out) {
    int wid = (blockIdx.x * blockDim.x + threadIdx.x) >> 6;
    int lane = threadIdx.x & 63;
    if (wid >= Nn) return;
    int s0 = rowptr[wid], s1 = rowptr[wid + 1];
    float a = 0.f;
    int e = s0;
    for (; e + 8 <= s1; e += 8) {
        int idx[8];
        #pragma unroll
        for (int j = 0; j < 8; ++j) idx[j] = csr[e + j];
        ushort_t u[8];
        #pragma unroll
        for (int j = 0; j < 8; ++j) u[j] = tb[(size_t)idx[j] * 64 + lane];
        #pragma unroll
        for (int j = 0; j < 8; ++j) a += __uint_as_float(((uint_t)u[j]) << 16);
    }
    for (; e < s1; ++e) {
        int s = csr[e];
        a += __uint_as_float(((uint_t)tb[(size_t)s * 64 + lane]) << 16);
    }
    float invd = (s1 > s0) ? 1.0f / (float)(s1 - s0) : 0.0f;
    out[(size_t)wid * 64 + lane] = a * invd;
}

// ---------------- MFMA GEMMs (16x16x32 bf16) ----------------
// A-frag: lane holds A[row0 + (lane&15)][ks*32 + (lane>>4)*8 .. +7]  (16B load)
// B-frag: lane holds W[k][col] = Wt[col][k]: Wt[c*16+(lane&15)][ks*32+(lane>>4)*8 ..]
// D: col = lane&15, row = (lane>>4)*4 + reg   [verified layout]

// hb[N,128](bf16) = relu(A0@W0 + A1@W1 + b); A0,A1 [N,128] bf16; Wt [128][128] bf16
__global__ __launch_bounds__(256) void k_gemm1m(const ushort_t* __restrict__ Ab0,
                                                const ushort_t* __restrict__ Ab1,
                                                const ushort_t* __restrict__ Wt0,
                                                const ushort_t* __restrict__ Wt1,
                                                const float* __restrict__ bias,
                                                ushort_t* __restrict__ hb) {
    int gw = (blockIdx.x * 256 + threadIdx.x) >> 6;
    int lane = threadIdx.x & 63;
    if (gw >= Nn / 16) return;
    int row0 = gw * 16;
    int r = lane & 15;
    int kg = lane >> 4;
    f32x4 acc[8];
    #pragma unroll
    for (int c = 0; c < 8; ++c) acc[c] = (f32x4){0.f, 0.f, 0.f, 0.f};
    #pragma unroll
    for (int pair = 0; pair < 2; ++pair) {
        const ushort_t* A  = pair ? Ab1 : Ab0;
        const ushort_t* Wt = pair ? Wt1 : Wt0;
        #pragma unroll
        for (int ks = 0; ks < 4; ++ks) {
            int kbase = ks * 32 + kg * 8;
            bf16x8 af = *reinterpret_cast<const bf16x8*>(A + (size_t)(row0 + r) * 128 + kbase);
            #pragma unroll
            for (int c = 0; c < 8; ++c) {
                bf16x8 bf = *reinterpret_cast<const bf16x8*>(Wt + (size_t)(c * 16 + r) * 128 + kbase);
                acc[c] = __builtin_amdgcn_mfma_f32_16x16x32_bf16(af, bf, acc[c], 0, 0, 0);
            }
        }
    }
    #pragma unroll
    for (int c = 0; c < 8; ++c) {
        float bv = bias[c * 16 + r];
        #pragma unroll
        for (int i = 0; i < 4; ++i) {
            int row = row0 + kg * 4 + i;
            hb[(size_t)row * 128 + c * 16 + r] = f2bf(fmaxf(acc[c][i] + bv, 0.f));
        }
    }
}

// tb[N,64](bf16) = A@Wt   (lin_l projection, pre-aggregation)
__global__ __launch_bounds__(256) void k_gemm2am(const ushort_t* __restrict__ Ab,
                                                 const ushort_t* __restrict__ Wt,
                                                 ushort_t* __restrict__ tb) {
    int gw = (blockIdx.x * 256 + threadIdx.x) >> 6;
    int lane = threadIdx.x & 63;
    if (gw >= Nn / 16) return;
    int row0 = gw * 16;
    int r = lane & 15;
    int kg = lane >> 4;
    f32x4 acc[4];
    #pragma unroll
    for (int c = 0; c < 4; ++c) acc[c] = (f32x4){0.f, 0.f, 0.f, 0.f};
    #pragma unroll
    for (int ks = 0; ks < 4; ++ks) {
        int kbase = ks * 32 + kg * 8;
        bf16x8 af = *reinterpret_cast<const bf16x8*>(Ab + (size_t)(row0 + r) * 128 + kbase);
        #pragma unroll
        for (int c = 0; c < 4; ++c) {
            bf16x8 bf = *reinterpret_cast<const bf16x8*>(Wt + (size_t)(c * 16 + r) * 128 + kbase);
            acc[c] = __builtin_amdgcn_mfma_f32_16x16x32_bf16(af, bf, acc[c], 0, 0, 0);
        }
    }
    #pragma unroll
    for (int c = 0; c < 4; ++c) {
        #pragma unroll
        for (int i = 0; i < 4; ++i) {
            int row = row0 + kg * 4 + i;
            tb[(size_t)row * 64 + c * 16 + r] = f2bf(acc[c][i]);
        }
    }
}

// out[N,64](fp32) = A@Wt + agg2 + bias
__global__ __launch_bounds__(256) void k_gemm2bm(const ushort_t* __restrict__ Ab,
                                                 const ushort_t* __restrict__ Wt,
                                                 const float* __restrict__ agg2,
                                                 const float* __restrict__ bias,
                                                 float* __restrict__ out) {
    int gw = (blockIdx.x * 256 + threadIdx.x) >> 6;
    int lane = threadIdx.x & 63;
    if (gw >= Nn / 16) return;
    int row0 = gw * 16;
    int r = lane & 15;
    int kg = lane >> 4;
    f32x4 acc[4];
    #pragma unroll
    for (int c = 0; c < 4; ++c) acc[c] = (f32x4){0.f, 0.f, 0.f, 0.f};
    #pragma unroll
    for (int ks = 0; ks < 4; ++ks) {
        int kbase = ks * 32 + kg * 8;
        bf16x8 af = *reinterpret_cast<const bf16x8*>(Ab + (size_t)(row0 + r) * 128 + kbase);
        #pragma unroll
        for (int c = 0; c < 4; ++c) {
            bf16x8 bf = *reinterpret_cast<const bf16x8*>(Wt + (size_t)(c * 16 + r) * 128 + kbase);
            acc[c] = __builtin_amdgcn_mfma_f32_16x16x32_bf16(af, bf, acc[c], 0, 0, 0);
        }
    }
    #pragma unroll
    for (int c = 0; c < 4; ++c) {
        float bv = bias[c * 16 + r];
        #pragma unroll
        for (int i = 0; i < 4; ++i) {
            int row = row0 + kg * 4 + i;
            size_t o = (size_t)row * 64 + c * 16 + r;
            out[o] = acc[c][i] + agg2[o] + bv;
        }
    }
}

// ---------------- in-place log_softmax over 64 classes ----------------

__global__ __launch_bounds__(256) void k_logsm(float* __restrict__ out) {
    int wid = (blockIdx.x * blockDim.x + threadIdx.x) >> 6;
    int lane = threadIdx.x & 63;
    if (wid >= Nn) return;
    float v = out[(size_t)wid * 64 + lane];
    float m = v;
    #pragma unroll
    for (int off = 32; off; off >>= 1) m = fmaxf(m, __shfl_xor(m, off));
    float ex = __expf(v - m);
    float s = ex;
    #pragma unroll
    for (int off = 32; off; off >>= 1) s += __shfl_xor(s, off);
    out[(size_t)wid * 64 + lane] = v - m - __logf(s);
}

// ---------------- launch ----------------

extern "C" void kernel_launch(void* const* d_in, const int* in_sizes, int n_in,
                              void* d_out, int out_size, void* d_ws, size_t ws_size,
                              hipStream_t stream) {
    const float* x   = (const float*)d_in[0];
    const int*   ei  = (const int*)d_in[1];
    const float* W1l = (const float*)d_in[2];
    const float* W1r = (const float*)d_in[3];
    const float* b1  = (const float*)d_in[4];
    const float* W2l = (const float*)d_in[5];
    const float* W2r = (const float*)d_in[6];
    const float* b2  = (const float*)d_in[7];
    float* out = (float*)d_out;

    char* ws = (char*)d_ws;
    int*      deg    = (int*)(ws + 0);             // N ints
    int*      cnt    = (int*)(ws + 400384);        // N ints
    int*      rowptr = (int*)(ws + 800768);        // N+1 ints
    int*      bsum   = (int*)(ws + 1200896);       // SCAN_NB ints
    int*      csr    = (int*)(ws + 1201152);       // E ints -> ends 7601152
    ushort_t* xb     = (ushort_t*)(ws + 7601152);  // N*128 bf16 -> ends 33201152
    ushort_t* aggb   = (ushort_t*)(ws + 33201152); // N*128 bf16 -> ends 58801152
    ushort_t* w1lt   = (ushort_t*)(ws + 58801152); // 128*128 bf16 (32KB)
    ushort_t* w1rt   = (ushort_t*)(ws + 58833920);
    ushort_t* w2lt   = (ushort_t*)(ws + 58866688); // 64*128 bf16 (16KB)
    ushort_t* w2rt   = (ushort_t*)(ws + 58883072); // ends 58899456
    ushort_t* hb     = (ushort_t*)(ws + 84401152); // N*128 bf16 -> ends 110001152
    // aliases (disjoint lifetimes; xb+aggb dead after k_gemm1m):
    ushort_t* tb     = (ushort_t*)(ws + 7601152);  // N*64 bf16 -> ends 20401152
    float*    agg2   = (float*)(ws + 20401152);    // N*64 f32  -> ends 46001152
    // high-water: 110001152 bytes

    const int* src = ei;
    const int* dst = ei + Ee;

    hipMemsetAsync(deg, 0, 800768, stream);   // deg + cnt

    k_count<<<(Ee + 255) / 256, 256, 0, stream>>>(dst, deg);
    k_scan1<<<SCAN_NB, 1024, 0, stream>>>(deg, bsum);
    k_scan2<<<1, 64, 0, stream>>>(bsum, rowptr);
    k_scan3<<<SCAN_NB, 1024, 0, stream>>>(deg, bsum, rowptr);
    k_fill<<<(Ee + 255) / 256, 256, 0, stream>>>(src, dst, rowptr, cnt, csr);

    // conversions
    k_cvt<<<(Nn * FIN / 4 + 255) / 256, 256, 0, stream>>>(x, xb, Nn * FIN / 4);
    k_cvtw<<<64, 256, 0, stream>>>(W1l, w1lt, 128);
    k_cvtw<<<64, 256, 0, stream>>>(W1r, w1rt, 128);
    k_cvtw<<<32, 256, 0, stream>>>(W2l, w2lt, 64);
    k_cvtw<<<32, 256, 0, stream>>>(W2r, w2rt, 64);

    // layer 1: aggb = bf16(mean-gather(xb)); hb = bf16(relu(aggb@W1l + xb@W1r + b1))
    k_agg1<<<(Nn + 3) / 4, 256, 0, stream>>>(xb, rowptr, csr, aggb);
    k_gemm1m<<<(Nn / 16 + 3) / 4, 256, 0, stream>>>(aggb, xb, w1lt, w1rt, b1, hb);

    // layer 2 (reassociated): tb = bf16(hb@W2l); agg2 = mean-gather(tb); out = hb@W2r + agg2 + b2
    k_gemm2am<<<(Nn / 16 + 3) / 4, 256, 0, stream>>>(hb, w2lt, tb);
    k_agg2<<<(Nn + 3) / 4, 256, 0, stream>>>(tb, rowptr, csr, agg2);
    k_gemm2bm<<<(Nn / 16 + 3) / 4, 256, 0, stream>>>(hb, w2rt, agg2, b2, out);

    k_logsm<<<(Nn + 3) / 4, 256, 0, stream>>>(out);
}

// Round 12
// 416.922 us; speedup vs baseline: 1.8913x; 1.0989x over previous
//
#include <hip/hip_runtime.h>

#define Nn 100000
#define Ee 1600000
#define FIN 128
#define HID 128
#define CLS 64
#define SCAN_NB 25   // ceil(Nn / 4096)
#define NB 196       // dst buckets of 512 nodes (dst>>9)

typedef unsigned short ushort_t;
typedef unsigned int uint_t;
typedef __attribute__((ext_vector_type(8))) short bf16x8;
typedef __attribute__((ext_vector_type(4))) float f32x4;

__device__ __forceinline__ ushort_t f2bf(float f) {   // RNE fp32->bf16
    uint_t u = __float_as_uint(f);
    return (ushort_t)((u + 0x7fffu + ((u >> 16) & 1u)) >> 16);
}
__device__ __forceinline__ float bflo(uint_t u) { return __uint_as_float(u << 16); }
__device__ __forceinline__ float bfhi(uint_t u) { return __uint_as_float(u & 0xffff0000u); }

// ---------------- degree count + rowptr scan ----------------

__global__ void k_count(const int* __restrict__ dst, int* __restrict__ deg) {
    int e = blockIdx.x * blockDim.x + threadIdx.x;
    if (e < Ee) {
        int d = dst[e];
        if ((unsigned)d < Nn) atomicAdd(&deg[d], 1);
    }
}

__global__ __launch_bounds__(1024) void k_scan1(const int* __restrict__ deg,
                                                int* __restrict__ bsum) {
    __shared__ int red[16];
    int t = threadIdx.x, b = blockIdx.x;
    int i4 = b * 1024 + t;
    int s = 0;
    if (i4 < Nn / 4) {
        int4 v = reinterpret_cast<const int4*>(deg)[i4];
        s = v.x + v.y + v.z + v.w;
    }
    #pragma unroll
    for (int off = 32; off; off >>= 1) s += __shfl_down(s, off);
    if ((t & 63) == 0) red[t >> 6] = s;
    __syncthreads();
    if (t < 16) {
        int v = red[t];
        #pragma unroll
        for (int off = 8; off; off >>= 1) v += __shfl_down(v, off);
        if (t == 0) bsum[b] = v;
    }
}

__global__ void k_scan2(int* __restrict__ bsum, int* __restrict__ rowptr) {
    if (threadIdx.x == 0) {
        int acc = 0;
        for (int b = 0; b < SCAN_NB; ++b) { int v = bsum[b]; bsum[b] = acc; acc += v; }
        rowptr[Nn] = acc;
    }
}

__global__ __launch_bounds__(1024) void k_scan3(const int* __restrict__ deg,
                                                const int* __restrict__ bsum,
                                                int* __restrict__ rowptr) {
    __shared__ int sums[1024];
    int t = threadIdx.x, b = blockIdx.x;
    int i4 = b * 1024 + t;
    int4 v = make_int4(0, 0, 0, 0);
    if (i4 < Nn / 4) v = reinterpret_cast<const int4*>(deg)[i4];
    int s = v.x + v.y + v.z + v.w;
    sums[t] = s;
    __syncthreads();
    for (int off = 1; off < 1024; off <<= 1) {
        int vv = (t >= off) ? sums[t - off] : 0;
        __syncthreads();
        sums[t] += vv;
        __syncthreads();
    }
    int excl = sums[t] - s + bsum[b];
    if (i4 < Nn / 4) {
        int4 o;
        o.x = excl;
        o.y = excl + v.x;
        o.z = excl + v.x + v.y;
        o.w = excl + v.x + v.y + v.z;
        reinterpret_cast<int4*>(rowptr)[i4] = o;
    }
}

// ---------------- bucketed CSR fill (kills scatter write-amplification) ----------------

// pass A: bucket histogram (LDS-staged)
__global__ __launch_bounds__(1024) void k_bhist(const int* __restrict__ dst,
                                                int* __restrict__ bcnt) {
    __shared__ int h[NB];
    int t = threadIdx.x;
    if (t < NB) h[t] = 0;
    __syncthreads();
    int base = blockIdx.x * 8192;
    #pragma unroll
    for (int it = 0; it < 8; ++it) {
        int e = base + it * 1024 + t;
        if (e < Ee) atomicAdd(&h[dst[e] >> 9], 1);
    }
    __syncthreads();
    if (t < NB && h[t]) atomicAdd(&bcnt[t], h[t]);
}

// pass B: exclusive scan of 196 bucket counts
__global__ __launch_bounds__(256) void k_bscan(const int* __restrict__ bcnt,
                                               int* __restrict__ bstart,
                                               int* __restrict__ bcur) {
    __shared__ int s[256];
    int t = threadIdx.x;
    int v = (t < NB) ? bcnt[t] : 0;
    s[t] = v;
    __syncthreads();
    for (int off = 1; off < 256; off <<= 1) {
        int u = (t >= off) ? s[t - off] : 0;
        __syncthreads();
        s[t] += u;
        __syncthreads();
    }
    int excl = s[t] - v;
    if (t < NB) { bstart[t] = excl; bcur[t] = excl; }
    if (t == NB - 1) bstart[NB] = excl + v;
}

// pass C: scatter (src,dst) into bucket-contiguous bedge (block-reserved ranges)
__global__ __launch_bounds__(1024) void k_bscatter(const int* __restrict__ src,
                                                   const int* __restrict__ dst,
                                                   int* __restrict__ bcur,
                                                   uint2* __restrict__ bedge) {
    __shared__ int h[NB];
    __shared__ int lbase[NB];
    int t = threadIdx.x;
    if (t < NB) h[t] = 0;
    __syncthreads();
    int base = blockIdx.x * 8192;
    int bk[8], loc[8];
    #pragma unroll
    for (int it = 0; it < 8; ++it) {
        int e = base + it * 1024 + t;
        if (e < Ee) {
            bk[it] = dst[e] >> 9;
            loc[it] = atomicAdd(&h[bk[it]], 1);
        }
    }
    __syncthreads();
    if (t < NB && h[t]) lbase[t] = atomicAdd(&bcur[t], h[t]);
    __syncthreads();
    #pragma unroll
    for (int it = 0; it < 8; ++it) {
        int e = base + it * 1024 + t;
        if (e < Ee)
            bedge[lbase[bk[it]] + loc[it]] = make_uint2((uint_t)src[e], (uint_t)dst[e]);
    }
}

// pass D: per-bucket CSR fill; bucket's csr window (~32KB) stays cache-resident
__global__ __launch_bounds__(1024) void k_fill2(const uint2* __restrict__ bedge,
                                                const int* __restrict__ bstart,
                                                const int* __restrict__ rowptr,
                                                int* __restrict__ cnt,
                                                int* __restrict__ csr) {
    int b = blockIdx.x;
    int s0 = bstart[b], s1 = bstart[b + 1];
    for (int i = s0 + threadIdx.x; i < s1; i += 1024) {
        uint2 ed = bedge[i];
        int d = (int)ed.y;
        int pos = rowptr[d] + atomicAdd(&cnt[d], 1);
        csr[pos] = (int)ed.x;
    }
}

// ---------------- conversions ----------------

__global__ __launch_bounds__(256) void k_cvt(const float* __restrict__ in,
                                             ushort_t* __restrict__ outb, int n4) {
    int i = blockIdx.x * blockDim.x + threadIdx.x;
    if (i < n4) {
        float4 v = reinterpret_cast<const float4*>(in)[i];
        ushort4 o;
        o.x = f2bf(v.x); o.y = f2bf(v.y); o.z = f2bf(v.z); o.w = f2bf(v.w);
        reinterpret_cast<ushort4*>(outb)[i] = o;
    }
}

// W [K=128][Ncols] f32 row-major -> Wt [Ncols][128] bf16
__global__ __launch_bounds__(256) void k_cvtw(const float* __restrict__ W,
                                              ushort_t* __restrict__ Wt, int Ncols) {
    int i = blockIdx.x * blockDim.x + threadIdx.x;
    if (i < 128 * Ncols) {
        int k = i / Ncols, n = i % Ncols;
        Wt[(size_t)n * 128 + k] = f2bf(W[i]);
    }
}

// ---------------- aggregation: bf16 gather, fp32 accumulate, x8 prefetch ----------------

__global__ __launch_bounds__(256) void k_agg1(const ushort_t* __restrict__ xb,
                                              const int* __restrict__ rowptr,
                                              const int* __restrict__ csr,
                                              ushort_t* __restrict__ outb) {
    int wid = (blockIdx.x * blockDim.x + threadIdx.x) >> 6;
    int lane = threadIdx.x & 63;
    if (wid >= Nn) return;
    int s0 = rowptr[wid], s1 = rowptr[wid + 1];
    float ax = 0.f, ay = 0.f;
    int e = s0;
    for (; e + 8 <= s1; e += 8) {
        int idx[8];
        #pragma unroll
        for (int j = 0; j < 8; ++j) idx[j] = csr[e + j];
        uint_t u[8];
        #pragma unroll
        for (int j = 0; j < 8; ++j)
            u[j] = *reinterpret_cast<const uint_t*>(xb + (size_t)idx[j] * 128 + lane * 2);
        #pragma unroll
        for (int j = 0; j < 8; ++j) { ax += bflo(u[j]); ay += bfhi(u[j]); }
    }
    for (; e < s1; ++e) {
        int s = csr[e];
        uint_t u = *reinterpret_cast<const uint_t*>(xb + (size_t)s * 128 + lane * 2);
        ax += bflo(u); ay += bfhi(u);
    }
    float invd = (s1 > s0) ? 1.0f / (float)(s1 - s0) : 0.0f;
    uint_t o = (uint_t)f2bf(ax * invd) | ((uint_t)f2bf(ay * invd) << 16);
    *reinterpret_cast<uint_t*>(outb + (size_t)wid * 128 + lane * 2) = o;
}

__global__ __launch_bounds__(256) void k_agg2(const ushort_t* __restrict__ tb,
                                              const int* __restrict__ rowptr,
                                              const int* __restrict__ csr,
                                              float* __restrict__ out) {
    int wid = (blockIdx.x * blockDim.x + threadIdx.x) >> 6;
    int lane = threadIdx.x & 63;
    if (wid >= Nn) return;
    int s0 = rowptr[wid], s1 = rowptr[wid + 1];
    float a = 0.f;
    int e = s0;
    for (; e + 8 <= s1; e += 8) {
        int idx[8];
        #pragma unroll
        for (int j = 0; j < 8; ++j) idx[j] = csr[e + j];
        ushort_t u[8];
        #pragma unroll
        for (int j = 0; j < 8; ++j) u[j] = tb[(size_t)idx[j] * 64 + lane];
        #pragma unroll
        for (int j = 0; j < 8; ++j) a += __uint_as_float(((uint_t)u[j]) << 16);
    }
    for (; e < s1; ++e) {
        int s = csr[e];
        a += __uint_as_float(((uint_t)tb[(size_t)s * 64 + lane]) << 16);
    }
    float invd = (s1 > s0) ? 1.0f / (float)(s1 - s0) : 0.0f;
    out[(size_t)wid * 64 + lane] = a * invd;
}

// ---------------- MFMA GEMMs (16x16x32 bf16) ----------------
// A-frag: lane holds A[row0+(lane&15)][ks*32+(lane>>4)*8 .. +7]
// B-frag: lane holds Wt[c*16+(lane&15)][ks*32+(lane>>4)*8 ..]
// D: col=lane&15, row=(lane>>4)*4+reg   [verified: absmax unchanged]

__global__ __launch_bounds__(256) void k_gemm1m(const ushort_t* __restrict__ Ab0,
                                                const ushort_t* __restrict__ Ab1,
                                                const ushort_t* __restrict__ Wt0,
                                                const ushort_t* __restrict__ Wt1,
                                                const float* __restrict__ bias,
                                                ushort_t* __restrict__ hb) {
    int gw = (blockIdx.x * 256 + threadIdx.x) >> 6;
    int lane = threadIdx.x & 63;
    if (gw >= Nn / 16) return;
    int row0 = gw * 16;
    int r = lane & 15;
    int kg = lane >> 4;
    f32x4 acc[8];
    #pragma unroll
    for (int c = 0; c < 8; ++c) acc[c] = (f32x4){0.f, 0.f, 0.f, 0.f};
    #pragma unroll
    for (int pair = 0; pair < 2; ++pair) {
        const ushort_t* A  = pair ? Ab1 : Ab0;
        const ushort_t* Wt = pair ? Wt1 : Wt0;
        #pragma unroll
        for (int ks = 0; ks < 4; ++ks) {
            int kbase = ks * 32 + kg * 8;
            bf16x8 af = *reinterpret_cast<const bf16x8*>(A + (size_t)(row0 + r) * 128 + kbase);
            #pragma unroll
            for (int c = 0; c < 8; ++c) {
                bf16x8 bf = *reinterpret_cast<const bf16x8*>(Wt + (size_t)(c * 16 + r) * 128 + kbase);
                acc[c] = __builtin_amdgcn_mfma_f32_16x16x32_bf16(af, bf, acc[c], 0, 0, 0);
            }
        }
    }
    #pragma unroll
    for (int c = 0; c < 8; ++c) {
        float bv = bias[c * 16 + r];
        #pragma unroll
        for (int i = 0; i < 4; ++i) {
            int row = row0 + kg * 4 + i;
            hb[(size_t)row * 128 + c * 16 + r] = f2bf(fmaxf(acc[c][i] + bv, 0.f));
        }
    }
}

__global__ __launch_bounds__(256) void k_gemm2am(const ushort_t* __restrict__ Ab,
                                                 const ushort_t* __restrict__ Wt,
                                                 ushort_t* __restrict__ tb) {
    int gw = (blockIdx.x * 256 + threadIdx.x) >> 6;
    int lane = threadIdx.x & 63;
    if (gw >= Nn / 16) return;
    int row0 = gw * 16;
    int r = lane & 15;
    int kg = lane >> 4;
    f32x4 acc[4];
    #pragma unroll
    for (int c = 0; c < 4; ++c) acc[c] = (f32x4){0.f, 0.f, 0.f, 0.f};
    #pragma unroll
    for (int ks = 0; ks < 4; ++ks) {
        int kbase = ks * 32 + kg * 8;
        bf16x8 af = *reinterpret_cast<const bf16x8*>(Ab + (size_t)(row0 + r) * 128 + kbase);
        #pragma unroll
        for (int c = 0; c < 4; ++c) {
            bf16x8 bf = *reinterpret_cast<const bf16x8*>(Wt + (size_t)(c * 16 + r) * 128 + kbase);
            acc[c] = __builtin_amdgcn_mfma_f32_16x16x32_bf16(af, bf, acc[c], 0, 0, 0);
        }
    }
    #pragma unroll
    for (int c = 0; c < 4; ++c) {
        #pragma unroll
        for (int i = 0; i < 4; ++i) {
            int row = row0 + kg * 4 + i;
            tb[(size_t)row * 64 + c * 16 + r] = f2bf(acc[c][i]);
        }
    }
}

__global__ __launch_bounds__(256) void k_gemm2bm(const ushort_t* __restrict__ Ab,
                                                 const ushort_t* __restrict__ Wt,
                                                 const float* __restrict__ agg2,
                                                 const float* __restrict__ bias,
                                                 float* __restrict__ out) {
    int gw = (blockIdx.x * 256 + threadIdx.x) >> 6;
    int lane = threadIdx.x & 63;
    if (gw >= Nn / 16) return;
    int row0 = gw * 16;
    int r = lane & 15;
    int kg = lane >> 4;
    f32x4 acc[4];
    #pragma unroll
    for (int c = 0; c < 4; ++c) acc[c] = (f32x4){0.f, 0.f, 0.f, 0.f};
    #pragma unroll
    for (int ks = 0; ks < 4; ++ks) {
        int kbase = ks * 32 + kg * 8;
        bf16x8 af = *reinterpret_cast<const bf16x8*>(Ab + (size_t)(row0 + r) * 128 + kbase);
        #pragma unroll
        for (int c = 0; c < 4; ++c) {
            bf16x8 bf = *reinterpret_cast<const bf16x8*>(Wt + (size_t)(c * 16 + r) * 128 + kbase);
            acc[c] = __builtin_amdgcn_mfma_f32_16x16x32_bf16(af, bf, acc[c], 0, 0, 0);
        }
    }
    #pragma unroll
    for (int c = 0; c < 4; ++c) {
        float bv = bias[c * 16 + r];
        #pragma unroll
        for (int i = 0; i < 4; ++i) {
            int row = row0 + kg * 4 + i;
            size_t o = (size_t)row * 64 + c * 16 + r;
            out[o] = acc[c][i] + agg2[o] + bv;
        }
    }
}

// ---------------- in-place log_softmax over 64 classes ----------------

__global__ __launch_bounds__(256) void k_logsm(float* __restrict__ out) {
    int wid = (blockIdx.x * blockDim.x + threadIdx.x) >> 6;
    int lane = threadIdx.x & 63;
    if (wid >= Nn) return;
    float v = out[(size_t)wid * 64 + lane];
    float m = v;
    #pragma unroll
    for (int off = 32; off; off >>= 1) m = fmaxf(m, __shfl_xor(m, off));
    float ex = __expf(v - m);
    float s = ex;
    #pragma unroll
    for (int off = 32; off; off >>= 1) s += __shfl_xor(s, off);
    out[(size_t)wid * 64 + lane] = v - m - __logf(s);
}

// ---------------- launch ----------------

extern "C" void kernel_launch(void* const* d_in, const int* in_sizes, int n_in,
                              void* d_out, int out_size, void* d_ws, size_t ws_size,
                              hipStream_t stream) {
    const float* x   = (const float*)d_in[0];
    const int*   ei  = (const int*)d_in[1];
    const float* W1l = (const float*)d_in[2];
    const float* W1r = (const float*)d_in[3];
    const float* b1  = (const float*)d_in[4];
    const float* W2l = (const float*)d_in[5];
    const float* W2r = (const float*)d_in[6];
    const float* b2  = (const float*)d_in[7];
    float* out = (float*)d_out;

    char* ws = (char*)d_ws;
    int*      deg    = (int*)(ws + 0);             // N ints
    int*      cnt    = (int*)(ws + 400384);        // N ints
    int*      rowptr = (int*)(ws + 800768);        // N+1 ints
    int*      bsum   = (int*)(ws + 1200896);       // SCAN_NB ints
    int*      csr    = (int*)(ws + 1201152);       // E ints -> ends 7601152
    ushort_t* xb     = (ushort_t*)(ws + 7601152);  // N*128 bf16 -> ends 33201152
    ushort_t* aggb   = (ushort_t*)(ws + 33201152); // N*128 bf16 -> ends 58801152
    ushort_t* w1lt   = (ushort_t*)(ws + 58801152); // 128*128 bf16
    ushort_t* w1rt   = (ushort_t*)(ws + 58833920);
    ushort_t* w2lt   = (ushort_t*)(ws + 58866688); // 64*128 bf16
    ushort_t* w2rt   = (ushort_t*)(ws + 58883072); // ends 58899456
    ushort_t* hb     = (ushort_t*)(ws + 84401152); // N*128 bf16 -> ends 110001152
    // CSR-build-phase aliases inside xb region (dead until k_cvt):
    uint2*    bedge  = (uint2*)(ws + 7601152);     // E uint2 = 12.8MB -> ends 20401152
    int*      bcnt   = (int*)(ws + 20401152);      // NB ints
    int*      bcur   = (int*)(ws + 20402176);      // NB ints
    int*      bstart = (int*)(ws + 20403200);      // NB+1 ints
    // layer-2 aliases (disjoint lifetimes):
    ushort_t* tb     = (ushort_t*)(ws + 7601152);  // N*64 bf16 -> ends 20401152
    float*    agg2   = (float*)(ws + 20401152 + 4096); // pad past bmeta; N*64 f32 -> ends 46005248
    // high-water: 110001152 bytes

    const int* src = ei;
    const int* dst = ei + Ee;

    hipMemsetAsync(deg, 0, 800768, stream);       // deg + cnt
    hipMemsetAsync(bcnt, 0, NB * 4, stream);

    k_count<<<(Ee + 255) / 256, 256, 0, stream>>>(dst, deg);
    k_scan1<<<SCAN_NB, 1024, 0, stream>>>(deg, bsum);
    k_scan2<<<1, 64, 0, stream>>>(bsum, rowptr);
    k_scan3<<<SCAN_NB, 1024, 0, stream>>>(deg, bsum, rowptr);

    // bucketed CSR fill
    k_bhist<<<196, 1024, 0, stream>>>(dst, bcnt);
    k_bscan<<<1, 256, 0, stream>>>(bcnt, bstart, bcur);
    k_bscatter<<<196, 1024, 0, stream>>>(src, dst, bcur, bedge);
    k_fill2<<<NB, 1024, 0, stream>>>(bedge, bstart, rowptr, cnt, csr);

    // conversions
    k_cvt<<<(Nn * FIN / 4 + 255) / 256, 256, 0, stream>>>(x, xb, Nn * FIN / 4);
    k_cvtw<<<64, 256, 0, stream>>>(W1l, w1lt, 128);
    k_cvtw<<<64, 256, 0, stream>>>(W1r, w1rt, 128);
    k_cvtw<<<32, 256, 0, stream>>>(W2l, w2lt, 64);
    k_cvtw<<<32, 256, 0, stream>>>(W2r, w2rt, 64);

    // layer 1
    k_agg1<<<(Nn + 3) / 4, 256, 0, stream>>>(xb, rowptr, csr, aggb);
    k_gemm1m<<<(Nn / 16 + 3) / 4, 256, 0, stream>>>(aggb, xb, w1lt, w1rt, b1, hb);

    // layer 2 (reassociated)
    k_gemm2am<<<(Nn / 16 + 3) / 4, 256, 0, stream>>>(hb, w2lt, tb);
    k_agg2<<<(Nn + 3) / 4, 256, 0, stream>>>(tb, rowptr, csr, agg2);
    k_gemm2bm<<<(Nn / 16 + 3) / 4, 256, 0, stream>>>(hb, w2rt, agg2, b2, out);

    k_logsm<<<(Nn + 3) / 4, 256, 0, stream>>>(out);
}

// Round 13
// 315.179 us; speedup vs baseline: 2.5018x; 1.3228x over previous
//
#include <hip/hip_runtime.h>

#define Nn 100000
#define Ee 1600000
#define FIN 128
#define HID 128
#define CLS 64
#define SCAN_NB 25   // ceil(Nn / 4096)
#define NB 196       // dst buckets of 512 nodes (dst>>9)
#define BCAP 9216    // per-bucket edge capacity (mean 8163 + 11 sigma)

typedef unsigned short ushort_t;
typedef unsigned int uint_t;
typedef __attribute__((ext_vector_type(8))) short bf16x8;
typedef __attribute__((ext_vector_type(4))) float f32x4;

__device__ __forceinline__ ushort_t f2bf(float f) {   // RNE fp32->bf16
    uint_t u = __float_as_uint(f);
    return (ushort_t)((u + 0x7fffu + ((u >> 16) & 1u)) >> 16);
}
__device__ __forceinline__ float bflo(uint_t u) { return __uint_as_float(u << 16); }
__device__ __forceinline__ float bfhi(uint_t u) { return __uint_as_float(u & 0xffff0000u); }

// ---------------- bucketed edge scatter (src,dst) -> bedge[bucket*BCAP + i] ----------------

__global__ __launch_bounds__(1024) void k_bscatter(const int* __restrict__ src,
                                                   const int* __restrict__ dst,
                                                   int* __restrict__ bcur,
                                                   uint2* __restrict__ bedge) {
    __shared__ int h[NB];
    __shared__ int lbase[NB];
    int t = threadIdx.x;
    if (t < NB) h[t] = 0;
    __syncthreads();
    int base = blockIdx.x * 8192;
    int bk[8], loc[8];
    #pragma unroll
    for (int it = 0; it < 8; ++it) {
        int e = base + it * 1024 + t;
        if (e < Ee) {
            bk[it] = dst[e] >> 9;
            loc[it] = atomicAdd(&h[bk[it]], 1);
        }
    }
    __syncthreads();
    if (t < NB && h[t]) lbase[t] = atomicAdd(&bcur[t], h[t]);
    __syncthreads();
    #pragma unroll
    for (int it = 0; it < 8; ++it) {
        int e = base + it * 1024 + t;
        if (e < Ee) {
            int pos = lbase[bk[it]] + loc[it];
            if (pos < BCAP)   // statistically impossible overflow guard
                bedge[(size_t)bk[it] * BCAP + pos] = make_uint2((uint_t)src[e], (uint_t)dst[e]);
        }
    }
}

// per-bucket degree count via LDS histogram -> deg (coalesced writes)
__global__ __launch_bounds__(1024) void k_countB(const uint2* __restrict__ bedge,
                                                 const int* __restrict__ bcur,
                                                 int* __restrict__ deg) {
    __shared__ int h[512];
    int b = blockIdx.x, t = threadIdx.x;
    if (t < 512) h[t] = 0;
    __syncthreads();
    int n = min(bcur[b], BCAP);
    int node0 = b << 9;
    for (int i = t; i < n; i += 1024)
        atomicAdd(&h[(int)bedge[(size_t)b * BCAP + i].y - node0], 1);
    __syncthreads();
    if (t < 512) {
        int node = node0 + t;
        if (node < Nn) deg[node] = h[t];
    }
}

// ---------------- rowptr scan ----------------

__global__ __launch_bounds__(1024) void k_scan1(const int* __restrict__ deg,
                                                int* __restrict__ bsum) {
    __shared__ int red[16];
    int t = threadIdx.x, b = blockIdx.x;
    int i4 = b * 1024 + t;
    int s = 0;
    if (i4 < Nn / 4) {
        int4 v = reinterpret_cast<const int4*>(deg)[i4];
        s = v.x + v.y + v.z + v.w;
    }
    #pragma unroll
    for (int off = 32; off; off >>= 1) s += __shfl_down(s, off);
    if ((t & 63) == 0) red[t >> 6] = s;
    __syncthreads();
    if (t < 16) {
        int v = red[t];
        #pragma unroll
        for (int off = 8; off; off >>= 1) v += __shfl_down(v, off);
        if (t == 0) bsum[b] = v;
    }
}

__global__ void k_scan2(int* __restrict__ bsum, int* __restrict__ rowptr) {
    if (threadIdx.x == 0) {
        int acc = 0;
        for (int b = 0; b < SCAN_NB; ++b) { int v = bsum[b]; bsum[b] = acc; acc += v; }
        rowptr[Nn] = acc;
    }
}

__global__ __launch_bounds__(1024) void k_scan3(const int* __restrict__ deg,
                                                const int* __restrict__ bsum,
                                                int* __restrict__ rowptr) {
    __shared__ int sums[1024];
    int t = threadIdx.x, b = blockIdx.x;
    int i4 = b * 1024 + t;
    int4 v = make_int4(0, 0, 0, 0);
    if (i4 < Nn / 4) v = reinterpret_cast<const int4*>(deg)[i4];
    int s = v.x + v.y + v.z + v.w;
    sums[t] = s;
    __syncthreads();
    for (int off = 1; off < 1024; off <<= 1) {
        int vv = (t >= off) ? sums[t - off] : 0;
        __syncthreads();
        sums[t] += vv;
        __syncthreads();
    }
    int excl = sums[t] - s + bsum[b];
    if (i4 < Nn / 4) {
        int4 o;
        o.x = excl;
        o.y = excl + v.x;
        o.z = excl + v.x + v.y;
        o.w = excl + v.x + v.y + v.z;
        reinterpret_cast<int4*>(rowptr)[i4] = o;
    }
}

// per-bucket CSR fill with LDS cnt window; csr window (~32KB) cache-resident
__global__ __launch_bounds__(1024) void k_fill2(const uint2* __restrict__ bedge,
                                                const int* __restrict__ bcur,
                                                const int* __restrict__ rowptr,
                                                int* __restrict__ csr) {
    __shared__ int cnt[512];
    int b = blockIdx.x, t = threadIdx.x;
    if (t < 512) cnt[t] = 0;
    __syncthreads();
    int n = min(bcur[b], BCAP);
    int node0 = b << 9;
    for (int i = t; i < n; i += 1024) {
        uint2 ed = bedge[(size_t)b * BCAP + i];
        int d = (int)ed.y;
        int loc = atomicAdd(&cnt[d - node0], 1);
        csr[rowptr[d] + loc] = (int)ed.x;
    }
}

// ---------------- conversions ----------------

__global__ __launch_bounds__(256) void k_cvt(const float* __restrict__ in,
                                             ushort_t* __restrict__ outb, int n4) {
    int i = blockIdx.x * blockDim.x + threadIdx.x;
    if (i < n4) {
        float4 v = reinterpret_cast<const float4*>(in)[i];
        ushort4 o;
        o.x = f2bf(v.x); o.y = f2bf(v.y); o.z = f2bf(v.z); o.w = f2bf(v.w);
        reinterpret_cast<ushort4*>(outb)[i] = o;
    }
}

// W [K=128][Ncols] f32 row-major -> Wt [Ncols][128] bf16
__global__ __launch_bounds__(256) void k_cvtw(const float* __restrict__ W,
                                              ushort_t* __restrict__ Wt, int Ncols) {
    int i = blockIdx.x * blockDim.x + threadIdx.x;
    if (i < 128 * Ncols) {
        int k = i / Ncols, n = i % Ncols;
        Wt[(size_t)n * 128 + k] = f2bf(W[i]);
    }
}

// ---------------- aggregation: bf16 gather, fp32 accumulate, x16 prefetch ----------------

__global__ __launch_bounds__(256) void k_agg1(const ushort_t* __restrict__ xb,
                                              const int* __restrict__ rowptr,
                                              const int* __restrict__ csr,
                                              ushort_t* __restrict__ outb) {
    int wid = (blockIdx.x * blockDim.x + threadIdx.x) >> 6;
    int lane = threadIdx.x & 63;
    if (wid >= Nn) return;
    int s0 = rowptr[wid], s1 = rowptr[wid + 1];
    float ax = 0.f, ay = 0.f;
    int e = s0;
    for (; e + 16 <= s1; e += 16) {
        int idx[16];
        #pragma unroll
        for (int j = 0; j < 16; ++j) idx[j] = csr[e + j];
        uint_t u[16];
        #pragma unroll
        for (int j = 0; j < 16; ++j)
            u[j] = *reinterpret_cast<const uint_t*>(xb + (size_t)idx[j] * 128 + lane * 2);
        #pragma unroll
        for (int j = 0; j < 16; ++j) { ax += bflo(u[j]); ay += bfhi(u[j]); }
    }
    for (; e + 8 <= s1; e += 8) {
        int idx[8];
        #pragma unroll
        for (int j = 0; j < 8; ++j) idx[j] = csr[e + j];
        uint_t u[8];
        #pragma unroll
        for (int j = 0; j < 8; ++j)
            u[j] = *reinterpret_cast<const uint_t*>(xb + (size_t)idx[j] * 128 + lane * 2);
        #pragma unroll
        for (int j = 0; j < 8; ++j) { ax += bflo(u[j]); ay += bfhi(u[j]); }
    }
    for (; e < s1; ++e) {
        int s = csr[e];
        uint_t u = *reinterpret_cast<const uint_t*>(xb + (size_t)s * 128 + lane * 2);
        ax += bflo(u); ay += bfhi(u);
    }
    float invd = (s1 > s0) ? 1.0f / (float)(s1 - s0) : 0.0f;
    uint_t o = (uint_t)f2bf(ax * invd) | ((uint_t)f2bf(ay * invd) << 16);
    *reinterpret_cast<uint_t*>(outb + (size_t)wid * 128 + lane * 2) = o;
}

__global__ __launch_bounds__(256) void k_agg2(const ushort_t* __restrict__ tb,
                                              const int* __restrict__ rowptr,
                                              const int* __restrict__ csr,
                                              float* __restrict__ out) {
    int wid = (blockIdx.x * blockDim.x + threadIdx.x) >> 6;
    int lane = threadIdx.x & 63;
    if (wid >= Nn) return;
    int s0 = rowptr[wid], s1 = rowptr[wid + 1];
    float a = 0.f;
    int e = s0;
    for (; e + 16 <= s1; e += 16) {
        int idx[16];
        #pragma unroll
        for (int j = 0; j < 16; ++j) idx[j] = csr[e + j];
        ushort_t u[16];
        #pragma unroll
        for (int j = 0; j < 16; ++j) u[j] = tb[(size_t)idx[j] * 64 + lane];
        #pragma unroll
        for (int j = 0; j < 16; ++j) a += __uint_as_float(((uint_t)u[j]) << 16);
    }
    for (; e + 8 <= s1; e += 8) {
        int idx[8];
        #pragma unroll
        for (int j = 0; j < 8; ++j) idx[j] = csr[e + j];
        ushort_t u[8];
        #pragma unroll
        for (int j = 0; j < 8; ++j) u[j] = tb[(size_t)idx[j] * 64 + lane];
        #pragma unroll
        for (int j = 0; j < 8; ++j) a += __uint_as_float(((uint_t)u[j]) << 16);
    }
    for (; e < s1; ++e) {
        int s = csr[e];
        a += __uint_as_float(((uint_t)tb[(size_t)s * 64 + lane]) << 16);
    }
    float invd = (s1 > s0) ? 1.0f / (float)(s1 - s0) : 0.0f;
    out[(size_t)wid * 64 + lane] = a * invd;
}

// ---------------- MFMA GEMMs (16x16x32 bf16) ----------------
// A-frag: lane holds A[row0+(lane&15)][ks*32+(lane>>4)*8 .. +7]
// B-frag: lane holds Wt[c*16+(lane&15)][ks*32+(lane>>4)*8 ..]
// D: col=lane&15, row=(lane>>4)*4+reg   [verified: absmax unchanged]

__global__ __launch_bounds__(256) void k_gemm1m(const ushort_t* __restrict__ Ab0,
                                                const ushort_t* __restrict__ Ab1,
                                                const ushort_t* __restrict__ Wt0,
                                                const ushort_t* __restrict__ Wt1,
                                                const float* __restrict__ bias,
                                                ushort_t* __restrict__ hb) {
    int gw = (blockIdx.x * 256 + threadIdx.x) >> 6;
    int lane = threadIdx.x & 63;
    if (gw >= Nn / 16) return;
    int row0 = gw * 16;
    int r = lane & 15;
    int kg = lane >> 4;
    f32x4 acc[8];
    #pragma unroll
    for (int c = 0; c < 8; ++c) acc[c] = (f32x4){0.f, 0.f, 0.f, 0.f};
    #pragma unroll
    for (int pair = 0; pair < 2; ++pair) {
        const ushort_t* A  = pair ? Ab1 : Ab0;
        const ushort_t* Wt = pair ? Wt1 : Wt0;
        #pragma unroll
        for (int ks = 0; ks < 4; ++ks) {
            int kbase = ks * 32 + kg * 8;
            bf16x8 af = *reinterpret_cast<const bf16x8*>(A + (size_t)(row0 + r) * 128 + kbase);
            #pragma unroll
            for (int c = 0; c < 8; ++c) {
                bf16x8 bf = *reinterpret_cast<const bf16x8*>(Wt + (size_t)(c * 16 + r) * 128 + kbase);
                acc[c] = __builtin_amdgcn_mfma_f32_16x16x32_bf16(af, bf, acc[c], 0, 0, 0);
            }
        }
    }
    #pragma unroll
    for (int c = 0; c < 8; ++c) {
        float bv = bias[c * 16 + r];
        #pragma unroll
        for (int i = 0; i < 4; ++i) {
            int row = row0 + kg * 4 + i;
            hb[(size_t)row * 128 + c * 16 + r] = f2bf(fmaxf(acc[c][i] + bv, 0.f));
        }
    }
}

__global__ __launch_bounds__(256) void k_gemm2am(const ushort_t* __restrict__ Ab,
                                                 const ushort_t* __restrict__ Wt,
                                                 ushort_t* __restrict__ tb) {
    int gw = (blockIdx.x * 256 + threadIdx.x) >> 6;
    int lane = threadIdx.x & 63;
    if (gw >= Nn / 16) return;
    int row0 = gw * 16;
    int r = lane & 15;
    int kg = lane >> 4;
    f32x4 acc[4];
    #pragma unroll
    for (int c = 0; c < 4; ++c) acc[c] = (f32x4){0.f, 0.f, 0.f, 0.f};
    #pragma unroll
    for (int ks = 0; ks < 4; ++ks) {
        int kbase = ks * 32 + kg * 8;
        bf16x8 af = *reinterpret_cast<const bf16x8*>(Ab + (size_t)(row0 + r) * 128 + kbase);
        #pragma unroll
        for (int c = 0; c < 4; ++c) {
            bf16x8 bf = *reinterpret_cast<const bf16x8*>(Wt + (size_t)(c * 16 + r) * 128 + kbase);
            acc[c] = __builtin_amdgcn_mfma_f32_16x16x32_bf16(af, bf, acc[c], 0, 0, 0);
        }
    }
    #pragma unroll
    for (int c = 0; c < 4; ++c) {
        #pragma unroll
        for (int i = 0; i < 4; ++i) {
            int row = row0 + kg * 4 + i;
            tb[(size_t)row * 64 + c * 16 + r] = f2bf(acc[c][i]);
        }
    }
}

__global__ __launch_bounds__(256) void k_gemm2bm(const ushort_t* __restrict__ Ab,
                                                 const ushort_t* __restrict__ Wt,
                                                 const float* __restrict__ agg2,
                                                 const float* __restrict__ bias,
                                                 float* __restrict__ out) {
    int gw = (blockIdx.x * 256 + threadIdx.x) >> 6;
    int lane = threadIdx.x & 63;
    if (gw >= Nn / 16) return;
    int row0 = gw * 16;
    int r = lane & 15;
    int kg = lane >> 4;
    f32x4 acc[4];
    #pragma unroll
    for (int c = 0; c < 4; ++c) acc[c] = (f32x4){0.f, 0.f, 0.f, 0.f};
    #pragma unroll
    for (int ks = 0; ks < 4; ++ks) {
        int kbase = ks * 32 + kg * 8;
        bf16x8 af = *reinterpret_cast<const bf16x8*>(Ab + (size_t)(row0 + r) * 128 + kbase);
        #pragma unroll
        for (int c = 0; c < 4; ++c) {
            bf16x8 bf = *reinterpret_cast<const bf16x8*>(Wt + (size_t)(c * 16 + r) * 128 + kbase);
            acc[c] = __builtin_amdgcn_mfma_f32_16x16x32_bf16(af, bf, acc[c], 0, 0, 0);
        }
    }
    #pragma unroll
    for (int c = 0; c < 4; ++c) {
        float bv = bias[c * 16 + r];
        #pragma unroll
        for (int i = 0; i < 4; ++i) {
            int row = row0 + kg * 4 + i;
            size_t o = (size_t)row * 64 + c * 16 + r;
            out[o] = acc[c][i] + agg2[o] + bv;
        }
    }
}

// ---------------- in-place log_softmax over 64 classes ----------------

__global__ __launch_bounds__(256) void k_logsm(float* __restrict__ out) {
    int wid = (blockIdx.x * blockDim.x + threadIdx.x) >> 6;
    int lane = threadIdx.x & 63;
    if (wid >= Nn) return;
    float v = out[(size_t)wid * 64 + lane];
    float m = v;
    #pragma unroll
    for (int off = 32; off; off >>= 1) m = fmaxf(m, __shfl_xor(m, off));
    float ex = __expf(v - m);
    float s = ex;
    #pragma unroll
    for (int off = 32; off; off >>= 1) s += __shfl_xor(s, off);
    out[(size_t)wid * 64 + lane] = v - m - __logf(s);
}

// ---------------- launch ----------------

extern "C" void kernel_launch(void* const* d_in, const int* in_sizes, int n_in,
                              void* d_out, int out_size, void* d_ws, size_t ws_size,
                              hipStream_t stream) {
    const float* x   = (const float*)d_in[0];
    const int*   ei  = (const int*)d_in[1];
    const float* W1l = (const float*)d_in[2];
    const float* W1r = (const float*)d_in[3];
    const float* b1  = (const float*)d_in[4];
    const float* W2l = (const float*)d_in[5];
    const float* W2r = (const float*)d_in[6];
    const float* b2  = (const float*)d_in[7];
    float* out = (float*)d_out;

    char* ws = (char*)d_ws;
    int*      deg    = (int*)(ws + 0);             // N ints
    int*      rowptr = (int*)(ws + 800768);        // N+1 ints
    int*      bsum   = (int*)(ws + 1200896);       // SCAN_NB ints
    int*      csr    = (int*)(ws + 1201152);       // E ints -> ends 7601152
    ushort_t* xb     = (ushort_t*)(ws + 7601152);  // N*128 bf16 -> ends 33201152
    ushort_t* aggb   = (ushort_t*)(ws + 33201152); // N*128 bf16 -> ends 58801152
    ushort_t* w1lt   = (ushort_t*)(ws + 58801152); // 128*128 bf16
    ushort_t* w1rt   = (ushort_t*)(ws + 58833920);
    ushort_t* w2lt   = (ushort_t*)(ws + 58866688); // 64*128 bf16
    ushort_t* w2rt   = (ushort_t*)(ws + 58883072); // ends 58899456
    ushort_t* hb     = (ushort_t*)(ws + 84401152); // N*128 bf16 -> ends 110001152
    // CSR-build-phase aliases inside xb region (dead before k_cvt):
    uint2*    bedge  = (uint2*)(ws + 7601152);     // NB*BCAP uint2 = 14.45MB -> ends 22051840
    int*      bcur   = (int*)(ws + 22051840);      // NB ints -> ends 22052624
    // layer-2 aliases (disjoint lifetimes):
    ushort_t* tb     = (ushort_t*)(ws + 7601152);  // N*64 bf16 -> ends 20401152
    float*    agg2   = (float*)(ws + 22052864);    // N*64 f32 -> ends 47652864
    // high-water: 110001152 bytes

    const int* src = ei;
    const int* dst = ei + Ee;

    hipMemsetAsync(bcur, 0, NB * 4, stream);

    // CSR build: bucket-scatter -> per-bucket degree count -> scan -> per-bucket fill
    k_bscatter<<<196, 1024, 0, stream>>>(src, dst, bcur, bedge);
    k_countB<<<NB, 1024, 0, stream>>>(bedge, bcur, deg);
    k_scan1<<<SCAN_NB, 1024, 0, stream>>>(deg, bsum);
    k_scan2<<<1, 64, 0, stream>>>(bsum, rowptr);
    k_scan3<<<SCAN_NB, 1024, 0, stream>>>(deg, bsum, rowptr);
    k_fill2<<<NB, 1024, 0, stream>>>(bedge, bcur, rowptr, csr);

    // conversions
    k_cvt<<<(Nn * FIN / 4 + 255) / 256, 256, 0, stream>>>(x, xb, Nn * FIN / 4);
    k_cvtw<<<64, 256, 0, stream>>>(W1l, w1lt, 128);
    k_cvtw<<<64, 256, 0, stream>>>(W1r, w1rt, 128);
    k_cvtw<<<32, 256, 0, stream>>>(W2l, w2lt, 64);
    k_cvtw<<<32, 256, 0, stream>>>(W2r, w2rt, 64);

    // layer 1
    k_agg1<<<(Nn + 3) / 4, 256, 0, stream>>>(xb, rowptr, csr, aggb);
    k_gemm1m<<<(Nn / 16 + 3) / 4, 256, 0, stream>>>(aggb, xb, w1lt, w1rt, b1, hb);

    // layer 2 (reassociated)
    k_gemm2am<<<(Nn / 16 + 3) / 4, 256, 0, stream>>>(hb, w2lt, tb);
    k_agg2<<<(Nn + 3) / 4, 256, 0, stream>>>(tb, rowptr, csr, agg2);
    k_gemm2bm<<<(Nn / 16 + 3) / 4, 256, 0, stream>>>(hb, w2rt, agg2, b2, out);

    k_logsm<<<(Nn + 3) / 4, 256, 0, stream>>>(out);
}

// Round 15
// 290.570 us; speedup vs baseline: 2.7137x; 1.0847x over previous
//
#include <hip/hip_runtime.h>

#define Nn 100000
#define Ee 1600000
#define FIN 128
#define HID 128
#define CLS 64
#define NB 196       // dst buckets of 512 nodes (dst>>9)
#define BCAP 9216    // per-bucket edge capacity (mean 8163 + 11 sigma)

typedef unsigned short ushort_t;
typedef unsigned int uint_t;
typedef __attribute__((ext_vector_type(8))) short bf16x8;
typedef __attribute__((ext_vector_type(4))) float f32x4;

__device__ __forceinline__ ushort_t f2bf(float f) {   // RNE fp32->bf16
    uint_t u = __float_as_uint(f);
    return (ushort_t)((u + 0x7fffu + ((u >> 16) & 1u)) >> 16);
}
__device__ __forceinline__ float bflo(uint_t u) { return __uint_as_float(u << 16); }
__device__ __forceinline__ float bfhi(uint_t u) { return __uint_as_float(u & 0xffff0000u); }

// ---------------- bucketed edge scatter (src,dst) -> bedge[bucket*BCAP + i] ----------------

__global__ __launch_bounds__(1024) void k_bscatter(const int* __restrict__ src,
                                                   const int* __restrict__ dst,
                                                   int* __restrict__ bcur,
                                                   uint2* __restrict__ bedge) {
    __shared__ int h[NB];
    __shared__ int lbase[NB];
    int t = threadIdx.x;
    if (t < NB) h[t] = 0;
    __syncthreads();
    int base = blockIdx.x * 8192;
    int bk[8], loc[8];
    #pragma unroll
    for (int it = 0; it < 8; ++it) {
        int e = base + it * 1024 + t;
        if (e < Ee) {
            bk[it] = dst[e] >> 9;
            loc[it] = atomicAdd(&h[bk[it]], 1);
        }
    }
    __syncthreads();
    if (t < NB && h[t]) lbase[t] = atomicAdd(&bcur[t], h[t]);
    __syncthreads();
    #pragma unroll
    for (int it = 0; it < 8; ++it) {
        int e = base + it * 1024 + t;
        if (e < Ee) {
            int pos = lbase[bk[it]] + loc[it];
            if (pos < BCAP)   // statistically impossible overflow guard
                bedge[(size_t)bk[it] * BCAP + pos] = make_uint2((uint_t)src[e], (uint_t)dst[e]);
        }
    }
}

// exclusive scan of 196 bucket counts -> bstart[NB+1]; rowptr[Nn] = total
__global__ __launch_bounds__(256) void k_bscan(const int* __restrict__ bcur,
                                               int* __restrict__ bstart,
                                               int* __restrict__ rowptr) {
    __shared__ int s[256];
    int t = threadIdx.x;
    int v = (t < NB) ? min(bcur[t], BCAP) : 0;
    s[t] = v;
    __syncthreads();
    for (int off = 1; off < 256; off <<= 1) {
        int u = (t >= off) ? s[t - off] : 0;
        __syncthreads();
        s[t] += u;
        __syncthreads();
    }
    if (t < NB) bstart[t] = s[t] - v;
    if (t == NB - 1) { bstart[NB] = s[t]; rowptr[Nn] = s[t]; }
}

// fused per-bucket: LDS hist -> LDS scan -> rowptr write -> CSR fill
__global__ __launch_bounds__(1024) void k_fillB(const uint2* __restrict__ bedge,
                                                const int* __restrict__ bcur,
                                                const int* __restrict__ bstart,
                                                int* __restrict__ rowptr,
                                                int* __restrict__ csr) {
    __shared__ int h[512];
    __shared__ int off[512];
    int b = blockIdx.x, t = threadIdx.x;
    if (t < 512) h[t] = 0;
    __syncthreads();
    int n = min(bcur[b], BCAP);
    int node0 = b << 9;
    const uint2* be = bedge + (size_t)b * BCAP;
    for (int i = t; i < n; i += 1024)
        atomicAdd(&h[(int)be[i].y - node0], 1);
    __syncthreads();
    if (t < 512) off[t] = h[t];
    __syncthreads();
    for (int o = 1; o < 512; o <<= 1) {
        int v = (t < 512 && t >= o) ? off[t - o] : 0;
        __syncthreads();
        if (t < 512) off[t] += v;
        __syncthreads();
    }
    int base_ = bstart[b];
    if (t < 512) {
        int excl = off[t] - h[t];
        int node = node0 + t;
        if (node < Nn) rowptr[node] = base_ + excl;
        h[t] = excl;    // running local offset
    }
    __syncthreads();
    for (int i = t; i < n; i += 1024) {
        uint2 ed = be[i];
        int loc = atomicAdd(&h[(int)ed.y - node0], 1);
        csr[base_ + loc] = (int)ed.x;
    }
}

// ---------------- conversions ----------------

__global__ __launch_bounds__(256) void k_cvt(const float* __restrict__ in,
                                             ushort_t* __restrict__ outb, int n4) {
    int i = blockIdx.x * blockDim.x + threadIdx.x;
    if (i < n4) {
        float4 v = reinterpret_cast<const float4*>(in)[i];
        ushort4 o;
        o.x = f2bf(v.x); o.y = f2bf(v.y); o.z = f2bf(v.z); o.w = f2bf(v.w);
        reinterpret_cast<ushort4*>(outb)[i] = o;
    }
}

__global__ __launch_bounds__(256) void k_cvtw(const float* __restrict__ W,
                                              ushort_t* __restrict__ Wt, int Ncols) {
    int i = blockIdx.x * blockDim.x + threadIdx.x;
    if (i < 128 * Ncols) {
        int k = i / Ncols, n = i % Ncols;
        Wt[(size_t)n * 128 + k] = f2bf(W[i]);
    }
}

// ---------------- aggregation: multi-row gathers ----------------
// agg1: 256B rows; 32 lanes x 8B per row -> 2 edges per load instruction.

__global__ __launch_bounds__(256) void k_agg1(const ushort_t* __restrict__ xb,
                                              const int* __restrict__ rowptr,
                                              const int* __restrict__ csr,
                                              ushort_t* __restrict__ outb) {
    int wid = (blockIdx.x * blockDim.x + threadIdx.x) >> 6;
    int lane = threadIdx.x & 63;
    if (wid >= Nn) return;
    int s0 = rowptr[wid], s1 = rowptr[wid + 1];
    int half = lane >> 5;
    int col = lane & 31;                     // 8B chunk: elems col*4..+3
    const ushort_t* base = xb + col * 4;
    float a0 = 0.f, a1 = 0.f, a2 = 0.f, a3 = 0.f;
    int e = s0;
    for (; e + 8 <= s1; e += 8) {
        int idx[8];
        #pragma unroll
        for (int j = 0; j < 8; ++j) idx[j] = csr[e + j];
        uint2 u[4];
        #pragma unroll
        for (int p = 0; p < 4; ++p)
            u[p] = *reinterpret_cast<const uint2*>(base + (size_t)idx[p * 2 + half] * 128);
        #pragma unroll
        for (int p = 0; p < 4; ++p) {
            a0 += bflo(u[p].x); a1 += bfhi(u[p].x);
            a2 += bflo(u[p].y); a3 += bfhi(u[p].y);
        }
    }
    for (; e + 2 <= s1; e += 2) {
        uint2 u = *reinterpret_cast<const uint2*>(base + (size_t)csr[e + half] * 128);
        a0 += bflo(u.x); a1 += bfhi(u.x); a2 += bflo(u.y); a3 += bfhi(u.y);
    }
    if (e < s1 && half == 0) {
        uint2 u = *reinterpret_cast<const uint2*>(base + (size_t)csr[e] * 128);
        a0 += bflo(u.x); a1 += bfhi(u.x); a2 += bflo(u.y); a3 += bfhi(u.y);
    }
    a0 += __shfl_xor(a0, 32); a1 += __shfl_xor(a1, 32);
    a2 += __shfl_xor(a2, 32); a3 += __shfl_xor(a3, 32);
    float invd = (s1 > s0) ? 1.0f / (float)(s1 - s0) : 0.0f;
    if (half == 0) {
        uint2 o;
        o.x = (uint_t)f2bf(a0 * invd) | ((uint_t)f2bf(a1 * invd) << 16);
        o.y = (uint_t)f2bf(a2 * invd) | ((uint_t)f2bf(a3 * invd) << 16);
        *reinterpret_cast<uint2*>(outb + (size_t)wid * 128 + col * 4) = o;
    }
}

// agg2: 128B rows; 16 lanes x 8B per row -> 4 edges per load instruction.
__global__ __launch_bounds__(256) void k_agg2(const ushort_t* __restrict__ tb,
                                              const int* __restrict__ rowptr,
                                              const int* __restrict__ csr,
                                              float* __restrict__ out) {
    int wid = (blockIdx.x * blockDim.x + threadIdx.x) >> 6;
    int lane = threadIdx.x & 63;
    if (wid >= Nn) return;
    int s0 = rowptr[wid], s1 = rowptr[wid + 1];
    int g = lane >> 4;
    int col = lane & 15;                     // elems col*4..+3
    const ushort_t* base = tb + col * 4;
    float a0 = 0.f, a1 = 0.f, a2 = 0.f, a3 = 0.f;
    int e = s0;
    for (; e + 8 <= s1; e += 8) {
        int idx[8];
        #pragma unroll
        for (int j = 0; j < 8; ++j) idx[j] = csr[e + j];
        uint2 u[2];
        #pragma unroll
        for (int p = 0; p < 2; ++p)
            u[p] = *reinterpret_cast<const uint2*>(base + (size_t)idx[p * 4 + g] * 64);
        #pragma unroll
        for (int p = 0; p < 2; ++p) {
            a0 += bflo(u[p].x); a1 += bfhi(u[p].x);
            a2 += bflo(u[p].y); a3 += bfhi(u[p].y);
        }
    }
    for (; e < s1; e += 4) {
        int rem = s1 - e;
        if (g < rem) {
            uint2 u = *reinterpret_cast<const uint2*>(base + (size_t)csr[e + g] * 64);
            a0 += bflo(u.x); a1 += bfhi(u.x); a2 += bflo(u.y); a3 += bfhi(u.y);
        }
    }
    a0 += __shfl_xor(a0, 16); a1 += __shfl_xor(a1, 16);
    a2 += __shfl_xor(a2, 16); a3 += __shfl_xor(a3, 16);
    a0 += __shfl_xor(a0, 32); a1 += __shfl_xor(a1, 32);
    a2 += __shfl_xor(a2, 32); a3 += __shfl_xor(a3, 32);
    float invd = (s1 > s0) ? 1.0f / (float)(s1 - s0) : 0.0f;
    if (g == 0) {
        float4 o;
        o.x = a0 * invd; o.y = a1 * invd; o.z = a2 * invd; o.w = a3 * invd;
        *reinterpret_cast<float4*>(out + (size_t)wid * 64 + col * 4) = o;
    }
}

// ---------------- MFMA GEMMs (16x16x32 bf16) ----------------
// A-frag: lane holds A[row0+(lane&15)][ks*32+(lane>>4)*8 .. +7]
// B-frag: lane holds Wt[c*16+(lane&15)][ks*32+(lane>>4)*8 ..]
// D: col=lane&15, row=(lane>>4)*4+reg   [verified: absmax unchanged]

__global__ __launch_bounds__(256) void k_gemm1m(const ushort_t* __restrict__ Ab0,
                                                const ushort_t* __restrict__ Ab1,
                                                const ushort_t* __restrict__ Wt0,
                                                const ushort_t* __restrict__ Wt1,
                                                const float* __restrict__ bias,
                                                ushort_t* __restrict__ hb) {
    int gw = (blockIdx.x * 256 + threadIdx.x) >> 6;
    int lane = threadIdx.x & 63;
    if (gw >= Nn / 16) return;
    int row0 = gw * 16;
    int r = lane & 15;
    int kg = lane >> 4;
    f32x4 acc[8];
    #pragma unroll
    for (int c = 0; c < 8; ++c) acc[c] = (f32x4){0.f, 0.f, 0.f, 0.f};
    #pragma unroll
    for (int pair = 0; pair < 2; ++pair) {
        const ushort_t* A  = pair ? Ab1 : Ab0;
        const ushort_t* Wt = pair ? Wt1 : Wt0;
        #pragma unroll
        for (int ks = 0; ks < 4; ++ks) {
            int kbase = ks * 32 + kg * 8;
            bf16x8 af = *reinterpret_cast<const bf16x8*>(A + (size_t)(row0 + r) * 128 + kbase);
            #pragma unroll
            for (int c = 0; c < 8; ++c) {
                bf16x8 bf = *reinterpret_cast<const bf16x8*>(Wt + (size_t)(c * 16 + r) * 128 + kbase);
                acc[c] = __builtin_amdgcn_mfma_f32_16x16x32_bf16(af, bf, acc[c], 0, 0, 0);
            }
        }
    }
    #pragma unroll
    for (int c = 0; c < 8; ++c) {
        float bv = bias[c * 16 + r];
        #pragma unroll
        for (int i = 0; i < 4; ++i) {
            int row = row0 + kg * 4 + i;
            hb[(size_t)row * 128 + c * 16 + r] = f2bf(fmaxf(acc[c][i] + bv, 0.f));
        }
    }
}

__global__ __launch_bounds__(256) void k_gemm2am(const ushort_t* __restrict__ Ab,
                                                 const ushort_t* __restrict__ Wt,
                                                 ushort_t* __restrict__ tb) {
    int gw = (blockIdx.x * 256 + threadIdx.x) >> 6;
    int lane = threadIdx.x & 63;
    if (gw >= Nn / 16) return;
    int row0 = gw * 16;
    int r = lane & 15;
    int kg = lane >> 4;
    f32x4 acc[4];
    #pragma unroll
    for (int c = 0; c < 4; ++c) acc[c] = (f32x4){0.f, 0.f, 0.f, 0.f};
    #pragma unroll
    for (int ks = 0; ks < 4; ++ks) {
        int kbase = ks * 32 + kg * 8;
        bf16x8 af = *reinterpret_cast<const bf16x8*>(Ab + (size_t)(row0 + r) * 128 + kbase);
        #pragma unroll
        for (int c = 0; c < 4; ++c) {
            bf16x8 bf = *reinterpret_cast<const bf16x8*>(Wt + (size_t)(c * 16 + r) * 128 + kbase);
            acc[c] = __builtin_amdgcn_mfma_f32_16x16x32_bf16(af, bf, acc[c], 0, 0, 0);
        }
    }
    #pragma unroll
    for (int c = 0; c < 4; ++c) {
        #pragma unroll
        for (int i = 0; i < 4; ++i) {
            int row = row0 + kg * 4 + i;
            tb[(size_t)row * 64 + c * 16 + r] = f2bf(acc[c][i]);
        }
    }
}

__global__ __launch_bounds__(256) void k_gemm2bm(const ushort_t* __restrict__ Ab,
                                                 const ushort_t* __restrict__ Wt,
                                                 const float* __restrict__ agg2,
                                                 const float* __restrict__ bias,
                                                 float* __restrict__ out) {
    int gw = (blockIdx.x * 256 + threadIdx.x) >> 6;
    int lane = threadIdx.x & 63;
    if (gw >= Nn / 16) return;
    int row0 = gw * 16;
    int r = lane & 15;
    int kg = lane >> 4;
    f32x4 acc[4];
    #pragma unroll
    for (int c = 0; c < 4; ++c) acc[c] = (f32x4){0.f, 0.f, 0.f, 0.f};
    #pragma unroll
    for (int ks = 0; ks < 4; ++ks) {
        int kbase = ks * 32 + kg * 8;
        bf16x8 af = *reinterpret_cast<const bf16x8*>(Ab + (size_t)(row0 + r) * 128 + kbase);
        #pragma unroll
        for (int c = 0; c < 4; ++c) {
            bf16x8 bf = *reinterpret_cast<const bf16x8*>(Wt + (size_t)(c * 16 + r) * 128 + kbase);
            acc[c] = __builtin_amdgcn_mfma_f32_16x16x32_bf16(af, bf, acc[c], 0, 0, 0);
        }
    }
    #pragma unroll
    for (int c = 0; c < 4; ++c) {
        float bv = bias[c * 16 + r];
        #pragma unroll
        for (int i = 0; i < 4; ++i) {
            int row = row0 + kg * 4 + i;
            size_t o = (size_t)row * 64 + c * 16 + r;
            out[o] = acc[c][i] + agg2[o] + bv;
        }
    }
}

// ---------------- in-place log_softmax over 64 classes ----------------

__global__ __launch_bounds__(256) void k_logsm(float* __restrict__ out) {
    int wid = (blockIdx.x * blockDim.x + threadIdx.x) >> 6;
    int lane = threadIdx.x & 63;
    if (wid >= Nn) return;
    float v = out[(size_t)wid * 64 + lane];
    float m = v;
    #pragma unroll
    for (int off = 32; off; off >>= 1) m = fmaxf(m, __shfl_xor(m, off));
    float ex = __expf(v - m);
    float s = ex;
    #pragma unroll
    for (int off = 32; off; off >>= 1) s += __shfl_xor(s, off);
    out[(size_t)wid * 64 + lane] = v - m - __logf(s);
}

// ---------------- launch ----------------

extern "C" void kernel_launch(void* const* d_in, const int* in_sizes, int n_in,
                              void* d_out, int out_size, void* d_ws, size_t ws_size,
                              hipStream_t stream) {
    const float* x   = (const float*)d_in[0];
    const int*   ei  = (const int*)d_in[1];
    const float* W1l = (const float*)d_in[2];
    const float* W1r = (const float*)d_in[3];
    const float* b1  = (const float*)d_in[4];
    const float* W2l = (const float*)d_in[5];
    const float* W2r = (const float*)d_in[6];
    const float* b2  = (const float*)d_in[7];
    float* out = (float*)d_out;

    char* ws = (char*)d_ws;
    int*      bstart = (int*)(ws + 0);             // NB+1 ints (region freed by deg removal)
    int*      rowptr = (int*)(ws + 800768);        // N+1 ints -> ends 1200772
    int*      csr    = (int*)(ws + 1201152);       // E ints -> ends 7601152
    ushort_t* xb     = (ushort_t*)(ws + 7601152);  // N*128 bf16 -> ends 33201152
    ushort_t* aggb   = (ushort_t*)(ws + 33201152); // N*128 bf16 -> ends 58801152
    ushort_t* w1lt   = (ushort_t*)(ws + 58801152); // 128*128 bf16
    ushort_t* w1rt   = (ushort_t*)(ws + 58833920);
    ushort_t* w2lt   = (ushort_t*)(ws + 58866688); // 64*128 bf16
    ushort_t* w2rt   = (ushort_t*)(ws + 58883072); // ends 58899456
    ushort_t* hb     = (ushort_t*)(ws + 84401152); // N*128 bf16 -> ends 110001152
    // CSR-build-phase aliases inside xb region (dead before k_cvt):
    uint2*    bedge  = (uint2*)(ws + 7601152);     // NB*BCAP uint2 = 14.45MB -> ends 22051840
    int*      bcur   = (int*)(ws + 22051840);      // NB ints -> ends 22052624
    // layer-2 aliases (disjoint lifetimes):
    ushort_t* tb     = (ushort_t*)(ws + 7601152);  // N*64 bf16 -> ends 20401152
    float*    agg2   = (float*)(ws + 22052864);    // N*64 f32 -> ends 47652864 (aggb dead by then)
    // high-water: 110001152 bytes

    const int* src = ei;
    const int* dst = ei + Ee;

    hipMemsetAsync(bcur, 0, NB * 4, stream);

    // CSR build: bucket-scatter -> bucket scan -> fused per-bucket hist+scan+fill
    k_bscatter<<<196, 1024, 0, stream>>>(src, dst, bcur, bedge);
    k_bscan<<<1, 256, 0, stream>>>(bcur, bstart, rowptr);
    k_fillB<<<NB, 1024, 0, stream>>>(bedge, bcur, bstart, rowptr, csr);

    // conversions
    k_cvt<<<(Nn * FIN / 4 + 255) / 256, 256, 0, stream>>>(x, xb, Nn * FIN / 4);
    k_cvtw<<<64, 256, 0, stream>>>(W1l, w1lt, 128);
    k_cvtw<<<64, 256, 0, stream>>>(W1r, w1rt, 128);
    k_cvtw<<<32, 256, 0, stream>>>(W2l, w2lt, 64);
    k_cvtw<<<32, 256, 0, stream>>>(W2r, w2rt, 64);

    // layer 1
    k_agg1<<<(Nn + 3) / 4, 256, 0, stream>>>(xb, rowptr, csr, aggb);
    k_gemm1m<<<(Nn / 16 + 3) / 4, 256, 0, stream>>>(aggb, xb, w1lt, w1rt, b1, hb);

    // layer 2 (reassociated)
    k_gemm2am<<<(Nn / 16 + 3) / 4, 256, 0, stream>>>(hb, w2lt, tb);
    k_agg2<<<(Nn + 3) / 4, 256, 0, stream>>>(tb, rowptr, csr, agg2);
    k_gemm2bm<<<(Nn / 16 + 3) / 4, 256, 0, stream>>>(hb, w2rt, agg2, b2, out);

    k_logsm<<<(Nn + 3) / 4, 256, 0, stream>>>(out);
}

// Round 16
// 286.114 us; speedup vs baseline: 2.7559x; 1.0156x over previous
//
#include <hip/hip_runtime.h>

#define Nn 100000
#define Ee 1600000
#define FIN 128
#define HID 128
#define CLS 64
#define NB 196       // dst buckets of 512 nodes (dst>>9)
#define BCAP 9216    // per-bucket edge capacity (mean 8163 + 11 sigma)

typedef unsigned short ushort_t;
typedef unsigned int uint_t;
typedef __attribute__((ext_vector_type(8))) short bf16x8;
typedef __attribute__((ext_vector_type(4))) float f32x4;

__device__ __forceinline__ ushort_t f2bf(float f) {   // RNE fp32->bf16
    uint_t u = __float_as_uint(f);
    return (ushort_t)((u + 0x7fffu + ((u >> 16) & 1u)) >> 16);
}
__device__ __forceinline__ float bflo(uint_t u) { return __uint_as_float(u << 16); }
__device__ __forceinline__ float bfhi(uint_t u) { return __uint_as_float(u & 0xffff0000u); }

// ---------------- bucketed edge scatter (src,dst) -> bedge[bucket*BCAP + i] ----------------

__global__ __launch_bounds__(1024) void k_bscatter(const int* __restrict__ src,
                                                   const int* __restrict__ dst,
                                                   int* __restrict__ bcur,
                                                   uint2* __restrict__ bedge) {
    __shared__ int h[NB];
    __shared__ int lbase[NB];
    int t = threadIdx.x;
    if (t < NB) h[t] = 0;
    __syncthreads();
    int base = blockIdx.x * 8192;
    int bk[8], loc[8];
    #pragma unroll
    for (int it = 0; it < 8; ++it) {
        int e = base + it * 1024 + t;
        if (e < Ee) {
            bk[it] = dst[e] >> 9;
            loc[it] = atomicAdd(&h[bk[it]], 1);
        }
    }
    __syncthreads();
    if (t < NB && h[t]) lbase[t] = atomicAdd(&bcur[t], h[t]);
    __syncthreads();
    #pragma unroll
    for (int it = 0; it < 8; ++it) {
        int e = base + it * 1024 + t;
        if (e < Ee) {
            int pos = lbase[bk[it]] + loc[it];
            if (pos < BCAP)   // statistically impossible overflow guard
                bedge[(size_t)bk[it] * BCAP + pos] = make_uint2((uint_t)src[e], (uint_t)dst[e]);
        }
    }
}

// exclusive scan of 196 bucket counts -> bstart[NB+1]; rowptr[Nn] = total
__global__ __launch_bounds__(256) void k_bscan(const int* __restrict__ bcur,
                                               int* __restrict__ bstart,
                                               int* __restrict__ rowptr) {
    __shared__ int s[256];
    int t = threadIdx.x;
    int v = (t < NB) ? min(bcur[t], BCAP) : 0;
    s[t] = v;
    __syncthreads();
    for (int off = 1; off < 256; off <<= 1) {
        int u = (t >= off) ? s[t - off] : 0;
        __syncthreads();
        s[t] += u;
        __syncthreads();
    }
    if (t < NB) bstart[t] = s[t] - v;
    if (t == NB - 1) { bstart[NB] = s[t]; rowptr[Nn] = s[t]; }
}

// fused per-bucket: LDS hist -> LDS scan -> rowptr write -> CSR fill
__global__ __launch_bounds__(1024) void k_fillB(const uint2* __restrict__ bedge,
                                                const int* __restrict__ bcur,
                                                const int* __restrict__ bstart,
                                                int* __restrict__ rowptr,
                                                int* __restrict__ csr) {
    __shared__ int h[512];
    __shared__ int off[512];
    int b = blockIdx.x, t = threadIdx.x;
    if (t < 512) h[t] = 0;
    __syncthreads();
    int n = min(bcur[b], BCAP);
    int node0 = b << 9;
    const uint2* be = bedge + (size_t)b * BCAP;
    for (int i = t; i < n; i += 1024)
        atomicAdd(&h[(int)be[i].y - node0], 1);
    __syncthreads();
    if (t < 512) off[t] = h[t];
    __syncthreads();
    for (int o = 1; o < 512; o <<= 1) {
        int v = (t < 512 && t >= o) ? off[t - o] : 0;
        __syncthreads();
        if (t < 512) off[t] += v;
        __syncthreads();
    }
    int base_ = bstart[b];
    if (t < 512) {
        int excl = off[t] - h[t];
        int node = node0 + t;
        if (node < Nn) rowptr[node] = base_ + excl;
        h[t] = excl;    // running local offset
    }
    __syncthreads();
    for (int i = t; i < n; i += 1024) {
        uint2 ed = be[i];
        int loc = atomicAdd(&h[(int)ed.y - node0], 1);
        csr[base_ + loc] = (int)ed.x;
    }
}

// ---------------- conversions ----------------

__global__ __launch_bounds__(256) void k_cvt(const float* __restrict__ in,
                                             ushort_t* __restrict__ outb, int n4) {
    int i = blockIdx.x * blockDim.x + threadIdx.x;
    if (i < n4) {
        float4 v = reinterpret_cast<const float4*>(in)[i];
        ushort4 o;
        o.x = f2bf(v.x); o.y = f2bf(v.y); o.z = f2bf(v.z); o.w = f2bf(v.w);
        reinterpret_cast<ushort4*>(outb)[i] = o;
    }
}

__global__ __launch_bounds__(256) void k_cvtw(const float* __restrict__ W,
                                              ushort_t* __restrict__ Wt, int Ncols) {
    int i = blockIdx.x * blockDim.x + threadIdx.x;
    if (i < 128 * Ncols) {
        int k = i / Ncols, n = i % Ncols;
        Wt[(size_t)n * 128 + k] = f2bf(W[i]);
    }
}

// ---------------- aggregation: full-row gather with scalar (saddr) addressing ----------------
// Row index is wave-uniform; readfirstlane forces it into SGPR so the gather
// emits global_load with SGPR base + fixed lane offset (address math on SALU).

__global__ __launch_bounds__(256) void k_agg1(const ushort_t* __restrict__ xb,
                                              const int* __restrict__ rowptr,
                                              const int* __restrict__ csr,
                                              ushort_t* __restrict__ outb) {
    int wid = (blockIdx.x * blockDim.x + threadIdx.x) >> 6;
    int lane = threadIdx.x & 63;
    if (wid >= Nn) return;
    int s0 = __builtin_amdgcn_readfirstlane(rowptr[wid]);
    int s1 = __builtin_amdgcn_readfirstlane(rowptr[wid + 1]);
    float ax = 0.f, ay = 0.f;
    int e = s0;
    for (; e + 8 <= s1; e += 8) {
        int idx[8];
        #pragma unroll
        for (int j = 0; j < 8; ++j) idx[j] = __builtin_amdgcn_readfirstlane(csr[e + j]);
        uint_t u[8];
        #pragma unroll
        for (int j = 0; j < 8; ++j)
            u[j] = *reinterpret_cast<const uint_t*>(xb + (size_t)idx[j] * 128 + lane * 2);
        #pragma unroll
        for (int j = 0; j < 8; ++j) { ax += bflo(u[j]); ay += bfhi(u[j]); }
    }
    for (; e < s1; ++e) {
        int s = __builtin_amdgcn_readfirstlane(csr[e]);
        uint_t u = *reinterpret_cast<const uint_t*>(xb + (size_t)s * 128 + lane * 2);
        ax += bflo(u); ay += bfhi(u);
    }
    float invd = (s1 > s0) ? 1.0f / (float)(s1 - s0) : 0.0f;
    uint_t o = (uint_t)f2bf(ax * invd) | ((uint_t)f2bf(ay * invd) << 16);
    *reinterpret_cast<uint_t*>(outb + (size_t)wid * 128 + lane * 2) = o;
}

__global__ __launch_bounds__(256) void k_agg2(const ushort_t* __restrict__ tb,
                                              const int* __restrict__ rowptr,
                                              const int* __restrict__ csr,
                                              float* __restrict__ out) {
    int wid = (blockIdx.x * blockDim.x + threadIdx.x) >> 6;
    int lane = threadIdx.x & 63;
    if (wid >= Nn) return;
    int s0 = __builtin_amdgcn_readfirstlane(rowptr[wid]);
    int s1 = __builtin_amdgcn_readfirstlane(rowptr[wid + 1]);
    float a = 0.f;
    int e = s0;
    for (; e + 8 <= s1; e += 8) {
        int idx[8];
        #pragma unroll
        for (int j = 0; j < 8; ++j) idx[j] = __builtin_amdgcn_readfirstlane(csr[e + j]);
        ushort_t u[8];
        #pragma unroll
        for (int j = 0; j < 8; ++j) u[j] = tb[(size_t)idx[j] * 64 + lane];
        #pragma unroll
        for (int j = 0; j < 8; ++j) a += __uint_as_float(((uint_t)u[j]) << 16);
    }
    for (; e < s1; ++e) {
        int s = __builtin_amdgcn_readfirstlane(csr[e]);
        a += __uint_as_float(((uint_t)tb[(size_t)s * 64 + lane]) << 16);
    }
    float invd = (s1 > s0) ? 1.0f / (float)(s1 - s0) : 0.0f;
    out[(size_t)wid * 64 + lane] = a * invd;
}

// ---------------- MFMA GEMMs (16x16x32 bf16) ----------------
// A-frag: lane holds A[row0+(lane&15)][ks*32+(lane>>4)*8 .. +7]
// B-frag: lane holds Wt[c*16+(lane&15)][ks*32+(lane>>4)*8 ..]
// D: col=lane&15, row=(lane>>4)*4+reg   [verified: absmax unchanged]

__global__ __launch_bounds__(256) void k_gemm1m(const ushort_t* __restrict__ Ab0,
                                                const ushort_t* __restrict__ Ab1,
                                                const ushort_t* __restrict__ Wt0,
                                                const ushort_t* __restrict__ Wt1,
                                                const float* __restrict__ bias,
                                                ushort_t* __restrict__ hb) {
    int gw = (blockIdx.x * 256 + threadIdx.x) >> 6;
    int lane = threadIdx.x & 63;
    if (gw >= Nn / 16) return;
    int row0 = gw * 16;
    int r = lane & 15;
    int kg = lane >> 4;
    f32x4 acc[8];
    #pragma unroll
    for (int c = 0; c < 8; ++c) acc[c] = (f32x4){0.f, 0.f, 0.f, 0.f};
    #pragma unroll
    for (int pair = 0; pair < 2; ++pair) {
        const ushort_t* A  = pair ? Ab1 : Ab0;
        const ushort_t* Wt = pair ? Wt1 : Wt0;
        #pragma unroll
        for (int ks = 0; ks < 4; ++ks) {
            int kbase = ks * 32 + kg * 8;
            bf16x8 af = *reinterpret_cast<const bf16x8*>(A + (size_t)(row0 + r) * 128 + kbase);
            #pragma unroll
            for (int c = 0; c < 8; ++c) {
                bf16x8 bf = *reinterpret_cast<const bf16x8*>(Wt + (size_t)(c * 16 + r) * 128 + kbase);
                acc[c] = __builtin_amdgcn_mfma_f32_16x16x32_bf16(af, bf, acc[c], 0, 0, 0);
            }
        }
    }
    #pragma unroll
    for (int c = 0; c < 8; ++c) {
        float bv = bias[c * 16 + r];
        #pragma unroll
        for (int i = 0; i < 4; ++i) {
            int row = row0 + kg * 4 + i;
            hb[(size_t)row * 128 + c * 16 + r] = f2bf(fmaxf(acc[c][i] + bv, 0.f));
        }
    }
}

__global__ __launch_bounds__(256) void k_gemm2am(const ushort_t* __restrict__ Ab,
                                                 const ushort_t* __restrict__ Wt,
                                                 ushort_t* __restrict__ tb) {
    int gw = (blockIdx.x * 256 + threadIdx.x) >> 6;
    int lane = threadIdx.x & 63;
    if (gw >= Nn / 16) return;
    int row0 = gw * 16;
    int r = lane & 15;
    int kg = lane >> 4;
    f32x4 acc[4];
    #pragma unroll
    for (int c = 0; c < 4; ++c) acc[c] = (f32x4){0.f, 0.f, 0.f, 0.f};
    #pragma unroll
    for (int ks = 0; ks < 4; ++ks) {
        int kbase = ks * 32 + kg * 8;
        bf16x8 af = *reinterpret_cast<const bf16x8*>(Ab + (size_t)(row0 + r) * 128 + kbase);
        #pragma unroll
        for (int c = 0; c < 4; ++c) {
            bf16x8 bf = *reinterpret_cast<const bf16x8*>(Wt + (size_t)(c * 16 + r) * 128 + kbase);
            acc[c] = __builtin_amdgcn_mfma_f32_16x16x32_bf16(af, bf, acc[c], 0, 0, 0);
        }
    }
    #pragma unroll
    for (int c = 0; c < 4; ++c) {
        #pragma unroll
        for (int i = 0; i < 4; ++i) {
            int row = row0 + kg * 4 + i;
            tb[(size_t)row * 64 + c * 16 + r] = f2bf(acc[c][i]);
        }
    }
}

__global__ __launch_bounds__(256) void k_gemm2bm(const ushort_t* __restrict__ Ab,
                                                 const ushort_t* __restrict__ Wt,
                                                 const float* __restrict__ agg2,
                                                 const float* __restrict__ bias,
                                                 float* __restrict__ out) {
    int gw = (blockIdx.x * 256 + threadIdx.x) >> 6;
    int lane = threadIdx.x & 63;
    if (gw >= Nn / 16) return;
    int row0 = gw * 16;
    int r = lane & 15;
    int kg = lane >> 4;
    f32x4 acc[4];
    #pragma unroll
    for (int c = 0; c < 4; ++c) acc[c] = (f32x4){0.f, 0.f, 0.f, 0.f};
    #pragma unroll
    for (int ks = 0; ks < 4; ++ks) {
        int kbase = ks * 32 + kg * 8;
        bf16x8 af = *reinterpret_cast<const bf16x8*>(Ab + (size_t)(row0 + r) * 128 + kbase);
        #pragma unroll
        for (int c = 0; c < 4; ++c) {
            bf16x8 bf = *reinterpret_cast<const bf16x8*>(Wt + (size_t)(c * 16 + r) * 128 + kbase);
            acc[c] = __builtin_amdgcn_mfma_f32_16x16x32_bf16(af, bf, acc[c], 0, 0, 0);
        }
    }
    #pragma unroll
    for (int c = 0; c < 4; ++c) {
        float bv = bias[c * 16 + r];
        #pragma unroll
        for (int i = 0; i < 4; ++i) {
            int row = row0 + kg * 4 + i;
            size_t o = (size_t)row * 64 + c * 16 + r;
            out[o] = acc[c][i] + agg2[o] + bv;
        }
    }
}

// ---------------- in-place log_softmax over 64 classes ----------------

__global__ __launch_bounds__(256) void k_logsm(float* __restrict__ out) {
    int wid = (blockIdx.x * blockDim.x + threadIdx.x) >> 6;
    int lane = threadIdx.x & 63;
    if (wid >= Nn) return;
    float v = out[(size_t)wid * 64 + lane];
    float m = v;
    #pragma unroll
    for (int off = 32; off; off >>= 1) m = fmaxf(m, __shfl_xor(m, off));
    float ex = __expf(v - m);
    float s = ex;
    #pragma unroll
    for (int off = 32; off; off >>= 1) s += __shfl_xor(s, off);
    out[(size_t)wid * 64 + lane] = v - m - __logf(s);
}

// ---------------- launch ----------------

extern "C" void kernel_launch(void* const* d_in, const int* in_sizes, int n_in,
                              void* d_out, int out_size, void* d_ws, size_t ws_size,
                              hipStream_t stream) {
    const float* x   = (const float*)d_in[0];
    const int*   ei  = (const int*)d_in[1];
    const float* W1l = (const float*)d_in[2];
    const float* W1r = (const float*)d_in[3];
    const float* b1  = (const float*)d_in[4];
    const float* W2l = (const float*)d_in[5];
    const float* W2r = (const float*)d_in[6];
    const float* b2  = (const float*)d_in[7];
    float* out = (float*)d_out;

    char* ws = (char*)d_ws;
    int*      bstart = (int*)(ws + 0);             // NB+1 ints (region freed by deg removal)
    int*      rowptr = (int*)(ws + 800768);        // N+1 ints -> ends 1200772
    int*      csr    = (int*)(ws + 1201152);       // E ints -> ends 7601152
    ushort_t* xb     = (ushort_t*)(ws + 7601152);  // N*128 bf16 -> ends 33201152
    ushort_t* aggb   = (ushort_t*)(ws + 33201152); // N*128 bf16 -> ends 58801152
    ushort_t* w1lt   = (ushort_t*)(ws + 58801152); // 128*128 bf16
    ushort_t* w1rt   = (ushort_t*)(ws + 58833920);
    ushort_t* w2lt   = (ushort_t*)(ws + 58866688); // 64*128 bf16
    ushort_t* w2rt   = (ushort_t*)(ws + 58883072); // ends 58899456
    ushort_t* hb     = (ushort_t*)(ws + 84401152); // N*128 bf16 -> ends 110001152
    // CSR-build-phase aliases inside xb region (dead before k_cvt):
    uint2*    bedge  = (uint2*)(ws + 7601152);     // NB*BCAP uint2 = 14.45MB -> ends 22051840
    int*      bcur   = (int*)(ws + 22051840);      // NB ints -> ends 22052624
    // layer-2 aliases (disjoint lifetimes):
    ushort_t* tb     = (ushort_t*)(ws + 7601152);  // N*64 bf16 -> ends 20401152
    float*    agg2   = (float*)(ws + 22052864);    // N*64 f32 -> ends 47652864 (aggb dead by then)
    // high-water: 110001152 bytes

    const int* src = ei;
    const int* dst = ei + Ee;

    hipMemsetAsync(bcur, 0, NB * 4, stream);

    // CSR build: bucket-scatter -> bucket scan -> fused per-bucket hist+scan+fill
    k_bscatter<<<196, 1024, 0, stream>>>(src, dst, bcur, bedge);
    k_bscan<<<1, 256, 0, stream>>>(bcur, bstart, rowptr);
    k_fillB<<<NB, 1024, 0, stream>>>(bedge, bcur, bstart, rowptr, csr);

    // conversions
    k_cvt<<<(Nn * FIN / 4 + 255) / 256, 256, 0, stream>>>(x, xb, Nn * FIN / 4);
    k_cvtw<<<64, 256, 0, stream>>>(W1l, w1lt, 128);
    k_cvtw<<<64, 256, 0, stream>>>(W1r, w1rt, 128);
    k_cvtw<<<32, 256, 0, stream>>>(W2l, w2lt, 64);
    k_cvtw<<<32, 256, 0, stream>>>(W2r, w2rt, 64);

    // layer 1
    k_agg1<<<(Nn + 3) / 4, 256, 0, stream>>>(xb, rowptr, csr, aggb);
    k_gemm1m<<<(Nn / 16 + 3) / 4, 256, 0, stream>>>(aggb, xb, w1lt, w1rt, b1, hb);

    // layer 2 (reassociated)
    k_gemm2am<<<(Nn / 16 + 3) / 4, 256, 0, stream>>>(hb, w2lt, tb);
    k_agg2<<<(Nn + 3) / 4, 256, 0, stream>>>(tb, rowptr, csr, agg2);
    k_gemm2bm<<<(Nn / 16 + 3) / 4, 256, 0, stream>>>(hb, w2rt, agg2, b2, out);

    k_logsm<<<(Nn + 3) / 4, 256, 0, stream>>>(out);
}

// Round 17
// 245.572 us; speedup vs baseline: 3.2109x; 1.1651x over previous
//
#include <hip/hip_runtime.h>

#define Nn 100000
#define Ee 1600000
#define FIN 128
#define HID 128
#define CLS 64
#define NB 196       // dst buckets of 512 nodes (dst>>9)
#define BCAP 9216    // per-bucket edge capacity (mean 8163 + 11 sigma)

typedef unsigned short ushort_t;
typedef unsigned int uint_t;
typedef __attribute__((ext_vector_type(8))) short bf16x8;
typedef __attribute__((ext_vector_type(4))) float f32x4;

__device__ __forceinline__ ushort_t f2bf(float f) {   // RNE fp32->bf16
    uint_t u = __float_as_uint(f);
    return (ushort_t)((u + 0x7fffu + ((u >> 16) & 1u)) >> 16);
}
__device__ __forceinline__ float bflo(uint_t u) { return __uint_as_float(u << 16); }
__device__ __forceinline__ float bfhi(uint_t u) { return __uint_as_float(u & 0xffff0000u); }

// ---------------- bucketed edge scatter (src,dst) -> bedge[bucket*BCAP + i] ----------------

__global__ __launch_bounds__(1024) void k_bscatter(const int* __restrict__ src,
                                                   const int* __restrict__ dst,
                                                   int* __restrict__ bcur,
                                                   uint2* __restrict__ bedge) {
    __shared__ int h[NB];
    __shared__ int lbase[NB];
    int t = threadIdx.x;
    if (t < NB) h[t] = 0;
    __syncthreads();
    int base = blockIdx.x * 8192;
    int bk[8], loc[8];
    #pragma unroll
    for (int it = 0; it < 8; ++it) {
        int e = base + it * 1024 + t;
        if (e < Ee) {
            bk[it] = dst[e] >> 9;
            loc[it] = atomicAdd(&h[bk[it]], 1);
        }
    }
    __syncthreads();
    if (t < NB && h[t]) lbase[t] = atomicAdd(&bcur[t], h[t]);
    __syncthreads();
    #pragma unroll
    for (int it = 0; it < 8; ++it) {
        int e = base + it * 1024 + t;
        if (e < Ee) {
            int pos = lbase[bk[it]] + loc[it];
            if (pos < BCAP)   // statistically impossible overflow guard
                bedge[(size_t)bk[it] * BCAP + pos] = make_uint2((uint_t)src[e], (uint_t)dst[e]);
        }
    }
}

// exclusive scan of 196 bucket counts -> bstart[NB+1]; rowptr[Nn] = total
__global__ __launch_bounds__(256) void k_bscan(const int* __restrict__ bcur,
                                               int* __restrict__ bstart,
                                               int* __restrict__ rowptr) {
    __shared__ int s[256];
    int t = threadIdx.x;
    int v = (t < NB) ? min(bcur[t], BCAP) : 0;
    s[t] = v;
    __syncthreads();
    for (int off = 1; off < 256; off <<= 1) {
        int u = (t >= off) ? s[t - off] : 0;
        __syncthreads();
        s[t] += u;
        __syncthreads();
    }
    if (t < NB) bstart[t] = s[t] - v;
    if (t == NB - 1) { bstart[NB] = s[t]; rowptr[Nn] = s[t]; }
}

// fused per-bucket: LDS hist -> LDS scan -> rowptr write -> CSR fill
__global__ __launch_bounds__(1024) void k_fillB(const uint2* __restrict__ bedge,
                                                const int* __restrict__ bcur,
                                                const int* __restrict__ bstart,
                                                int* __restrict__ rowptr,
                                                int* __restrict__ csr) {
    __shared__ int h[512];
    __shared__ int off[512];
    int b = blockIdx.x, t = threadIdx.x;
    if (t < 512) h[t] = 0;
    __syncthreads();
    int n = min(bcur[b], BCAP);
    int node0 = b << 9;
    const uint2* be = bedge + (size_t)b * BCAP;
    for (int i = t; i < n; i += 1024)
        atomicAdd(&h[(int)be[i].y - node0], 1);
    __syncthreads();
    if (t < 512) off[t] = h[t];
    __syncthreads();
    for (int o = 1; o < 512; o <<= 1) {
        int v = (t < 512 && t >= o) ? off[t - o] : 0;
        __syncthreads();
        if (t < 512) off[t] += v;
        __syncthreads();
    }
    int base_ = bstart[b];
    if (t < 512) {
        int excl = off[t] - h[t];
        int node = node0 + t;
        if (node < Nn) rowptr[node] = base_ + excl;
        h[t] = excl;    // running local offset
    }
    __syncthreads();
    for (int i = t; i < n; i += 1024) {
        uint2 ed = be[i];
        int loc = atomicAdd(&h[(int)ed.y - node0], 1);
        csr[base_ + loc] = (int)ed.x;
    }
}

// ---------------- conversions ----------------

__global__ __launch_bounds__(256) void k_cvt(const float* __restrict__ in,
                                             ushort_t* __restrict__ outb, int n4) {
    int i = blockIdx.x * blockDim.x + threadIdx.x;
    if (i < n4) {
        float4 v = reinterpret_cast<const float4*>(in)[i];
        ushort4 o;
        o.x = f2bf(v.x); o.y = f2bf(v.y); o.z = f2bf(v.z); o.w = f2bf(v.w);
        reinterpret_cast<ushort4*>(outb)[i] = o;
    }
}

__global__ __launch_bounds__(256) void k_cvtw(const float* __restrict__ W,
                                              ushort_t* __restrict__ Wt, int Ncols) {
    int i = blockIdx.x * blockDim.x + threadIdx.x;
    if (i < 128 * Ncols) {
        int k = i / Ncols, n = i % Ncols;
        Wt[(size_t)n * 128 + k] = f2bf(W[i]);
    }
}

// ---------------- aggregation: full-row gather with scalar (saddr) addressing ----------------

__global__ __launch_bounds__(256) void k_agg1(const ushort_t* __restrict__ xb,
                                              const int* __restrict__ rowptr,
                                              const int* __restrict__ csr,
                                              ushort_t* __restrict__ outb) {
    int wid = (blockIdx.x * blockDim.x + threadIdx.x) >> 6;
    int lane = threadIdx.x & 63;
    if (wid >= Nn) return;
    int s0 = __builtin_amdgcn_readfirstlane(rowptr[wid]);
    int s1 = __builtin_amdgcn_readfirstlane(rowptr[wid + 1]);
    float ax = 0.f, ay = 0.f;
    int e = s0;
    for (; e + 8 <= s1; e += 8) {
        int idx[8];
        #pragma unroll
        for (int j = 0; j < 8; ++j) idx[j] = __builtin_amdgcn_readfirstlane(csr[e + j]);
        uint_t u[8];
        #pragma unroll
        for (int j = 0; j < 8; ++j)
            u[j] = *reinterpret_cast<const uint_t*>(xb + (size_t)idx[j] * 128 + lane * 2);
        #pragma unroll
        for (int j = 0; j < 8; ++j) { ax += bflo(u[j]); ay += bfhi(u[j]); }
    }
    for (; e < s1; ++e) {
        int s = __builtin_amdgcn_readfirstlane(csr[e]);
        uint_t u = *reinterpret_cast<const uint_t*>(xb + (size_t)s * 128 + lane * 2);
        ax += bflo(u); ay += bfhi(u);
    }
    float invd = (s1 > s0) ? 1.0f / (float)(s1 - s0) : 0.0f;
    uint_t o = (uint_t)f2bf(ax * invd) | ((uint_t)f2bf(ay * invd) << 16);
    *reinterpret_cast<uint_t*>(outb + (size_t)wid * 128 + lane * 2) = o;
}

__global__ __launch_bounds__(256) void k_agg2(const ushort_t* __restrict__ tb,
                                              const int* __restrict__ rowptr,
                                              const int* __restrict__ csr,
                                              float* __restrict__ out) {
    int wid = (blockIdx.x * blockDim.x + threadIdx.x) >> 6;
    int lane = threadIdx.x & 63;
    if (wid >= Nn) return;
    int s0 = __builtin_amdgcn_readfirstlane(rowptr[wid]);
    int s1 = __builtin_amdgcn_readfirstlane(rowptr[wid + 1]);
    float a = 0.f;
    int e = s0;
    for (; e + 8 <= s1; e += 8) {
        int idx[8];
        #pragma unroll
        for (int j = 0; j < 8; ++j) idx[j] = __builtin_amdgcn_readfirstlane(csr[e + j]);
        ushort_t u[8];
        #pragma unroll
        for (int j = 0; j < 8; ++j) u[j] = tb[(size_t)idx[j] * 64 + lane];
        #pragma unroll
        for (int j = 0; j < 8; ++j) a += __uint_as_float(((uint_t)u[j]) << 16);
    }
    for (; e < s1; ++e) {
        int s = __builtin_amdgcn_readfirstlane(csr[e]);
        a += __uint_as_float(((uint_t)tb[(size_t)s * 64 + lane]) << 16);
    }
    float invd = (s1 > s0) ? 1.0f / (float)(s1 - s0) : 0.0f;
    out[(size_t)wid * 64 + lane] = a * invd;
}

// ---------------- MFMA GEMMs (16x16x32 bf16) ----------------
// gemm1m: both W matrices (64KB > L1) staged in LDS with XOR swizzle
// (byte ^= (col&7)<<4): lanes r=0..7 hit distinct bank quads, r/r+8 2-way (free).
// A-frag: lane holds A[row0+(lane&15)][ks*32+(lane>>4)*8 .. +7]
// D: col=lane&15, row=(lane>>4)*4+reg   [verified: absmax unchanged]

__global__ __launch_bounds__(512) void k_gemm1m(const ushort_t* __restrict__ Ab0,
                                                const ushort_t* __restrict__ Ab1,
                                                const ushort_t* __restrict__ Wt0,
                                                const ushort_t* __restrict__ Wt1,
                                                const float* __restrict__ bias,
                                                ushort_t* __restrict__ hb) {
    __shared__ ushort_t lw[2 * 16384];   // 64KB: [pair][col][k] bf16, swizzled
    const int tid = threadIdx.x;
    char* lwc = reinterpret_cast<char*>(lw);
    #pragma unroll
    for (int i = 0; i < 8; ++i) {        // 4096 16B chunks / 512 threads
        int c = tid + i * 512;
        int pair = c >> 11;              // 2048 chunks per pair
        int col = (c & 2047) >> 4;       // 16 chunks per 256B row
        int kc = c & 15;
        const ushort_t* Wsrc = pair ? Wt1 : Wt0;
        uint4 v = *reinterpret_cast<const uint4*>(Wsrc + col * 128 + kc * 8);
        int dst = ((pair << 15) | (col << 8) | (kc << 4)) ^ ((col & 7) << 4);
        *reinterpret_cast<uint4*>(lwc + dst) = v;
    }
    __syncthreads();

    int gw = (blockIdx.x * 512 + tid) >> 6;
    int lane = tid & 63;
    if (gw >= Nn / 16) return;
    int row0 = gw * 16;
    int r = lane & 15;
    int kg = lane >> 4;
    f32x4 acc[8];
    #pragma unroll
    for (int c = 0; c < 8; ++c) acc[c] = (f32x4){0.f, 0.f, 0.f, 0.f};
    #pragma unroll
    for (int pair = 0; pair < 2; ++pair) {
        const ushort_t* A = pair ? Ab1 : Ab0;
        #pragma unroll
        for (int ks = 0; ks < 4; ++ks) {
            int kbase = ks * 32 + kg * 8;
            bf16x8 af = *reinterpret_cast<const bf16x8*>(A + (size_t)(row0 + r) * 128 + kbase);
            #pragma unroll
            for (int c = 0; c < 8; ++c) {
                int boff = ((pair << 15) | ((c * 16 + r) << 8) | (ks * 64 + kg * 16))
                           ^ ((r & 7) << 4);
                bf16x8 bf = *reinterpret_cast<const bf16x8*>(lwc + boff);
                acc[c] = __builtin_amdgcn_mfma_f32_16x16x32_bf16(af, bf, acc[c], 0, 0, 0);
            }
        }
    }
    #pragma unroll
    for (int c = 0; c < 8; ++c) {
        float bv = bias[c * 16 + r];
        #pragma unroll
        for (int i = 0; i < 4; ++i) {
            int row = row0 + kg * 4 + i;
            hb[(size_t)row * 128 + c * 16 + r] = f2bf(fmaxf(acc[c][i] + bv, 0.f));
        }
    }
}

__global__ __launch_bounds__(256) void k_gemm2am(const ushort_t* __restrict__ Ab,
                                                 const ushort_t* __restrict__ Wt,
                                                 ushort_t* __restrict__ tb) {
    int gw = (blockIdx.x * 256 + threadIdx.x) >> 6;
    int lane = threadIdx.x & 63;
    if (gw >= Nn / 16) return;
    int row0 = gw * 16;
    int r = lane & 15;
    int kg = lane >> 4;
    f32x4 acc[4];
    #pragma unroll
    for (int c = 0; c < 4; ++c) acc[c] = (f32x4){0.f, 0.f, 0.f, 0.f};
    #pragma unroll
    for (int ks = 0; ks < 4; ++ks) {
        int kbase = ks * 32 + kg * 8;
        bf16x8 af = *reinterpret_cast<const bf16x8*>(Ab + (size_t)(row0 + r) * 128 + kbase);
        #pragma unroll
        for (int c = 0; c < 4; ++c) {
            bf16x8 bf = *reinterpret_cast<const bf16x8*>(Wt + (size_t)(c * 16 + r) * 128 + kbase);
            acc[c] = __builtin_amdgcn_mfma_f32_16x16x32_bf16(af, bf, acc[c], 0, 0, 0);
        }
    }
    #pragma unroll
    for (int c = 0; c < 4; ++c) {
        #pragma unroll
        for (int i = 0; i < 4; ++i) {
            int row = row0 + kg * 4 + i;
            tb[(size_t)row * 64 + c * 16 + r] = f2bf(acc[c][i]);
        }
    }
}

__global__ __launch_bounds__(256) void k_gemm2bm(const ushort_t* __restrict__ Ab,
                                                 const ushort_t* __restrict__ Wt,
                                                 const float* __restrict__ agg2,
                                                 const float* __restrict__ bias,
                                                 float* __restrict__ out) {
    int gw = (blockIdx.x * 256 + threadIdx.x) >> 6;
    int lane = threadIdx.x & 63;
    if (gw >= Nn / 16) return;
    int row0 = gw * 16;
    int r = lane & 15;
    int kg = lane >> 4;
    f32x4 acc[4];
    #pragma unroll
    for (int c = 0; c < 4; ++c) acc[c] = (f32x4){0.f, 0.f, 0.f, 0.f};
    #pragma unroll
    for (int ks = 0; ks < 4; ++ks) {
        int kbase = ks * 32 + kg * 8;
        bf16x8 af = *reinterpret_cast<const bf16x8*>(Ab + (size_t)(row0 + r) * 128 + kbase);
        #pragma unroll
        for (int c = 0; c < 4; ++c) {
            bf16x8 bf = *reinterpret_cast<const bf16x8*>(Wt + (size_t)(c * 16 + r) * 128 + kbase);
            acc[c] = __builtin_amdgcn_mfma_f32_16x16x32_bf16(af, bf, acc[c], 0, 0, 0);
        }
    }
    #pragma unroll
    for (int c = 0; c < 4; ++c) {
        float bv = bias[c * 16 + r];
        #pragma unroll
        for (int i = 0; i < 4; ++i) {
            int row = row0 + kg * 4 + i;
            size_t o = (size_t)row * 64 + c * 16 + r;
            out[o] = acc[c][i] + agg2[o] + bv;
        }
    }
}

// ---------------- in-place log_softmax over 64 classes ----------------

__global__ __launch_bounds__(256) void k_logsm(float* __restrict__ out) {
    int wid = (blockIdx.x * blockDim.x + threadIdx.x) >> 6;
    int lane = threadIdx.x & 63;
    if (wid >= Nn) return;
    float v = out[(size_t)wid * 64 + lane];
    float m = v;
    #pragma unroll
    for (int off = 32; off; off >>= 1) m = fmaxf(m, __shfl_xor(m, off));
    float ex = __expf(v - m);
    float s = ex;
    #pragma unroll
    for (int off = 32; off; off >>= 1) s += __shfl_xor(s, off);
    out[(size_t)wid * 64 + lane] = v - m - __logf(s);
}

// ---------------- launch ----------------

extern "C" void kernel_launch(void* const* d_in, const int* in_sizes, int n_in,
                              void* d_out, int out_size, void* d_ws, size_t ws_size,
                              hipStream_t stream) {
    const float* x   = (const float*)d_in[0];
    const int*   ei  = (const int*)d_in[1];
    const float* W1l = (const float*)d_in[2];
    const float* W1r = (const float*)d_in[3];
    const float* b1  = (const float*)d_in[4];
    const float* W2l = (const float*)d_in[5];
    const float* W2r = (const float*)d_in[6];
    const float* b2  = (const float*)d_in[7];
    float* out = (float*)d_out;

    char* ws = (char*)d_ws;
    int*      bstart = (int*)(ws + 0);             // NB+1 ints
    int*      rowptr = (int*)(ws + 800768);        // N+1 ints -> ends 1200772
    int*      csr    = (int*)(ws + 1201152);       // E ints -> ends 7601152
    ushort_t* xb     = (ushort_t*)(ws + 7601152);  // N*128 bf16 -> ends 33201152
    ushort_t* aggb   = (ushort_t*)(ws + 33201152); // N*128 bf16 -> ends 58801152
    ushort_t* w1lt   = (ushort_t*)(ws + 58801152); // 128*128 bf16
    ushort_t* w1rt   = (ushort_t*)(ws + 58833920);
    ushort_t* w2lt   = (ushort_t*)(ws + 58866688); // 64*128 bf16
    ushort_t* w2rt   = (ushort_t*)(ws + 58883072); // ends 58899456
    ushort_t* hb     = (ushort_t*)(ws + 84401152); // N*128 bf16 -> ends 110001152
    // CSR-build-phase aliases inside xb region (dead before k_cvt):
    uint2*    bedge  = (uint2*)(ws + 7601152);     // NB*BCAP uint2 -> ends 22051840
    int*      bcur   = (int*)(ws + 22051840);      // NB ints -> ends 22052624
    // layer-2 aliases (disjoint lifetimes):
    ushort_t* tb     = (ushort_t*)(ws + 7601152);  // N*64 bf16 -> ends 20401152
    float*    agg2   = (float*)(ws + 22052864);    // N*64 f32 -> ends 47652864
    // high-water: 110001152 bytes

    const int* src = ei;
    const int* dst = ei + Ee;

    hipMemsetAsync(bcur, 0, NB * 4, stream);

    // CSR build
    k_bscatter<<<196, 1024, 0, stream>>>(src, dst, bcur, bedge);
    k_bscan<<<1, 256, 0, stream>>>(bcur, bstart, rowptr);
    k_fillB<<<NB, 1024, 0, stream>>>(bedge, bcur, bstart, rowptr, csr);

    // conversions
    k_cvt<<<(Nn * FIN / 4 + 255) / 256, 256, 0, stream>>>(x, xb, Nn * FIN / 4);
    k_cvtw<<<64, 256, 0, stream>>>(W1l, w1lt, 128);
    k_cvtw<<<64, 256, 0, stream>>>(W1r, w1rt, 128);
    k_cvtw<<<32, 256, 0, stream>>>(W2l, w2lt, 64);
    k_cvtw<<<32, 256, 0, stream>>>(W2r, w2rt, 64);

    // layer 1
    k_agg1<<<(Nn + 3) / 4, 256, 0, stream>>>(xb, rowptr, csr, aggb);
    k_gemm1m<<<(Nn / 16 + 7) / 8, 512, 0, stream>>>(aggb, xb, w1lt, w1rt, b1, hb);

    // layer 2 (reassociated)
    k_gemm2am<<<(Nn / 16 + 3) / 4, 256, 0, stream>>>(hb, w2lt, tb);
    k_agg2<<<(Nn + 3) / 4, 256, 0, stream>>>(tb, rowptr, csr, agg2);
    k_gemm2bm<<<(Nn / 16 + 3) / 4, 256, 0, stream>>>(hb, w2rt, agg2, b2, out);

    k_logsm<<<(Nn + 3) / 4, 256, 0, stream>>>(out);
}

// Round 18
// 233.765 us; speedup vs baseline: 3.3731x; 1.0505x over previous
//
#include <hip/hip_runtime.h>

#define Nn 100000
#define Ee 1600000
#define FIN 128
#define HID 128
#define CLS 64
#define NB 196       // dst buckets of 512 nodes (dst>>9)
#define BCAP 9216    // per-bucket edge capacity (mean 8163 + 11 sigma)

typedef unsigned short ushort_t;
typedef unsigned int uint_t;
typedef __attribute__((ext_vector_type(8))) short bf16x8;
typedef __attribute__((ext_vector_type(4))) float f32x4;

__device__ __forceinline__ ushort_t f2bf(float f) {   // RNE fp32->bf16
    uint_t u = __float_as_uint(f);
    return (ushort_t)((u + 0x7fffu + ((u >> 16) & 1u)) >> 16);
}
__device__ __forceinline__ float bflo(uint_t u) { return __uint_as_float(u << 16); }
__device__ __forceinline__ float bfhi(uint_t u) { return __uint_as_float(u & 0xffff0000u); }

// ---------------- bucketed edge scatter (src,dst) -> bedge[bucket*BCAP + i] ----------------

__global__ __launch_bounds__(1024) void k_bscatter(const int* __restrict__ src,
                                                   const int* __restrict__ dst,
                                                   int* __restrict__ bcur,
                                                   uint2* __restrict__ bedge) {
    __shared__ int h[NB];
    __shared__ int lbase[NB];
    int t = threadIdx.x;
    if (t < NB) h[t] = 0;
    __syncthreads();
    int base = blockIdx.x * 8192;
    int bk[8], loc[8];
    #pragma unroll
    for (int it = 0; it < 8; ++it) {
        int e = base + it * 1024 + t;
        if (e < Ee) {
            bk[it] = dst[e] >> 9;
            loc[it] = atomicAdd(&h[bk[it]], 1);
        }
    }
    __syncthreads();
    if (t < NB && h[t]) lbase[t] = atomicAdd(&bcur[t], h[t]);
    __syncthreads();
    #pragma unroll
    for (int it = 0; it < 8; ++it) {
        int e = base + it * 1024 + t;
        if (e < Ee) {
            int pos = lbase[bk[it]] + loc[it];
            if (pos < BCAP)   // statistically impossible overflow guard
                bedge[(size_t)bk[it] * BCAP + pos] = make_uint2((uint_t)src[e], (uint_t)dst[e]);
        }
    }
}

// exclusive scan of 196 bucket counts -> bstart[NB+1]; rowptr[Nn] = total
__global__ __launch_bounds__(256) void k_bscan(const int* __restrict__ bcur,
                                               int* __restrict__ bstart,
                                               int* __restrict__ rowptr) {
    __shared__ int s[256];
    int t = threadIdx.x;
    int v = (t < NB) ? min(bcur[t], BCAP) : 0;
    s[t] = v;
    __syncthreads();
    for (int off = 1; off < 256; off <<= 1) {
        int u = (t >= off) ? s[t - off] : 0;
        __syncthreads();
        s[t] += u;
        __syncthreads();
    }
    if (t < NB) bstart[t] = s[t] - v;
    if (t == NB - 1) { bstart[NB] = s[t]; rowptr[Nn] = s[t]; }
}

// fused per-bucket: LDS hist -> LDS scan -> rowptr write -> CSR fill
__global__ __launch_bounds__(1024) void k_fillB(const uint2* __restrict__ bedge,
                                                const int* __restrict__ bcur,
                                                const int* __restrict__ bstart,
                                                int* __restrict__ rowptr,
                                                int* __restrict__ csr) {
    __shared__ int h[512];
    __shared__ int off[512];
    int b = blockIdx.x, t = threadIdx.x;
    if (t < 512) h[t] = 0;
    __syncthreads();
    int n = min(bcur[b], BCAP);
    int node0 = b << 9;
    const uint2* be = bedge + (size_t)b * BCAP;
    for (int i = t; i < n; i += 1024)
        atomicAdd(&h[(int)be[i].y - node0], 1);
    __syncthreads();
    if (t < 512) off[t] = h[t];
    __syncthreads();
    for (int o = 1; o < 512; o <<= 1) {
        int v = (t < 512 && t >= o) ? off[t - o] : 0;
        __syncthreads();
        if (t < 512) off[t] += v;
        __syncthreads();
    }
    int base_ = bstart[b];
    if (t < 512) {
        int excl = off[t] - h[t];
        int node = node0 + t;
        if (node < Nn) rowptr[node] = base_ + excl;
        h[t] = excl;    // running local offset
    }
    __syncthreads();
    for (int i = t; i < n; i += 1024) {
        uint2 ed = be[i];
        int loc = atomicAdd(&h[(int)ed.y - node0], 1);
        csr[base_ + loc] = (int)ed.x;
    }
}

// ---------------- conversions ----------------

__global__ __launch_bounds__(256) void k_cvt(const float* __restrict__ in,
                                             ushort_t* __restrict__ outb, int n4) {
    int i = blockIdx.x * blockDim.x + threadIdx.x;
    if (i < n4) {
        float4 v = reinterpret_cast<const float4*>(in)[i];
        ushort4 o;
        o.x = f2bf(v.x); o.y = f2bf(v.y); o.z = f2bf(v.z); o.w = f2bf(v.w);
        reinterpret_cast<ushort4*>(outb)[i] = o;
    }
}

__global__ __launch_bounds__(256) void k_cvtw(const float* __restrict__ W,
                                              ushort_t* __restrict__ Wt, int Ncols) {
    int i = blockIdx.x * blockDim.x + threadIdx.x;
    if (i < 128 * Ncols) {
        int k = i / Ncols, n = i % Ncols;
        Wt[(size_t)n * 128 + k] = f2bf(W[i]);
    }
}

// ---------------- aggregation: saddr gather, x16 prefetch ----------------

__global__ __launch_bounds__(256) void k_agg1(const ushort_t* __restrict__ xb,
                                              const int* __restrict__ rowptr,
                                              const int* __restrict__ csr,
                                              ushort_t* __restrict__ outb) {
    int wid = (blockIdx.x * blockDim.x + threadIdx.x) >> 6;
    int lane = threadIdx.x & 63;
    if (wid >= Nn) return;
    int s0 = __builtin_amdgcn_readfirstlane(rowptr[wid]);
    int s1 = __builtin_amdgcn_readfirstlane(rowptr[wid + 1]);
    float ax = 0.f, ay = 0.f;
    int e = s0;
    for (; e + 16 <= s1; e += 16) {
        int idx[16];
        #pragma unroll
        for (int j = 0; j < 16; ++j) idx[j] = __builtin_amdgcn_readfirstlane(csr[e + j]);
        uint_t u[16];
        #pragma unroll
        for (int j = 0; j < 16; ++j)
            u[j] = *reinterpret_cast<const uint_t*>(xb + (size_t)idx[j] * 128 + lane * 2);
        #pragma unroll
        for (int j = 0; j < 16; ++j) { ax += bflo(u[j]); ay += bfhi(u[j]); }
    }
    for (; e + 8 <= s1; e += 8) {
        int idx[8];
        #pragma unroll
        for (int j = 0; j < 8; ++j) idx[j] = __builtin_amdgcn_readfirstlane(csr[e + j]);
        uint_t u[8];
        #pragma unroll
        for (int j = 0; j < 8; ++j)
            u[j] = *reinterpret_cast<const uint_t*>(xb + (size_t)idx[j] * 128 + lane * 2);
        #pragma unroll
        for (int j = 0; j < 8; ++j) { ax += bflo(u[j]); ay += bfhi(u[j]); }
    }
    for (; e < s1; ++e) {
        int s = __builtin_amdgcn_readfirstlane(csr[e]);
        uint_t u = *reinterpret_cast<const uint_t*>(xb + (size_t)s * 128 + lane * 2);
        ax += bflo(u); ay += bfhi(u);
    }
    float invd = (s1 > s0) ? 1.0f / (float)(s1 - s0) : 0.0f;
    uint_t o = (uint_t)f2bf(ax * invd) | ((uint_t)f2bf(ay * invd) << 16);
    *reinterpret_cast<uint_t*>(outb + (size_t)wid * 128 + lane * 2) = o;
}

__global__ __launch_bounds__(256) void k_agg2(const ushort_t* __restrict__ tb,
                                              const int* __restrict__ rowptr,
                                              const int* __restrict__ csr,
                                              float* __restrict__ out) {
    int wid = (blockIdx.x * blockDim.x + threadIdx.x) >> 6;
    int lane = threadIdx.x & 63;
    if (wid >= Nn) return;
    int s0 = __builtin_amdgcn_readfirstlane(rowptr[wid]);
    int s1 = __builtin_amdgcn_readfirstlane(rowptr[wid + 1]);
    float a = 0.f;
    int e = s0;
    for (; e + 16 <= s1; e += 16) {
        int idx[16];
        #pragma unroll
        for (int j = 0; j < 16; ++j) idx[j] = __builtin_amdgcn_readfirstlane(csr[e + j]);
        ushort_t u[16];
        #pragma unroll
        for (int j = 0; j < 16; ++j) u[j] = tb[(size_t)idx[j] * 64 + lane];
        #pragma unroll
        for (int j = 0; j < 16; ++j) a += __uint_as_float(((uint_t)u[j]) << 16);
    }
    for (; e + 8 <= s1; e += 8) {
        int idx[8];
        #pragma unroll
        for (int j = 0; j < 8; ++j) idx[j] = __builtin_amdgcn_readfirstlane(csr[e + j]);
        ushort_t u[8];
        #pragma unroll
        for (int j = 0; j < 8; ++j) u[j] = tb[(size_t)idx[j] * 64 + lane];
        #pragma unroll
        for (int j = 0; j < 8; ++j) a += __uint_as_float(((uint_t)u[j]) << 16);
    }
    for (; e < s1; ++e) {
        int s = __builtin_amdgcn_readfirstlane(csr[e]);
        a += __uint_as_float(((uint_t)tb[(size_t)s * 64 + lane]) << 16);
    }
    float invd = (s1 > s0) ? 1.0f / (float)(s1 - s0) : 0.0f;
    out[(size_t)wid * 64 + lane] = a * invd;
}

// ---------------- MFMA GEMMs (16x16x32 bf16) ----------------
// gemm1m: both W matrices (64KB > L1) staged in LDS with XOR swizzle.
// A-frag: lane holds A[row0+(lane&15)][ks*32+(lane>>4)*8 .. +7]
// D: col=lane&15, row=(lane>>4)*4+reg   [verified: absmax unchanged]

__global__ __launch_bounds__(512) void k_gemm1m(const ushort_t* __restrict__ Ab0,
                                                const ushort_t* __restrict__ Ab1,
                                                const ushort_t* __restrict__ Wt0,
                                                const ushort_t* __restrict__ Wt1,
                                                const float* __restrict__ bias,
                                                ushort_t* __restrict__ hb) {
    __shared__ ushort_t lw[2 * 16384];   // 64KB: [pair][col][k] bf16, swizzled
    const int tid = threadIdx.x;
    char* lwc = reinterpret_cast<char*>(lw);
    #pragma unroll
    for (int i = 0; i < 8; ++i) {        // 4096 16B chunks / 512 threads
        int c = tid + i * 512;
        int pair = c >> 11;
        int col = (c & 2047) >> 4;
        int kc = c & 15;
        const ushort_t* Wsrc = pair ? Wt1 : Wt0;
        uint4 v = *reinterpret_cast<const uint4*>(Wsrc + col * 128 + kc * 8);
        int dst = ((pair << 15) | (col << 8) | (kc << 4)) ^ ((col & 7) << 4);
        *reinterpret_cast<uint4*>(lwc + dst) = v;
    }
    __syncthreads();

    int gw = (blockIdx.x * 512 + tid) >> 6;
    int lane = tid & 63;
    if (gw >= Nn / 16) return;
    int row0 = gw * 16;
    int r = lane & 15;
    int kg = lane >> 4;
    f32x4 acc[8];
    #pragma unroll
    for (int c = 0; c < 8; ++c) acc[c] = (f32x4){0.f, 0.f, 0.f, 0.f};
    #pragma unroll
    for (int pair = 0; pair < 2; ++pair) {
        const ushort_t* A = pair ? Ab1 : Ab0;
        #pragma unroll
        for (int ks = 0; ks < 4; ++ks) {
            int kbase = ks * 32 + kg * 8;
            bf16x8 af = *reinterpret_cast<const bf16x8*>(A + (size_t)(row0 + r) * 128 + kbase);
            #pragma unroll
            for (int c = 0; c < 8; ++c) {
                int boff = ((pair << 15) | ((c * 16 + r) << 8) | (ks * 64 + kg * 16))
                           ^ ((r & 7) << 4);
                bf16x8 bf = *reinterpret_cast<const bf16x8*>(lwc + boff);
                acc[c] = __builtin_amdgcn_mfma_f32_16x16x32_bf16(af, bf, acc[c], 0, 0, 0);
            }
        }
    }
    #pragma unroll
    for (int c = 0; c < 8; ++c) {
        float bv = bias[c * 16 + r];
        #pragma unroll
        for (int i = 0; i < 4; ++i) {
            int row = row0 + kg * 4 + i;
            hb[(size_t)row * 128 + c * 16 + r] = f2bf(fmaxf(acc[c][i] + bv, 0.f));
        }
    }
}

// fused layer-2 projections: tb = bf16(hb@W2l); out = f32(hb@W2r)
// (one hb read feeds both; W matrices 16KB each, L1-resident)
__global__ __launch_bounds__(256) void k_gemm2f(const ushort_t* __restrict__ Ab,
                                                const ushort_t* __restrict__ Wtl,
                                                const ushort_t* __restrict__ Wtr,
                                                ushort_t* __restrict__ tb,
                                                float* __restrict__ outu) {
    int gw = (blockIdx.x * 256 + threadIdx.x) >> 6;
    int lane = threadIdx.x & 63;
    if (gw >= Nn / 16) return;
    int row0 = gw * 16;
    int r = lane & 15;
    int kg = lane >> 4;
    f32x4 accL[4], accR[4];
    #pragma unroll
    for (int c = 0; c < 4; ++c) {
        accL[c] = (f32x4){0.f, 0.f, 0.f, 0.f};
        accR[c] = (f32x4){0.f, 0.f, 0.f, 0.f};
    }
    #pragma unroll
    for (int ks = 0; ks < 4; ++ks) {
        int kbase = ks * 32 + kg * 8;
        bf16x8 af = *reinterpret_cast<const bf16x8*>(Ab + (size_t)(row0 + r) * 128 + kbase);
        #pragma unroll
        for (int c = 0; c < 4; ++c) {
            bf16x8 bl = *reinterpret_cast<const bf16x8*>(Wtl + (size_t)(c * 16 + r) * 128 + kbase);
            accL[c] = __builtin_amdgcn_mfma_f32_16x16x32_bf16(af, bl, accL[c], 0, 0, 0);
            bf16x8 br = *reinterpret_cast<const bf16x8*>(Wtr + (size_t)(c * 16 + r) * 128 + kbase);
            accR[c] = __builtin_amdgcn_mfma_f32_16x16x32_bf16(af, br, accR[c], 0, 0, 0);
        }
    }
    #pragma unroll
    for (int c = 0; c < 4; ++c) {
        #pragma unroll
        for (int i = 0; i < 4; ++i) {
            int row = row0 + kg * 4 + i;
            tb[(size_t)row * 64 + c * 16 + r] = f2bf(accL[c][i]);
            outu[(size_t)row * 64 + c * 16 + r] = accR[c][i];
        }
    }
}

// ---------------- fused add + log_softmax over 64 classes ----------------
// out = log_softmax(out + agg2 + bias)  (order (u+agg2)+bias preserved)

__global__ __launch_bounds__(256) void k_logsm(float* __restrict__ out,
                                               const float* __restrict__ agg2,
                                               const float* __restrict__ bias) {
    int wid = (blockIdx.x * blockDim.x + threadIdx.x) >> 6;
    int lane = threadIdx.x & 63;
    if (wid >= Nn) return;
    size_t o = (size_t)wid * 64 + lane;
    float v = (out[o] + agg2[o]) + bias[lane];
    float m = v;
    #pragma unroll
    for (int off = 32; off; off >>= 1) m = fmaxf(m, __shfl_xor(m, off));
    float ex = __expf(v - m);
    float s = ex;
    #pragma unroll
    for (int off = 32; off; off >>= 1) s += __shfl_xor(s, off);
    out[o] = v - m - __logf(s);
}

// ---------------- launch ----------------

extern "C" void kernel_launch(void* const* d_in, const int* in_sizes, int n_in,
                              void* d_out, int out_size, void* d_ws, size_t ws_size,
                              hipStream_t stream) {
    const float* x   = (const float*)d_in[0];
    const int*   ei  = (const int*)d_in[1];
    const float* W1l = (const float*)d_in[2];
    const float* W1r = (const float*)d_in[3];
    const float* b1  = (const float*)d_in[4];
    const float* W2l = (const float*)d_in[5];
    const float* W2r = (const float*)d_in[6];
    const float* b2  = (const float*)d_in[7];
    float* out = (float*)d_out;

    char* ws = (char*)d_ws;
    int*      bstart = (int*)(ws + 0);             // NB+1 ints
    int*      rowptr = (int*)(ws + 800768);        // N+1 ints -> ends 1200772
    int*      csr    = (int*)(ws + 1201152);       // E ints -> ends 7601152
    ushort_t* xb     = (ushort_t*)(ws + 7601152);  // N*128 bf16 -> ends 33201152
    ushort_t* aggb   = (ushort_t*)(ws + 33201152); // N*128 bf16 -> ends 58801152
    ushort_t* w1lt   = (ushort_t*)(ws + 58801152); // 128*128 bf16
    ushort_t* w1rt   = (ushort_t*)(ws + 58833920);
    ushort_t* w2lt   = (ushort_t*)(ws + 58866688); // 64*128 bf16
    ushort_t* w2rt   = (ushort_t*)(ws + 58883072); // ends 58899456
    ushort_t* hb     = (ushort_t*)(ws + 84401152); // N*128 bf16 -> ends 110001152
    // CSR-build-phase aliases inside xb region (dead before k_cvt):
    uint2*    bedge  = (uint2*)(ws + 7601152);     // NB*BCAP uint2 -> ends 22051840
    int*      bcur   = (int*)(ws + 22051840);      // NB ints -> ends 22052624
    // layer-2 aliases (disjoint lifetimes):
    ushort_t* tb     = (ushort_t*)(ws + 7601152);  // N*64 bf16 -> ends 20401152
    float*    agg2   = (float*)(ws + 22052864);    // N*64 f32 -> ends 47652864
    // high-water: 110001152 bytes

    const int* src = ei;
    const int* dst = ei + Ee;

    hipMemsetAsync(bcur, 0, NB * 4, stream);

    // CSR build
    k_bscatter<<<196, 1024, 0, stream>>>(src, dst, bcur, bedge);
    k_bscan<<<1, 256, 0, stream>>>(bcur, bstart, rowptr);
    k_fillB<<<NB, 1024, 0, stream>>>(bedge, bcur, bstart, rowptr, csr);

    // conversions
    k_cvt<<<(Nn * FIN / 4 + 255) / 256, 256, 0, stream>>>(x, xb, Nn * FIN / 4);
    k_cvtw<<<64, 256, 0, stream>>>(W1l, w1lt, 128);
    k_cvtw<<<64, 256, 0, stream>>>(W1r, w1rt, 128);
    k_cvtw<<<32, 256, 0, stream>>>(W2l, w2lt, 64);
    k_cvtw<<<32, 256, 0, stream>>>(W2r, w2rt, 64);

    // layer 1
    k_agg1<<<(Nn + 3) / 4, 256, 0, stream>>>(xb, rowptr, csr, aggb);
    k_gemm1m<<<(Nn / 16 + 7) / 8, 512, 0, stream>>>(aggb, xb, w1lt, w1rt, b1, hb);

    // layer 2 (reassociated, fused projections)
    k_gemm2f<<<(Nn / 16 + 3) / 4, 256, 0, stream>>>(hb, w2lt, w2rt, tb, out);
    k_agg2<<<(Nn + 3) / 4, 256, 0, stream>>>(tb, rowptr, csr, agg2);
    k_logsm<<<(Nn + 3) / 4, 256, 0, stream>>>(out, agg2, b2);
}

// Round 19
// 210.241 us; speedup vs baseline: 3.7505x; 1.1119x over previous
//
#include <hip/hip_runtime.h>

#define Nn 100000
#define Ee 1600000
#define FIN 128
#define HID 128
#define CLS 64
#define NB 196       // dst buckets of 512 nodes (dst>>9)
#define BCAP 9216    // per-bucket edge capacity (mean 8163 + 11 sigma)

typedef unsigned short ushort_t;
typedef unsigned int uint_t;
typedef __attribute__((ext_vector_type(8))) short bf16x8;
typedef __attribute__((ext_vector_type(4))) float f32x4;

__device__ __forceinline__ ushort_t f2bf(float f) {   // RNE fp32->bf16
    uint_t u = __float_as_uint(f);
    return (ushort_t)((u + 0x7fffu + ((u >> 16) & 1u)) >> 16);
}
__device__ __forceinline__ float bflo(uint_t u) { return __uint_as_float(u << 16); }
__device__ __forceinline__ float bfhi(uint_t u) { return __uint_as_float(u & 0xffff0000u); }

// ---------------- combined front kernel ----------------
// blocks [0,196): bucketed edge scatter; [196,3321): x->bf16 cvt;
// [3321,3369): weight transpose+cvt. All jobs independent; running them in
// one dispatch overlaps latency-bound scatter with BW-bound conversion.

__global__ __launch_bounds__(1024) void k_front(const int* __restrict__ src,
                                                const int* __restrict__ dst,
                                                int* __restrict__ bcur,
                                                uint2* __restrict__ bedge,
                                                const float* __restrict__ x,
                                                ushort_t* __restrict__ xb,
                                                const float* __restrict__ W1l,
                                                const float* __restrict__ W1r,
                                                const float* __restrict__ W2l,
                                                const float* __restrict__ W2r,
                                                ushort_t* __restrict__ w1lt,
                                                ushort_t* __restrict__ w1rt,
                                                ushort_t* __restrict__ w2lt,
                                                ushort_t* __restrict__ w2rt) {
    __shared__ int h[NB];
    __shared__ int lbase[NB];
    int b = blockIdx.x;
    int t = threadIdx.x;
    if (b < NB) {
        // ---- bucketed edge scatter ----
        if (t < NB) h[t] = 0;
        __syncthreads();
        int base = b * 8192;
        int bk[8], loc[8];
        #pragma unroll
        for (int it = 0; it < 8; ++it) {
            int e = base + it * 1024 + t;
            if (e < Ee) {
                bk[it] = dst[e] >> 9;
                loc[it] = atomicAdd(&h[bk[it]], 1);
            }
        }
        __syncthreads();
        if (t < NB && h[t]) lbase[t] = atomicAdd(&bcur[t], h[t]);
        __syncthreads();
        #pragma unroll
        for (int it = 0; it < 8; ++it) {
            int e = base + it * 1024 + t;
            if (e < Ee) {
                int pos = lbase[bk[it]] + loc[it];
                if (pos < BCAP)   // statistically impossible overflow guard
                    bedge[(size_t)bk[it] * BCAP + pos] = make_uint2((uint_t)src[e], (uint_t)dst[e]);
            }
        }
    } else if (b < NB + 3125) {
        // ---- x (f32) -> xb (bf16), float4-vectorized; 3125*1024 = Nn*FIN/4 ----
        int i = (b - NB) * 1024 + t;
        float4 v = reinterpret_cast<const float4*>(x)[i];
        ushort4 o;
        o.x = f2bf(v.x); o.y = f2bf(v.y); o.z = f2bf(v.z); o.w = f2bf(v.w);
        reinterpret_cast<ushort4*>(xb)[i] = o;
    } else {
        // ---- weight transpose + cvt: W[k][n] f32 -> Wt[n][k] bf16 ----
        int j = b - (NB + 3125);
        const float* Wsrc; ushort_t* Wdst; int Ncols; int cb;
        if (j < 16)      { Wsrc = W1l; Wdst = w1lt; Ncols = 128; cb = j; }
        else if (j < 32) { Wsrc = W1r; Wdst = w1rt; Ncols = 128; cb = j - 16; }
        else if (j < 40) { Wsrc = W2l; Wdst = w2lt; Ncols = 64;  cb = j - 32; }
        else             { Wsrc = W2r; Wdst = w2rt; Ncols = 64;  cb = j - 40; }
        int i = cb * 1024 + t;
        if (i < 128 * Ncols) {
            int k = i / Ncols, n = i % Ncols;
            Wdst[(size_t)n * 128 + k] = f2bf(Wsrc[i]);
        }
    }
}

// exclusive scan of 196 bucket counts -> bstart[NB+1]; rowptr[Nn] = total
__global__ __launch_bounds__(256) void k_bscan(const int* __restrict__ bcur,
                                               int* __restrict__ bstart,
                                               int* __restrict__ rowptr) {
    __shared__ int s[256];
    int t = threadIdx.x;
    int v = (t < NB) ? min(bcur[t], BCAP) : 0;
    s[t] = v;
    __syncthreads();
    for (int off = 1; off < 256; off <<= 1) {
        int u = (t >= off) ? s[t - off] : 0;
        __syncthreads();
        s[t] += u;
        __syncthreads();
    }
    if (t < NB) bstart[t] = s[t] - v;
    if (t == NB - 1) { bstart[NB] = s[t]; rowptr[Nn] = s[t]; }
}

// fused per-bucket: LDS hist -> LDS scan -> rowptr write -> CSR fill
__global__ __launch_bounds__(1024) void k_fillB(const uint2* __restrict__ bedge,
                                                const int* __restrict__ bcur,
                                                const int* __restrict__ bstart,
                                                int* __restrict__ rowptr,
                                                int* __restrict__ csr) {
    __shared__ int h[512];
    __shared__ int off[512];
    int b = blockIdx.x, t = threadIdx.x;
    if (t < 512) h[t] = 0;
    __syncthreads();
    int n = min(bcur[b], BCAP);
    int node0 = b << 9;
    const uint2* be = bedge + (size_t)b * BCAP;
    for (int i = t; i < n; i += 1024)
        atomicAdd(&h[(int)be[i].y - node0], 1);
    __syncthreads();
    if (t < 512) off[t] = h[t];
    __syncthreads();
    for (int o = 1; o < 512; o <<= 1) {
        int v = (t < 512 && t >= o) ? off[t - o] : 0;
        __syncthreads();
        if (t < 512) off[t] += v;
        __syncthreads();
    }
    int base_ = bstart[b];
    if (t < 512) {
        int excl = off[t] - h[t];
        int node = node0 + t;
        if (node < Nn) rowptr[node] = base_ + excl;
        h[t] = excl;    // running local offset
    }
    __syncthreads();
    for (int i = t; i < n; i += 1024) {
        uint2 ed = be[i];
        int loc = atomicAdd(&h[(int)ed.y - node0], 1);
        csr[base_ + loc] = (int)ed.x;
    }
}

// ---------------- aggregation: saddr gather, x16 prefetch ----------------

__global__ __launch_bounds__(256) void k_agg1(const ushort_t* __restrict__ xb,
                                              const int* __restrict__ rowptr,
                                              const int* __restrict__ csr,
                                              ushort_t* __restrict__ outb) {
    int wid = (blockIdx.x * blockDim.x + threadIdx.x) >> 6;
    int lane = threadIdx.x & 63;
    if (wid >= Nn) return;
    int s0 = __builtin_amdgcn_readfirstlane(rowptr[wid]);
    int s1 = __builtin_amdgcn_readfirstlane(rowptr[wid + 1]);
    float ax = 0.f, ay = 0.f;
    int e = s0;
    for (; e + 16 <= s1; e += 16) {
        int idx[16];
        #pragma unroll
        for (int j = 0; j < 16; ++j) idx[j] = __builtin_amdgcn_readfirstlane(csr[e + j]);
        uint_t u[16];
        #pragma unroll
        for (int j = 0; j < 16; ++j)
            u[j] = *reinterpret_cast<const uint_t*>(xb + (size_t)idx[j] * 128 + lane * 2);
        #pragma unroll
        for (int j = 0; j < 16; ++j) { ax += bflo(u[j]); ay += bfhi(u[j]); }
    }
    for (; e + 8 <= s1; e += 8) {
        int idx[8];
        #pragma unroll
        for (int j = 0; j < 8; ++j) idx[j] = __builtin_amdgcn_readfirstlane(csr[e + j]);
        uint_t u[8];
        #pragma unroll
        for (int j = 0; j < 8; ++j)
            u[j] = *reinterpret_cast<const uint_t*>(xb + (size_t)idx[j] * 128 + lane * 2);
        #pragma unroll
        for (int j = 0; j < 8; ++j) { ax += bflo(u[j]); ay += bfhi(u[j]); }
    }
    for (; e < s1; ++e) {
        int s = __builtin_amdgcn_readfirstlane(csr[e]);
        uint_t u = *reinterpret_cast<const uint_t*>(xb + (size_t)s * 128 + lane * 2);
        ax += bflo(u); ay += bfhi(u);
    }
    float invd = (s1 > s0) ? 1.0f / (float)(s1 - s0) : 0.0f;
    uint_t o = (uint_t)f2bf(ax * invd) | ((uint_t)f2bf(ay * invd) << 16);
    *reinterpret_cast<uint_t*>(outb + (size_t)wid * 128 + lane * 2) = o;
}

// ---------------- MFMA GEMMs (16x16x32 bf16) ----------------
// gemm1m: both W matrices (64KB > L1) staged in LDS with XOR swizzle.
// A-frag: lane holds A[row0+(lane&15)][ks*32+(lane>>4)*8 .. +7]
// D: col=lane&15, row=(lane>>4)*4+reg   [verified: absmax unchanged]

__global__ __launch_bounds__(512) void k_gemm1m(const ushort_t* __restrict__ Ab0,
                                                const ushort_t* __restrict__ Ab1,
                                                const ushort_t* __restrict__ Wt0,
                                                const ushort_t* __restrict__ Wt1,
                                                const float* __restrict__ bias,
                                                ushort_t* __restrict__ hb) {
    __shared__ ushort_t lw[2 * 16384];   // 64KB: [pair][col][k] bf16, swizzled
    const int tid = threadIdx.x;
    char* lwc = reinterpret_cast<char*>(lw);
    #pragma unroll
    for (int i = 0; i < 8; ++i) {        // 4096 16B chunks / 512 threads
        int c = tid + i * 512;
        int pair = c >> 11;
        int col = (c & 2047) >> 4;
        int kc = c & 15;
        const ushort_t* Wsrc = pair ? Wt1 : Wt0;
        uint4 v = *reinterpret_cast<const uint4*>(Wsrc + col * 128 + kc * 8);
        int dst = ((pair << 15) | (col << 8) | (kc << 4)) ^ ((col & 7) << 4);
        *reinterpret_cast<uint4*>(lwc + dst) = v;
    }
    __syncthreads();

    int gw = (blockIdx.x * 512 + tid) >> 6;
    int lane = tid & 63;
    if (gw >= Nn / 16) return;
    int row0 = gw * 16;
    int r = lane & 15;
    int kg = lane >> 4;
    f32x4 acc[8];
    #pragma unroll
    for (int c = 0; c < 8; ++c) acc[c] = (f32x4){0.f, 0.f, 0.f, 0.f};
    #pragma unroll
    for (int pair = 0; pair < 2; ++pair) {
        const ushort_t* A = pair ? Ab1 : Ab0;
        #pragma unroll
        for (int ks = 0; ks < 4; ++ks) {
            int kbase = ks * 32 + kg * 8;
            bf16x8 af = *reinterpret_cast<const bf16x8*>(A + (size_t)(row0 + r) * 128 + kbase);
            #pragma unroll
            for (int c = 0; c < 8; ++c) {
                int boff = ((pair << 15) | ((c * 16 + r) << 8) | (ks * 64 + kg * 16))
                           ^ ((r & 7) << 4);
                bf16x8 bf = *reinterpret_cast<const bf16x8*>(lwc + boff);
                acc[c] = __builtin_amdgcn_mfma_f32_16x16x32_bf16(af, bf, acc[c], 0, 0, 0);
            }
        }
    }
    #pragma unroll
    for (int c = 0; c < 8; ++c) {
        float bv = bias[c * 16 + r];
        #pragma unroll
        for (int i = 0; i < 4; ++i) {
            int row = row0 + kg * 4 + i;
            hb[(size_t)row * 128 + c * 16 + r] = f2bf(fmaxf(acc[c][i] + bv, 0.f));
        }
    }
}

// fused layer-2 projections: tb = bf16(hb@W2l); out = f32(hb@W2r)
__global__ __launch_bounds__(256) void k_gemm2f(const ushort_t* __restrict__ Ab,
                                                const ushort_t* __restrict__ Wtl,
                                                const ushort_t* __restrict__ Wtr,
                                                ushort_t* __restrict__ tb,
                                                float* __restrict__ outu) {
    int gw = (blockIdx.x * 256 + threadIdx.x) >> 6;
    int lane = threadIdx.x & 63;
    if (gw >= Nn / 16) return;
    int row0 = gw * 16;
    int r = lane & 15;
    int kg = lane >> 4;
    f32x4 accL[4], accR[4];
    #pragma unroll
    for (int c = 0; c < 4; ++c) {
        accL[c] = (f32x4){0.f, 0.f, 0.f, 0.f};
        accR[c] = (f32x4){0.f, 0.f, 0.f, 0.f};
    }
    #pragma unroll
    for (int ks = 0; ks < 4; ++ks) {
        int kbase = ks * 32 + kg * 8;
        bf16x8 af = *reinterpret_cast<const bf16x8*>(Ab + (size_t)(row0 + r) * 128 + kbase);
        #pragma unroll
        for (int c = 0; c < 4; ++c) {
            bf16x8 bl = *reinterpret_cast<const bf16x8*>(Wtl + (size_t)(c * 16 + r) * 128 + kbase);
            accL[c] = __builtin_amdgcn_mfma_f32_16x16x32_bf16(af, bl, accL[c], 0, 0, 0);
            bf16x8 br = *reinterpret_cast<const bf16x8*>(Wtr + (size_t)(c * 16 + r) * 128 + kbase);
            accR[c] = __builtin_amdgcn_mfma_f32_16x16x32_bf16(af, br, accR[c], 0, 0, 0);
        }
    }
    #pragma unroll
    for (int c = 0; c < 4; ++c) {
        #pragma unroll
        for (int i = 0; i < 4; ++i) {
            int row = row0 + kg * 4 + i;
            tb[(size_t)row * 64 + c * 16 + r] = f2bf(accL[c][i]);
            outu[(size_t)row * 64 + c * 16 + r] = accR[c][i];
        }
    }
}

// ---------------- fused agg2-gather + add + log_softmax ----------------
// out = log_softmax(out + mean_gather(tb) + bias); gather order = old k_agg2,
// combine order (u + a*invd) + bias = old two-kernel path (bitwise same).

__global__ __launch_bounds__(256) void k_logsm(float* __restrict__ out,
                                               const ushort_t* __restrict__ tb,
                                               const int* __restrict__ rowptr,
                                               const int* __restrict__ csr,
                                               const float* __restrict__ bias) {
    int wid = (blockIdx.x * blockDim.x + threadIdx.x) >> 6;
    int lane = threadIdx.x & 63;
    if (wid >= Nn) return;
    int s0 = __builtin_amdgcn_readfirstlane(rowptr[wid]);
    int s1 = __builtin_amdgcn_readfirstlane(rowptr[wid + 1]);
    float a = 0.f;
    int e = s0;
    for (; e + 16 <= s1; e += 16) {
        int idx[16];
        #pragma unroll
        for (int j = 0; j < 16; ++j) idx[j] = __builtin_amdgcn_readfirstlane(csr[e + j]);
        ushort_t u[16];
        #pragma unroll
        for (int j = 0; j < 16; ++j) u[j] = tb[(size_t)idx[j] * 64 + lane];
        #pragma unroll
        for (int j = 0; j < 16; ++j) a += __uint_as_float(((uint_t)u[j]) << 16);
    }
    for (; e + 8 <= s1; e += 8) {
        int idx[8];
        #pragma unroll
        for (int j = 0; j < 8; ++j) idx[j] = __builtin_amdgcn_readfirstlane(csr[e + j]);
        ushort_t u[8];
        #pragma unroll
        for (int j = 0; j < 8; ++j) u[j] = tb[(size_t)idx[j] * 64 + lane];
        #pragma unroll
        for (int j = 0; j < 8; ++j) a += __uint_as_float(((uint_t)u[j]) << 16);
    }
    for (; e < s1; ++e) {
        int s = __builtin_amdgcn_readfirstlane(csr[e]);
        a += __uint_as_float(((uint_t)tb[(size_t)s * 64 + lane]) << 16);
    }
    float invd = (s1 > s0) ? 1.0f / (float)(s1 - s0) : 0.0f;
    size_t o = (size_t)wid * 64 + lane;
    float v = (out[o] + a * invd) + bias[lane];
    float m = v;
    #pragma unroll
    for (int off = 32; off; off >>= 1) m = fmaxf(m, __shfl_xor(m, off));
    float ex = __expf(v - m);
    float s_ = ex;
    #pragma unroll
    for (int off = 32; off; off >>= 1) s_ += __shfl_xor(s_, off);
    out[o] = v - m - __logf(s_);
}

// ---------------- launch ----------------

extern "C" void kernel_launch(void* const* d_in, const int* in_sizes, int n_in,
                              void* d_out, int out_size, void* d_ws, size_t ws_size,
                              hipStream_t stream) {
    const float* x   = (const float*)d_in[0];
    const int*   ei  = (const int*)d_in[1];
    const float* W1l = (const float*)d_in[2];
    const float* W1r = (const float*)d_in[3];
    const float* b1  = (const float*)d_in[4];
    const float* W2l = (const float*)d_in[5];
    const float* W2r = (const float*)d_in[6];
    const float* b2  = (const float*)d_in[7];
    float* out = (float*)d_out;

    char* ws = (char*)d_ws;
    int*      bstart = (int*)(ws + 0);             // NB+1 ints
    int*      rowptr = (int*)(ws + 800768);        // N+1 ints -> ends 1200772
    int*      csr    = (int*)(ws + 1201152);       // E ints -> ends 7601152
    ushort_t* xb     = (ushort_t*)(ws + 7601152);  // N*128 bf16 -> ends 33201152
    ushort_t* aggb   = (ushort_t*)(ws + 33201152); // N*128 bf16 -> ends 58801152
    ushort_t* w1lt   = (ushort_t*)(ws + 58801152); // 128*128 bf16
    ushort_t* w1rt   = (ushort_t*)(ws + 58833920);
    ushort_t* w2lt   = (ushort_t*)(ws + 58866688); // 64*128 bf16
    ushort_t* w2rt   = (ushort_t*)(ws + 58883072); // ends 58899456
    uint2*    bedge  = (uint2*)(ws + 60000000);    // NB*BCAP uint2 -> ends 74450688
    int*      bcur   = (int*)(ws + 74450688);      // NB ints -> ends 74451472
    ushort_t* hb     = (ushort_t*)(ws + 84401152); // N*128 bf16 -> ends 110001152
    // layer-2 alias (xb dead after k_gemm1m):
    ushort_t* tb     = (ushort_t*)(ws + 7601152);  // N*64 bf16 -> ends 20401152
    // high-water: 110001152 bytes

    const int* src = ei;
    const int* dst = ei + Ee;

    hipMemsetAsync(bcur, 0, NB * 4, stream);

    // front: edge scatter + x cvt + weight cvt (independent, one dispatch)
    k_front<<<NB + 3125 + 48, 1024, 0, stream>>>(src, dst, bcur, bedge, x, xb,
                                                 W1l, W1r, W2l, W2r,
                                                 w1lt, w1rt, w2lt, w2rt);
    k_bscan<<<1, 256, 0, stream>>>(bcur, bstart, rowptr);
    k_fillB<<<NB, 1024, 0, stream>>>(bedge, bcur, bstart, rowptr, csr);

    // layer 1
    k_agg1<<<(Nn + 3) / 4, 256, 0, stream>>>(xb, rowptr, csr, aggb);
    k_gemm1m<<<(Nn / 16 + 7) / 8, 512, 0, stream>>>(aggb, xb, w1lt, w1rt, b1, hb);

    // layer 2 (reassociated, fused projections; agg2 fused into logsm)
    k_gemm2f<<<(Nn / 16 + 3) / 4, 256, 0, stream>>>(hb, w2lt, w2rt, tb, out);
    k_logsm<<<(Nn + 3) / 4, 256, 0, stream>>>(out, tb, rowptr, csr, b2);
}

// Round 20
// 198.695 us; speedup vs baseline: 3.9685x; 1.0581x over previous
//
#include <hip/hip_runtime.h>

#define Nn 100000
#define Ee 1600000
#define FIN 128
#define HID 128
#define CLS 64
#define NB 196       // dst buckets of 512 nodes (dst>>9)
#define BCAP 9216    // per-bucket edge capacity (mean 8163 + 11 sigma)

typedef unsigned short ushort_t;
typedef unsigned char uchar_t;
typedef unsigned int uint_t;
typedef __attribute__((ext_vector_type(8))) short bf16x8;
typedef __attribute__((ext_vector_type(4))) float f32x4;
typedef __attribute__((ext_vector_type(2))) float f32x2;

__device__ __forceinline__ ushort_t f2bf(float f) {   // RNE fp32->bf16
    uint_t u = __float_as_uint(f);
    return (ushort_t)((u + 0x7fffu + ((u >> 16) & 1u)) >> 16);
}
__device__ __forceinline__ float bflo(uint_t u) { return __uint_as_float(u << 16); }
__device__ __forceinline__ float bfhi(uint_t u) { return __uint_as_float(u & 0xffff0000u); }

// ---------------- combined front kernel ----------------
// blocks [0,196): bucketed edge scatter; [196,3321): x -> {bf16 xb, fp8 xq};
// [3321,3369): weight transpose+cvt.

__global__ __launch_bounds__(1024) void k_front(const int* __restrict__ src,
                                                const int* __restrict__ dst,
                                                int* __restrict__ bcur,
                                                uint2* __restrict__ bedge,
                                                const float* __restrict__ x,
                                                ushort_t* __restrict__ xb,
                                                uint_t* __restrict__ xq,
                                                const float* __restrict__ W1l,
                                                const float* __restrict__ W1r,
                                                const float* __restrict__ W2l,
                                                const float* __restrict__ W2r,
                                                ushort_t* __restrict__ w1lt,
                                                ushort_t* __restrict__ w1rt,
                                                ushort_t* __restrict__ w2lt,
                                                ushort_t* __restrict__ w2rt) {
    __shared__ int h[NB];
    __shared__ int lbase[NB];
    int b = blockIdx.x;
    int t = threadIdx.x;
    if (b < NB) {
        // ---- bucketed edge scatter ----
        if (t < NB) h[t] = 0;
        __syncthreads();
        int base = b * 8192;
        int bk[8], loc[8];
        #pragma unroll
        for (int it = 0; it < 8; ++it) {
            int e = base + it * 1024 + t;
            if (e < Ee) {
                bk[it] = dst[e] >> 9;
                loc[it] = atomicAdd(&h[bk[it]], 1);
            }
        }
        __syncthreads();
        if (t < NB && h[t]) lbase[t] = atomicAdd(&bcur[t], h[t]);
        __syncthreads();
        #pragma unroll
        for (int it = 0; it < 8; ++it) {
            int e = base + it * 1024 + t;
            if (e < Ee) {
                int pos = lbase[bk[it]] + loc[it];
                if (pos < BCAP)   // statistically impossible overflow guard
                    bedge[(size_t)bk[it] * BCAP + pos] = make_uint2((uint_t)src[e], (uint_t)dst[e]);
            }
        }
    } else if (b < NB + 3125) {
        // ---- x (f32) -> xb (bf16) + xq (fp8 e4m3); 3125*1024 = Nn*FIN/4 ----
        int i = (b - NB) * 1024 + t;
        float4 v = reinterpret_cast<const float4*>(x)[i];
        ushort4 o;
        o.x = f2bf(v.x); o.y = f2bf(v.y); o.z = f2bf(v.z); o.w = f2bf(v.w);
        reinterpret_cast<ushort4*>(xb)[i] = o;
        int q = __builtin_amdgcn_cvt_pk_fp8_f32(v.x, v.y, 0, false);
        q = __builtin_amdgcn_cvt_pk_fp8_f32(v.z, v.w, q, true);
        xq[i] = (uint_t)q;
    } else {
        // ---- weight transpose + cvt: W[k][n] f32 -> Wt[n][k] bf16 ----
        int j = b - (NB + 3125);
        const float* Wsrc; ushort_t* Wdst; int Ncols; int cb;
        if (j < 16)      { Wsrc = W1l; Wdst = w1lt; Ncols = 128; cb = j; }
        else if (j < 32) { Wsrc = W1r; Wdst = w1rt; Ncols = 128; cb = j - 16; }
        else if (j < 40) { Wsrc = W2l; Wdst = w2lt; Ncols = 64;  cb = j - 32; }
        else             { Wsrc = W2r; Wdst = w2rt; Ncols = 64;  cb = j - 40; }
        int i = cb * 1024 + t;
        if (i < 128 * Ncols) {
            int k = i / Ncols, n = i % Ncols;
            Wdst[(size_t)n * 128 + k] = f2bf(Wsrc[i]);
        }
    }
}

// fused per-bucket: bucket scan (from bcur) -> LDS hist -> LDS scan ->
// rowptr write -> CSR fill
__global__ __launch_bounds__(1024) void k_fillB(const uint2* __restrict__ bedge,
                                                const int* __restrict__ bcur,
                                                int* __restrict__ rowptr,
                                                int* __restrict__ csr) {
    __shared__ int h[512];
    __shared__ int off[512];
    __shared__ int sbase;
    int b = blockIdx.x, t = threadIdx.x;
    // bucket prefix scan (each block computes independently from read-only bcur)
    if (t < 256) off[t] = (t < NB) ? min(bcur[t], BCAP) : 0;
    __syncthreads();
    for (int o = 1; o < 256; o <<= 1) {
        int v = (t < 256 && t >= o) ? off[t - o] : 0;
        __syncthreads();
        if (t < 256) off[t] += v;
        __syncthreads();
    }
    if (t == 0) sbase = off[b] - min(bcur[b], BCAP);
    if (b == NB - 1 && t == 0) rowptr[Nn] = off[NB - 1];
    __syncthreads();
    int base_ = sbase;
    int n = min(bcur[b], BCAP);
    int node0 = b << 9;
    const uint2* be = bedge + (size_t)b * BCAP;
    if (t < 512) h[t] = 0;
    __syncthreads();
    for (int i = t; i < n; i += 1024)
        atomicAdd(&h[(int)be[i].y - node0], 1);
    __syncthreads();
    if (t < 512) off[t] = h[t];
    __syncthreads();
    for (int o = 1; o < 512; o <<= 1) {
        int v = (t < 512 && t >= o) ? off[t - o] : 0;
        __syncthreads();
        if (t < 512) off[t] += v;
        __syncthreads();
    }
    if (t < 512) {
        int excl = off[t] - h[t];
        int node = node0 + t;
        if (node < Nn) rowptr[node] = base_ + excl;
        h[t] = excl;    // running local offset
    }
    __syncthreads();
    for (int i = t; i < n; i += 1024) {
        uint2 ed = be[i];
        int loc = atomicAdd(&h[(int)ed.y - node0], 1);
        csr[base_ + loc] = (int)ed.x;
    }
}

// ---------------- agg1: fp8 gather (128B/row), fp32 accumulate, saddr x16 ----------------

__global__ __launch_bounds__(256) void k_agg1(const uchar_t* __restrict__ xq,
                                              const int* __restrict__ rowptr,
                                              const int* __restrict__ csr,
                                              ushort_t* __restrict__ outb) {
    int wid = (blockIdx.x * blockDim.x + threadIdx.x) >> 6;
    int lane = threadIdx.x & 63;
    if (wid >= Nn) return;
    int s0 = __builtin_amdgcn_readfirstlane(rowptr[wid]);
    int s1 = __builtin_amdgcn_readfirstlane(rowptr[wid + 1]);
    float ax = 0.f, ay = 0.f;
    int e = s0;
    for (; e + 16 <= s1; e += 16) {
        int idx[16];
        #pragma unroll
        for (int j = 0; j < 16; ++j) idx[j] = __builtin_amdgcn_readfirstlane(csr[e + j]);
        ushort_t u[16];
        #pragma unroll
        for (int j = 0; j < 16; ++j)
            u[j] = *reinterpret_cast<const ushort_t*>(xq + (size_t)idx[j] * 128 + lane * 2);
        #pragma unroll
        for (int j = 0; j < 16; ++j) {
            f32x2 f = __builtin_amdgcn_cvt_pk_f32_fp8((int)u[j], false);
            ax += f.x; ay += f.y;
        }
    }
    for (; e + 8 <= s1; e += 8) {
        int idx[8];
        #pragma unroll
        for (int j = 0; j < 8; ++j) idx[j] = __builtin_amdgcn_readfirstlane(csr[e + j]);
        ushort_t u[8];
        #pragma unroll
        for (int j = 0; j < 8; ++j)
            u[j] = *reinterpret_cast<const ushort_t*>(xq + (size_t)idx[j] * 128 + lane * 2);
        #pragma unroll
        for (int j = 0; j < 8; ++j) {
            f32x2 f = __builtin_amdgcn_cvt_pk_f32_fp8((int)u[j], false);
            ax += f.x; ay += f.y;
        }
    }
    for (; e < s1; ++e) {
        int s = __builtin_amdgcn_readfirstlane(csr[e]);
        ushort_t u = *reinterpret_cast<const ushort_t*>(xq + (size_t)s * 128 + lane * 2);
        f32x2 f = __builtin_amdgcn_cvt_pk_f32_fp8((int)u, false);
        ax += f.x; ay += f.y;
    }
    float invd = (s1 > s0) ? 1.0f / (float)(s1 - s0) : 0.0f;
    uint_t o = (uint_t)f2bf(ax * invd) | ((uint_t)f2bf(ay * invd) << 16);
    *reinterpret_cast<uint_t*>(outb + (size_t)wid * 128 + lane * 2) = o;
}

// ---------------- MFMA GEMMs (16x16x32 bf16) ----------------
// gemm1m: both W matrices (64KB > L1) staged in LDS with XOR swizzle.
// A-frag: lane holds A[row0+(lane&15)][ks*32+(lane>>4)*8 .. +7]
// D: col=lane&15, row=(lane>>4)*4+reg   [verified: absmax unchanged]

__global__ __launch_bounds__(512) void k_gemm1m(const ushort_t* __restrict__ Ab0,
                                                const ushort_t* __restrict__ Ab1,
                                                const ushort_t* __restrict__ Wt0,
                                                const ushort_t* __restrict__ Wt1,
                                                const float* __restrict__ bias,
                                                ushort_t* __restrict__ hb) {
    __shared__ ushort_t lw[2 * 16384];   // 64KB: [pair][col][k] bf16, swizzled
    const int tid = threadIdx.x;
    char* lwc = reinterpret_cast<char*>(lw);
    #pragma unroll
    for (int i = 0; i < 8; ++i) {        // 4096 16B chunks / 512 threads
        int c = tid + i * 512;
        int pair = c >> 11;
        int col = (c & 2047) >> 4;
        int kc = c & 15;
        const ushort_t* Wsrc = pair ? Wt1 : Wt0;
        uint4 v = *reinterpret_cast<const uint4*>(Wsrc + col * 128 + kc * 8);
        int dst = ((pair << 15) | (col << 8) | (kc << 4)) ^ ((col & 7) << 4);
        *reinterpret_cast<uint4*>(lwc + dst) = v;
    }
    __syncthreads();

    int gw = (blockIdx.x * 512 + tid) >> 6;
    int lane = tid & 63;
    if (gw >= Nn / 16) return;
    int row0 = gw * 16;
    int r = lane & 15;
    int kg = lane >> 4;
    f32x4 acc[8];
    #pragma unroll
    for (int c = 0; c < 8; ++c) acc[c] = (f32x4){0.f, 0.f, 0.f, 0.f};
    #pragma unroll
    for (int pair = 0; pair < 2; ++pair) {
        const ushort_t* A = pair ? Ab1 : Ab0;
        #pragma unroll
        for (int ks = 0; ks < 4; ++ks) {
            int kbase = ks * 32 + kg * 8;
            bf16x8 af = *reinterpret_cast<const bf16x8*>(A + (size_t)(row0 + r) * 128 + kbase);
            #pragma unroll
            for (int c = 0; c < 8; ++c) {
                int boff = ((pair << 15) | ((c * 16 + r) << 8) | (ks * 64 + kg * 16))
                           ^ ((r & 7) << 4);
                bf16x8 bf = *reinterpret_cast<const bf16x8*>(lwc + boff);
                acc[c] = __builtin_amdgcn_mfma_f32_16x16x32_bf16(af, bf, acc[c], 0, 0, 0);
            }
        }
    }
    #pragma unroll
    for (int c = 0; c < 8; ++c) {
        float bv = bias[c * 16 + r];
        #pragma unroll
        for (int i = 0; i < 4; ++i) {
            int row = row0 + kg * 4 + i;
            hb[(size_t)row * 128 + c * 16 + r] = f2bf(fmaxf(acc[c][i] + bv, 0.f));
        }
    }
}

// fused layer-2 projections: tb = bf16(hb@W2l); out = f32(hb@W2r)
__global__ __launch_bounds__(256) void k_gemm2f(const ushort_t* __restrict__ Ab,
                                                const ushort_t* __restrict__ Wtl,
                                                const ushort_t* __restrict__ Wtr,
                                                ushort_t* __restrict__ tb,
                                                float* __restrict__ outu) {
    int gw = (blockIdx.x * 256 + threadIdx.x) >> 6;
    int lane = threadIdx.x & 63;
    if (gw >= Nn / 16) return;
    int row0 = gw * 16;
    int r = lane & 15;
    int kg = lane >> 4;
    f32x4 accL[4], accR[4];
    #pragma unroll
    for (int c = 0; c < 4; ++c) {
        accL[c] = (f32x4){0.f, 0.f, 0.f, 0.f};
        accR[c] = (f32x4){0.f, 0.f, 0.f, 0.f};
    }
    #pragma unroll
    for (int ks = 0; ks < 4; ++ks) {
        int kbase = ks * 32 + kg * 8;
        bf16x8 af = *reinterpret_cast<const bf16x8*>(Ab + (size_t)(row0 + r) * 128 + kbase);
        #pragma unroll
        for (int c = 0; c < 4; ++c) {
            bf16x8 bl = *reinterpret_cast<const bf16x8*>(Wtl + (size_t)(c * 16 + r) * 128 + kbase);
            accL[c] = __builtin_amdgcn_mfma_f32_16x16x32_bf16(af, bl, accL[c], 0, 0, 0);
            bf16x8 br = *reinterpret_cast<const bf16x8*>(Wtr + (size_t)(c * 16 + r) * 128 + kbase);
            accR[c] = __builtin_amdgcn_mfma_f32_16x16x32_bf16(af, br, accR[c], 0, 0, 0);
        }
    }
    #pragma unroll
    for (int c = 0; c < 4; ++c) {
        #pragma unroll
        for (int i = 0; i < 4; ++i) {
            int row = row0 + kg * 4 + i;
            tb[(size_t)row * 64 + c * 16 + r] = f2bf(accL[c][i]);
            outu[(size_t)row * 64 + c * 16 + r] = accR[c][i];
        }
    }
}

// ---------------- fused agg2-gather + add + log_softmax ----------------

__global__ __launch_bounds__(256) void k_logsm(float* __restrict__ out,
                                               const ushort_t* __restrict__ tb,
                                               const int* __restrict__ rowptr,
                                               const int* __restrict__ csr,
                                               const float* __restrict__ bias) {
    int wid = (blockIdx.x * blockDim.x + threadIdx.x) >> 6;
    int lane = threadIdx.x & 63;
    if (wid >= Nn) return;
    int s0 = __builtin_amdgcn_readfirstlane(rowptr[wid]);
    int s1 = __builtin_amdgcn_readfirstlane(rowptr[wid + 1]);
    float a = 0.f;
    int e = s0;
    for (; e + 16 <= s1; e += 16) {
        int idx[16];
        #pragma unroll
        for (int j = 0; j < 16; ++j) idx[j] = __builtin_amdgcn_readfirstlane(csr[e + j]);
        ushort_t u[16];
        #pragma unroll
        for (int j = 0; j < 16; ++j) u[j] = tb[(size_t)idx[j] * 64 + lane];
        #pragma unroll
        for (int j = 0; j < 16; ++j) a += __uint_as_float(((uint_t)u[j]) << 16);
    }
    for (; e + 8 <= s1; e += 8) {
        int idx[8];
        #pragma unroll
        for (int j = 0; j < 8; ++j) idx[j] = __builtin_amdgcn_readfirstlane(csr[e + j]);
        ushort_t u[8];
        #pragma unroll
        for (int j = 0; j < 8; ++j) u[j] = tb[(size_t)idx[j] * 64 + lane];
        #pragma unroll
        for (int j = 0; j < 8; ++j) a += __uint_as_float(((uint_t)u[j]) << 16);
    }
    for (; e < s1; ++e) {
        int s = __builtin_amdgcn_readfirstlane(csr[e]);
        a += __uint_as_float(((uint_t)tb[(size_t)s * 64 + lane]) << 16);
    }
    float invd = (s1 > s0) ? 1.0f / (float)(s1 - s0) : 0.0f;
    size_t o = (size_t)wid * 64 + lane;
    float v = (out[o] + a * invd) + bias[lane];
    float m = v;
    #pragma unroll
    for (int off = 32; off; off >>= 1) m = fmaxf(m, __shfl_xor(m, off));
    float ex = __expf(v - m);
    float s_ = ex;
    #pragma unroll
    for (int off = 32; off; off >>= 1) s_ += __shfl_xor(s_, off);
    out[o] = v - m - __logf(s_);
}

// ---------------- launch ----------------

extern "C" void kernel_launch(void* const* d_in, const int* in_sizes, int n_in,
                              void* d_out, int out_size, void* d_ws, size_t ws_size,
                              hipStream_t stream) {
    const float* x   = (const float*)d_in[0];
    const int*   ei  = (const int*)d_in[1];
    const float* W1l = (const float*)d_in[2];
    const float* W1r = (const float*)d_in[3];
    const float* b1  = (const float*)d_in[4];
    const float* W2l = (const float*)d_in[5];
    const float* W2r = (const float*)d_in[6];
    const float* b2  = (const float*)d_in[7];
    float* out = (float*)d_out;

    char* ws = (char*)d_ws;
    int*      rowptr = (int*)(ws + 800768);        // N+1 ints -> ends 1200772
    int*      csr    = (int*)(ws + 1201152);       // E ints -> ends 7601152
    ushort_t* xb     = (ushort_t*)(ws + 7601152);  // N*128 bf16 -> ends 33201152
    ushort_t* aggb   = (ushort_t*)(ws + 33201152); // N*128 bf16 -> ends 58801152
    ushort_t* w1lt   = (ushort_t*)(ws + 58801152); // 128*128 bf16
    ushort_t* w1rt   = (ushort_t*)(ws + 58833920);
    ushort_t* w2lt   = (ushort_t*)(ws + 58866688); // 64*128 bf16
    ushort_t* w2rt   = (ushort_t*)(ws + 58883072); // ends 58899456
    uint2*    bedge  = (uint2*)(ws + 60000000);    // NB*BCAP uint2 -> ends 74450688 (dead after fillB)
    int*      bcur   = (int*)(ws + 74450688);      // NB ints -> ends 74451472
    uint_t*   xq     = (uint_t*)(ws + 74451968);   // N*128 fp8 = 12.8MB -> ends 87251968
    ushort_t* hb     = (ushort_t*)(ws + 84401152); // N*128 bf16 -> ends 110001152
    // NOTE: xq overlaps hb head [84401152,87251968) — lifetime-disjoint:
    // xq last read in k_agg1; hb first written in k_gemm1m (stream-ordered after).
    ushort_t* tb     = (ushort_t*)(ws + 7601152);  // N*64 bf16 over dead xb (after gemm1m)
    // high-water: 110001152 bytes

    const int* src = ei;
    const int* dst = ei + Ee;

    hipMemsetAsync(bcur, 0, NB * 4, stream);

    // front: edge scatter + x cvt (bf16+fp8) + weight cvt
    k_front<<<NB + 3125 + 48, 1024, 0, stream>>>(src, dst, bcur, bedge, x, xb, xq,
                                                 W1l, W1r, W2l, W2r,
                                                 w1lt, w1rt, w2lt, w2rt);
    k_fillB<<<NB, 1024, 0, stream>>>(bedge, bcur, rowptr, csr);

    // layer 1 (fp8 gather table)
    k_agg1<<<(Nn + 3) / 4, 256, 0, stream>>>((const uchar_t*)xq, rowptr, csr, aggb);
    k_gemm1m<<<(Nn / 16 + 7) / 8, 512, 0, stream>>>(aggb, xb, w1lt, w1rt, b1, hb);

    // layer 2 (reassociated, fused projections; agg2 fused into logsm)
    k_gemm2f<<<(Nn / 16 + 3) / 4, 256, 0, stream>>>(hb, w2lt, w2rt, tb, out);
    k_logsm<<<(Nn + 3) / 4, 256, 0, stream>>>(out, tb, rowptr, csr, b2);
}

// Round 21
// 196.283 us; speedup vs baseline: 4.0172x; 1.0123x over previous
//
#include <hip/hip_runtime.h>

#define Nn 100000
#define Ee 1600000
#define FIN 128
#define HID 128
#define CLS 64
#define NB 196       // dst buckets of 512 nodes (dst>>9)
#define BCAP 9216    // per-bucket edge capacity (mean 8163 + 11 sigma)

typedef unsigned short ushort_t;
typedef unsigned char uchar_t;
typedef unsigned int uint_t;
typedef __attribute__((ext_vector_type(8))) short bf16x8;
typedef __attribute__((ext_vector_type(4))) float f32x4;
typedef __attribute__((ext_vector_type(2))) float f32x2;

__device__ __forceinline__ ushort_t f2bf(float f) {   // RNE fp32->bf16
    uint_t u = __float_as_uint(f);
    return (ushort_t)((u + 0x7fffu + ((u >> 16) & 1u)) >> 16);
}
__device__ __forceinline__ float bflo(uint_t u) { return __uint_as_float(u << 16); }
__device__ __forceinline__ float bfhi(uint_t u) { return __uint_as_float(u & 0xffff0000u); }

// ---------------- combined front kernel ----------------
// blocks [0,196): bucketed edge scatter; [196,3321): x -> {bf16 xb, fp8 xq};
// [3321,3369): weight transpose+cvt.

__global__ __launch_bounds__(1024) void k_front(const int* __restrict__ src,
                                                const int* __restrict__ dst,
                                                int* __restrict__ bcur,
                                                uint2* __restrict__ bedge,
                                                const float* __restrict__ x,
                                                ushort_t* __restrict__ xb,
                                                uint_t* __restrict__ xq,
                                                const float* __restrict__ W1l,
                                                const float* __restrict__ W1r,
                                                const float* __restrict__ W2l,
                                                const float* __restrict__ W2r,
                                                ushort_t* __restrict__ w1lt,
                                                ushort_t* __restrict__ w1rt,
                                                ushort_t* __restrict__ w2lt,
                                                ushort_t* __restrict__ w2rt) {
    __shared__ int h[NB];
    __shared__ int lbase[NB];
    int b = blockIdx.x;
    int t = threadIdx.x;
    if (b < NB) {
        // ---- bucketed edge scatter ----
        if (t < NB) h[t] = 0;
        __syncthreads();
        int base = b * 8192;
        int bk[8], loc[8];
        #pragma unroll
        for (int it = 0; it < 8; ++it) {
            int e = base + it * 1024 + t;
            if (e < Ee) {
                bk[it] = dst[e] >> 9;
                loc[it] = atomicAdd(&h[bk[it]], 1);
            }
        }
        __syncthreads();
        if (t < NB && h[t]) lbase[t] = atomicAdd(&bcur[t], h[t]);
        __syncthreads();
        #pragma unroll
        for (int it = 0; it < 8; ++it) {
            int e = base + it * 1024 + t;
            if (e < Ee) {
                int pos = lbase[bk[it]] + loc[it];
                if (pos < BCAP)   // statistically impossible overflow guard
                    bedge[(size_t)bk[it] * BCAP + pos] = make_uint2((uint_t)src[e], (uint_t)dst[e]);
            }
        }
    } else if (b < NB + 3125) {
        // ---- x (f32) -> xb (bf16) + xq (fp8 e4m3); 3125*1024 = Nn*FIN/4 ----
        int i = (b - NB) * 1024 + t;
        float4 v = reinterpret_cast<const float4*>(x)[i];
        ushort4 o;
        o.x = f2bf(v.x); o.y = f2bf(v.y); o.z = f2bf(v.z); o.w = f2bf(v.w);
        reinterpret_cast<ushort4*>(xb)[i] = o;
        int q = __builtin_amdgcn_cvt_pk_fp8_f32(v.x, v.y, 0, false);
        q = __builtin_amdgcn_cvt_pk_fp8_f32(v.z, v.w, q, true);
        xq[i] = (uint_t)q;
    } else {
        // ---- weight transpose + cvt: W[k][n] f32 -> Wt[n][k] bf16 ----
        int j = b - (NB + 3125);
        const float* Wsrc; ushort_t* Wdst; int Ncols; int cb;
        if (j < 16)      { Wsrc = W1l; Wdst = w1lt; Ncols = 128; cb = j; }
        else if (j < 32) { Wsrc = W1r; Wdst = w1rt; Ncols = 128; cb = j - 16; }
        else if (j < 40) { Wsrc = W2l; Wdst = w2lt; Ncols = 64;  cb = j - 32; }
        else             { Wsrc = W2r; Wdst = w2rt; Ncols = 64;  cb = j - 40; }
        int i = cb * 1024 + t;
        if (i < 128 * Ncols) {
            int k = i / Ncols, n = i % Ncols;
            Wdst[(size_t)n * 128 + k] = f2bf(Wsrc[i]);
        }
    }
}

// fused per-bucket: bucket scan (from bcur) -> LDS hist -> LDS scan ->
// rowptr write -> CSR fill
__global__ __launch_bounds__(1024) void k_fillB(const uint2* __restrict__ bedge,
                                                const int* __restrict__ bcur,
                                                int* __restrict__ rowptr,
                                                int* __restrict__ csr) {
    __shared__ int h[512];
    __shared__ int off[512];
    __shared__ int sbase;
    int b = blockIdx.x, t = threadIdx.x;
    if (t < 256) off[t] = (t < NB) ? min(bcur[t], BCAP) : 0;
    __syncthreads();
    for (int o = 1; o < 256; o <<= 1) {
        int v = (t < 256 && t >= o) ? off[t - o] : 0;
        __syncthreads();
        if (t < 256) off[t] += v;
        __syncthreads();
    }
    if (t == 0) sbase = off[b] - min(bcur[b], BCAP);
    if (b == NB - 1 && t == 0) rowptr[Nn] = off[NB - 1];
    __syncthreads();
    int base_ = sbase;
    int n = min(bcur[b], BCAP);
    int node0 = b << 9;
    const uint2* be = bedge + (size_t)b * BCAP;
    if (t < 512) h[t] = 0;
    __syncthreads();
    for (int i = t; i < n; i += 1024)
        atomicAdd(&h[(int)be[i].y - node0], 1);
    __syncthreads();
    if (t < 512) off[t] = h[t];
    __syncthreads();
    for (int o = 1; o < 512; o <<= 1) {
        int v = (t < 512 && t >= o) ? off[t - o] : 0;
        __syncthreads();
        if (t < 512) off[t] += v;
        __syncthreads();
    }
    if (t < 512) {
        int excl = off[t] - h[t];
        int node = node0 + t;
        if (node < Nn) rowptr[node] = base_ + excl;
        h[t] = excl;    // running local offset
    }
    __syncthreads();
    for (int i = t; i < n; i += 1024) {
        uint2 ed = be[i];
        int loc = atomicAdd(&h[(int)ed.y - node0], 1);
        csr[base_ + loc] = (int)ed.x;
    }
}

// ---------------- agg1: fp8 gather (128B/row), fp32 accumulate, saddr x16 ----------------

__global__ __launch_bounds__(256) void k_agg1(const uchar_t* __restrict__ xq,
                                              const int* __restrict__ rowptr,
                                              const int* __restrict__ csr,
                                              ushort_t* __restrict__ outb) {
    int wid = (blockIdx.x * blockDim.x + threadIdx.x) >> 6;
    int lane = threadIdx.x & 63;
    if (wid >= Nn) return;
    int s0 = __builtin_amdgcn_readfirstlane(rowptr[wid]);
    int s1 = __builtin_amdgcn_readfirstlane(rowptr[wid + 1]);
    float ax = 0.f, ay = 0.f;
    int e = s0;
    for (; e + 16 <= s1; e += 16) {
        int idx[16];
        #pragma unroll
        for (int j = 0; j < 16; ++j) idx[j] = __builtin_amdgcn_readfirstlane(csr[e + j]);
        ushort_t u[16];
        #pragma unroll
        for (int j = 0; j < 16; ++j)
            u[j] = *reinterpret_cast<const ushort_t*>(xq + (size_t)idx[j] * 128 + lane * 2);
        #pragma unroll
        for (int j = 0; j < 16; ++j) {
            f32x2 f = __builtin_amdgcn_cvt_pk_f32_fp8((int)u[j], false);
            ax += f.x; ay += f.y;
        }
    }
    for (; e + 8 <= s1; e += 8) {
        int idx[8];
        #pragma unroll
        for (int j = 0; j < 8; ++j) idx[j] = __builtin_amdgcn_readfirstlane(csr[e + j]);
        ushort_t u[8];
        #pragma unroll
        for (int j = 0; j < 8; ++j)
            u[j] = *reinterpret_cast<const ushort_t*>(xq + (size_t)idx[j] * 128 + lane * 2);
        #pragma unroll
        for (int j = 0; j < 8; ++j) {
            f32x2 f = __builtin_amdgcn_cvt_pk_f32_fp8((int)u[j], false);
            ax += f.x; ay += f.y;
        }
    }
    for (; e < s1; ++e) {
        int s = __builtin_amdgcn_readfirstlane(csr[e]);
        ushort_t u = *reinterpret_cast<const ushort_t*>(xq + (size_t)s * 128 + lane * 2);
        f32x2 f = __builtin_amdgcn_cvt_pk_f32_fp8((int)u, false);
        ax += f.x; ay += f.y;
    }
    float invd = (s1 > s0) ? 1.0f / (float)(s1 - s0) : 0.0f;
    uint_t o = (uint_t)f2bf(ax * invd) | ((uint_t)f2bf(ay * invd) << 16);
    *reinterpret_cast<uint_t*>(outb + (size_t)wid * 128 + lane * 2) = o;
}

// ---------------- MFMA GEMMs (16x16x32 bf16) ----------------
// gemm1m: both W matrices (64KB > L1) staged in LDS with XOR swizzle.
// A-frag: lane holds A[row0+(lane&15)][ks*32+(lane>>4)*8 .. +7]
// D: col=lane&15, row=(lane>>4)*4+reg   [verified: absmax unchanged]

__global__ __launch_bounds__(512) void k_gemm1m(const ushort_t* __restrict__ Ab0,
                                                const ushort_t* __restrict__ Ab1,
                                                const ushort_t* __restrict__ Wt0,
                                                const ushort_t* __restrict__ Wt1,
                                                const float* __restrict__ bias,
                                                ushort_t* __restrict__ hb) {
    __shared__ ushort_t lw[2 * 16384];   // 64KB: [pair][col][k] bf16, swizzled
    const int tid = threadIdx.x;
    char* lwc = reinterpret_cast<char*>(lw);
    #pragma unroll
    for (int i = 0; i < 8; ++i) {        // 4096 16B chunks / 512 threads
        int c = tid + i * 512;
        int pair = c >> 11;
        int col = (c & 2047) >> 4;
        int kc = c & 15;
        const ushort_t* Wsrc = pair ? Wt1 : Wt0;
        uint4 v = *reinterpret_cast<const uint4*>(Wsrc + col * 128 + kc * 8);
        int dst = ((pair << 15) | (col << 8) | (kc << 4)) ^ ((col & 7) << 4);
        *reinterpret_cast<uint4*>(lwc + dst) = v;
    }
    __syncthreads();

    int gw = (blockIdx.x * 512 + tid) >> 6;
    int lane = tid & 63;
    if (gw >= Nn / 16) return;
    int row0 = gw * 16;
    int r = lane & 15;
    int kg = lane >> 4;
    f32x4 acc[8];
    #pragma unroll
    for (int c = 0; c < 8; ++c) acc[c] = (f32x4){0.f, 0.f, 0.f, 0.f};
    #pragma unroll
    for (int pair = 0; pair < 2; ++pair) {
        const ushort_t* A = pair ? Ab1 : Ab0;
        #pragma unroll
        for (int ks = 0; ks < 4; ++ks) {
            int kbase = ks * 32 + kg * 8;
            bf16x8 af = *reinterpret_cast<const bf16x8*>(A + (size_t)(row0 + r) * 128 + kbase);
            #pragma unroll
            for (int c = 0; c < 8; ++c) {
                int boff = ((pair << 15) | ((c * 16 + r) << 8) | (ks * 64 + kg * 16))
                           ^ ((r & 7) << 4);
                bf16x8 bf = *reinterpret_cast<const bf16x8*>(lwc + boff);
                acc[c] = __builtin_amdgcn_mfma_f32_16x16x32_bf16(af, bf, acc[c], 0, 0, 0);
            }
        }
    }
    #pragma unroll
    for (int c = 0; c < 8; ++c) {
        float bv = bias[c * 16 + r];
        #pragma unroll
        for (int i = 0; i < 4; ++i) {
            int row = row0 + kg * 4 + i;
            hb[(size_t)row * 128 + c * 16 + r] = f2bf(fmaxf(acc[c][i] + bv, 0.f));
        }
    }
}

// fused layer-2 projections: tb8 = fp8(hb@W2l); out = f32(hb@W2r)
__global__ __launch_bounds__(256) void k_gemm2f(const ushort_t* __restrict__ Ab,
                                                const ushort_t* __restrict__ Wtl,
                                                const ushort_t* __restrict__ Wtr,
                                                uchar_t* __restrict__ tb8,
                                                float* __restrict__ outu) {
    int gw = (blockIdx.x * 256 + threadIdx.x) >> 6;
    int lane = threadIdx.x & 63;
    if (gw >= Nn / 16) return;
    int row0 = gw * 16;
    int r = lane & 15;
    int kg = lane >> 4;
    f32x4 accL[4], accR[4];
    #pragma unroll
    for (int c = 0; c < 4; ++c) {
        accL[c] = (f32x4){0.f, 0.f, 0.f, 0.f};
        accR[c] = (f32x4){0.f, 0.f, 0.f, 0.f};
    }
    #pragma unroll
    for (int ks = 0; ks < 4; ++ks) {
        int kbase = ks * 32 + kg * 8;
        bf16x8 af = *reinterpret_cast<const bf16x8*>(Ab + (size_t)(row0 + r) * 128 + kbase);
        #pragma unroll
        for (int c = 0; c < 4; ++c) {
            bf16x8 bl = *reinterpret_cast<const bf16x8*>(Wtl + (size_t)(c * 16 + r) * 128 + kbase);
            accL[c] = __builtin_amdgcn_mfma_f32_16x16x32_bf16(af, bl, accL[c], 0, 0, 0);
            bf16x8 br = *reinterpret_cast<const bf16x8*>(Wtr + (size_t)(c * 16 + r) * 128 + kbase);
            accR[c] = __builtin_amdgcn_mfma_f32_16x16x32_bf16(af, br, accR[c], 0, 0, 0);
        }
    }
    #pragma unroll
    for (int c = 0; c < 4; ++c) {
        #pragma unroll
        for (int i = 0; i < 4; ++i) {
            int row = row0 + kg * 4 + i;
            int q = __builtin_amdgcn_cvt_pk_fp8_f32(accL[c][i], accL[c][i], 0, false);
            tb8[(size_t)row * 64 + c * 16 + r] = (uchar_t)(q & 0xff);
            outu[(size_t)row * 64 + c * 16 + r] = accR[c][i];
        }
    }
}

// ---------------- fused agg2-gather (fp8) + add + log_softmax ----------------

__global__ __launch_bounds__(256) void k_logsm(float* __restrict__ out,
                                               const uchar_t* __restrict__ tb8,
                                               const int* __restrict__ rowptr,
                                               const int* __restrict__ csr,
                                               const float* __restrict__ bias) {
    int wid = (blockIdx.x * blockDim.x + threadIdx.x) >> 6;
    int lane = threadIdx.x & 63;
    if (wid >= Nn) return;
    int s0 = __builtin_amdgcn_readfirstlane(rowptr[wid]);
    int s1 = __builtin_amdgcn_readfirstlane(rowptr[wid + 1]);
    float a = 0.f;
    int e = s0;
    for (; e + 16 <= s1; e += 16) {
        int idx[16];
        #pragma unroll
        for (int j = 0; j < 16; ++j) idx[j] = __builtin_amdgcn_readfirstlane(csr[e + j]);
        uchar_t u[16];
        #pragma unroll
        for (int j = 0; j < 16; ++j) u[j] = tb8[(size_t)idx[j] * 64 + lane];
        #pragma unroll
        for (int j = 0; j < 16; ++j) a += __builtin_amdgcn_cvt_f32_fp8((int)u[j], 0);
    }
    for (; e + 8 <= s1; e += 8) {
        int idx[8];
        #pragma unroll
        for (int j = 0; j < 8; ++j) idx[j] = __builtin_amdgcn_readfirstlane(csr[e + j]);
        uchar_t u[8];
        #pragma unroll
        for (int j = 0; j < 8; ++j) u[j] = tb8[(size_t)idx[j] * 64 + lane];
        #pragma unroll
        for (int j = 0; j < 8; ++j) a += __builtin_amdgcn_cvt_f32_fp8((int)u[j], 0);
    }
    for (; e < s1; ++e) {
        int s = __builtin_amdgcn_readfirstlane(csr[e]);
        a += __builtin_amdgcn_cvt_f32_fp8((int)tb8[(size_t)s * 64 + lane], 0);
    }
    float invd = (s1 > s0) ? 1.0f / (float)(s1 - s0) : 0.0f;
    size_t o = (size_t)wid * 64 + lane;
    float v = (out[o] + a * invd) + bias[lane];
    float m = v;
    #pragma unroll
    for (int off = 32; off; off >>= 1) m = fmaxf(m, __shfl_xor(m, off));
    float ex = __expf(v - m);
    float s_ = ex;
    #pragma unroll
    for (int off = 32; off; off >>= 1) s_ += __shfl_xor(s_, off);
    out[o] = v - m - __logf(s_);
}

// ---------------- launch ----------------

extern "C" void kernel_launch(void* const* d_in, const int* in_sizes, int n_in,
                              void* d_out, int out_size, void* d_ws, size_t ws_size,
                              hipStream_t stream) {
    const float* x   = (const float*)d_in[0];
    const int*   ei  = (const int*)d_in[1];
    const float* W1l = (const float*)d_in[2];
    const float* W1r = (const float*)d_in[3];
    const float* b1  = (const float*)d_in[4];
    const float* W2l = (const float*)d_in[5];
    const float* W2r = (const float*)d_in[6];
    const float* b2  = (const float*)d_in[7];
    float* out = (float*)d_out;

    char* ws = (char*)d_ws;
    int*      rowptr = (int*)(ws + 800768);        // N+1 ints -> ends 1200772
    int*      csr    = (int*)(ws + 1201152);       // E ints -> ends 7601152
    ushort_t* xb     = (ushort_t*)(ws + 7601152);  // N*128 bf16 -> ends 33201152
    ushort_t* aggb   = (ushort_t*)(ws + 33201152); // N*128 bf16 -> ends 58801152
    ushort_t* w1lt   = (ushort_t*)(ws + 58801152); // 128*128 bf16
    ushort_t* w1rt   = (ushort_t*)(ws + 58833920);
    ushort_t* w2lt   = (ushort_t*)(ws + 58866688); // 64*128 bf16
    ushort_t* w2rt   = (ushort_t*)(ws + 58883072); // ends 58899456
    uint2*    bedge  = (uint2*)(ws + 60000000);    // NB*BCAP uint2 -> ends 74450688 (dead after fillB)
    int*      bcur   = (int*)(ws + 74450688);      // NB ints -> ends 74451472
    uint_t*   xq     = (uint_t*)(ws + 74451968);   // N*128 fp8 = 12.8MB -> ends 87251968
    ushort_t* hb     = (ushort_t*)(ws + 84401152); // N*128 bf16 -> ends 110001152
    // NOTE: xq overlaps hb head [84401152,87251968) — lifetime-disjoint:
    // xq last read in k_agg1; hb first written in k_gemm1m (stream-ordered after).
    uchar_t*  tb8    = (uchar_t*)(ws + 7601152);   // N*64 fp8 over dead xb (after gemm1m)
    // high-water: 110001152 bytes

    const int* src = ei;
    const int* dst = ei + Ee;

    hipMemsetAsync(bcur, 0, NB * 4, stream);

    // front: edge scatter + x cvt (bf16+fp8) + weight cvt
    k_front<<<NB + 3125 + 48, 1024, 0, stream>>>(src, dst, bcur, bedge, x, xb, xq,
                                                 W1l, W1r, W2l, W2r,
                                                 w1lt, w1rt, w2lt, w2rt);
    k_fillB<<<NB, 1024, 0, stream>>>(bedge, bcur, rowptr, csr);

    // layer 1 (fp8 gather table)
    k_agg1<<<(Nn + 3) / 4, 256, 0, stream>>>((const uchar_t*)xq, rowptr, csr, aggb);
    k_gemm1m<<<(Nn / 16 + 7) / 8, 512, 0, stream>>>(aggb, xb, w1lt, w1rt, b1, hb);

    // layer 2 (reassociated, fused projections; fp8 agg2 gather fused into logsm)
    k_gemm2f<<<(Nn / 16 + 3) / 4, 256, 0, stream>>>(hb, w2lt, w2rt, tb8, out);
    k_logsm<<<(Nn + 3) / 4, 256, 0, stream>>>(out, tb8, rowptr, csr, b2);
}